// Round 7
// baseline (647.813 us; speedup 1.0000x reference)
//
#include <hip/hip_runtime.h>
#include <math.h>

// Problem constants (B=1)
#define T_ 2048
#define D_ 1024
#define H_ 16
#define N_ 64
#define F_ 4096
#define NCHUNK 64
#define CLEN 32

typedef __attribute__((ext_vector_type(8))) short bf16x8;
typedef __attribute__((ext_vector_type(4))) float f32x4;
typedef __attribute__((address_space(3))) unsigned int lds_u32_t;
typedef __attribute__((address_space(1))) const unsigned int glb_u32_t;

static __device__ __forceinline__ float sigf(float x) { return 1.0f / (1.0f + __expf(-x)); }

static __device__ __forceinline__ ushort f2bf(float f) {
    union { float f; unsigned u; } c; c.f = f;
    unsigned r = (c.u + 0x7FFFu + ((c.u >> 16) & 1u)) >> 16;
    return (ushort)r;
}
static __device__ __forceinline__ float bf2f(ushort h) {
    union { unsigned u; float f; } c; c.u = ((unsigned)h) << 16;
    return c.f;
}

static __device__ __forceinline__ void st4(float* p, float4 v) { *(float4*)p = v; }
static __device__ __forceinline__ void st4(ushort* p, float4 v) {
    ushort4 o; o.x = f2bf(v.x); o.y = f2bf(v.y); o.z = f2bf(v.z); o.w = f2bf(v.w);
    *(ushort4*)p = o;
}

// ---------------------------------------------------------------------------
// RMSNorm: one block per token row. out = w * x * rsqrt(mean(x^2)+eps)
// ---------------------------------------------------------------------------
template <typename OutT>
__global__ __launch_bounds__(256) void rmsnorm_kernel(const float* __restrict__ x,
                                                      const float* __restrict__ w,
                                                      OutT* __restrict__ out,
                                                      float* __restrict__ last) {
    const int t = blockIdx.x;
    const int tid = threadIdx.x;
    const float4* xr = (const float4*)(x + (size_t)t * D_);
    float4 v = xr[tid];
    float ss = v.x * v.x + v.y * v.y + v.z * v.z + v.w * v.w;
    ss += __shfl_xor(ss, 1);
    ss += __shfl_xor(ss, 2);
    ss += __shfl_xor(ss, 4);
    ss += __shfl_xor(ss, 8);
    ss += __shfl_xor(ss, 16);
    ss += __shfl_xor(ss, 32);
    __shared__ float red[4];
    if ((tid & 63) == 0) red[tid >> 6] = ss;
    __syncthreads();
    float tot = red[0] + red[1] + red[2] + red[3];
    float scale = rsqrtf(tot * (1.0f / (float)D_) + 1e-6f);
    float4 wv = ((const float4*)w)[tid];
    float4 o;
    o.x = wv.x * v.x * scale;
    o.y = wv.y * v.y * scale;
    o.z = wv.z * v.z * scale;
    o.w = wv.w * v.w * scale;
    st4(out + (size_t)t * D_ + tid * 4, o);
    if (last != nullptr && t == T_ - 1) ((float4*)last)[tid] = o;
}

// ---------------------------------------------------------------------------
// Fused: v = x + p0 + p1 (split-K reduce of O-proj + residual); write v to
// resid_out AND rmsnorm(v)*w -> bf16 xm.
// ---------------------------------------------------------------------------
__global__ __launch_bounds__(256) void rmsnorm_reduce2(
    const float* __restrict__ x, const float* __restrict__ p0, const float* __restrict__ p1,
    const float* __restrict__ w, float* __restrict__ resid_out, ushort* __restrict__ xm) {
    const int t = blockIdx.x;
    const int tid = threadIdx.x;
    const size_t base = (size_t)t * D_ + tid * 4;
    float4 v = *(const float4*)(x + base);
    float4 a = *(const float4*)(p0 + base);
    float4 b = *(const float4*)(p1 + base);
    v.x += a.x + b.x; v.y += a.y + b.y; v.z += a.z + b.z; v.w += a.w + b.w;
    st4(resid_out + base, v);
    float ss = v.x * v.x + v.y * v.y + v.z * v.z + v.w * v.w;
    ss += __shfl_xor(ss, 1);
    ss += __shfl_xor(ss, 2);
    ss += __shfl_xor(ss, 4);
    ss += __shfl_xor(ss, 8);
    ss += __shfl_xor(ss, 16);
    ss += __shfl_xor(ss, 32);
    __shared__ float red[4];
    if ((tid & 63) == 0) red[tid >> 6] = ss;
    __syncthreads();
    float tot = red[0] + red[1] + red[2] + red[3];
    float scale = rsqrtf(tot * (1.0f / (float)D_) + 1e-6f);
    float4 wv = ((const float4*)w)[tid];
    float4 o;
    o.x = wv.x * v.x * scale;
    o.y = wv.y * v.y * scale;
    o.z = wv.z * v.z * scale;
    o.w = wv.w * v.w * scale;
    st4(xm + base, o);
}

// out[i] += p0[i]+p1[i]+p2[i]+p3[i]  (split-K4 reduce, float4-strided)
__global__ __launch_bounds__(256) void add4_kernel(float* __restrict__ out,
                                                   const float* __restrict__ p,
                                                   int n4slice) {
    const int i = blockIdx.x * 256 + threadIdx.x;  // float4 index
    const float4* p4 = (const float4*)p;
    float4 o = ((const float4*)out)[i];
    float4 a = p4[i], b = p4[i + n4slice], c = p4[i + 2 * n4slice], d = p4[i + 3 * n4slice];
    o.x += (a.x + b.x) + (c.x + d.x);
    o.y += (a.y + b.y) + (c.y + d.y);
    o.z += (a.z + b.z) + (c.z + d.z);
    o.w += (a.w + b.w) + (c.w + d.w);
    ((float4*)out)[i] = o;
}

// ---------------------------------------------------------------------------
// Token shift -> six bf16 activation buffers (GEMM A operands).
// ---------------------------------------------------------------------------
__global__ __launch_bounds__(256) void shift_kernel(
    const float* __restrict__ xn, const float* __restrict__ x_prev,
    const float* __restrict__ cr, const float* __restrict__ cw, const float* __restrict__ ck,
    const float* __restrict__ cv, const float* __restrict__ ca, const float* __restrict__ cg,
    ushort* __restrict__ xr, ushort* __restrict__ xw, ushort* __restrict__ xk,
    ushort* __restrict__ xv, ushort* __restrict__ xa, ushort* __restrict__ xg) {
    const int i = blockIdx.x * 256 + threadIdx.x;  // float4 index over T*256
    const int t = i >> 8, j = i & 255;
    const float4* xn4 = (const float4*)xn;
    float4 cur = xn4[i];
    float4 prev = (t == 0) ? ((const float4*)x_prev)[j] : xn4[i - 256];
    float4 xx;
    xx.x = prev.x - cur.x;
    xx.y = prev.y - cur.y;
    xx.z = prev.z - cur.z;
    xx.w = prev.w - cur.w;
#define APPLY(dst, c)                                   \
    {                                                   \
        float4 cc = ((const float4*)c)[j];              \
        float4 o;                                       \
        o.x = cur.x + xx.x * cc.x;                      \
        o.y = cur.y + xx.y * cc.y;                      \
        o.z = cur.z + xx.z * cc.z;                      \
        o.w = cur.w + xx.w * cc.w;                      \
        st4(dst + (size_t)i * 4, o);                    \
    }
    APPLY(xr, cr)
    APPLY(xw, cw)
    APPLY(xk, ck)
    APPLY(xv, cv)
    APPLY(xa, ca)
    APPLY(xg, cg)
#undef APPLY
}

// ---------------------------------------------------------------------------
// Merged weight transpose + cast: all 15 weights in ONE launch.
// ---------------------------------------------------------------------------
struct TDesc { const float* in; ushort* out; int K, N, off; };
struct TPack { TDesc d[15]; };

__global__ __launch_bounds__(256) void transpose_cast_multi(TPack p) {
    __shared__ float tile[32][33];
    const int bid = blockIdx.x;
    int di = 0;
#pragma unroll
    for (int i = 1; i < 15; i++)
        if (bid >= p.d[i].off) di = i;
    const TDesc d = p.d[di];
    const int local = bid - d.off;
    const int nt = d.N >> 5;
    const int bx = local % nt, by = local / nt;
    const int tx = threadIdx.x & 31, ty = threadIdx.x >> 5;  // 32 x 8
    const int n0 = bx * 32, k0 = by * 32;
#pragma unroll
    for (int i = 0; i < 4; i++)
        tile[ty + i * 8][tx] = d.in[(size_t)(k0 + ty + i * 8) * d.N + n0 + tx];
    __syncthreads();
#pragma unroll
    for (int i = 0; i < 4; i++)
        d.out[(size_t)(n0 + ty + i * 8) * d.K + k0 + tx] = f2bf(tile[tx][ty + i * 8]);
}

// ---------------------------------------------------------------------------
// bf16 MFMA GEMM, 2-phase double-buffered global_load_lds pipeline.
// 128x128 tile, 4 waves 2x2, BK=32. PARTIAL=true: split-K slice z writes fp32
// partials at C + z*M*Ntot. Grids of exactly 8x16 (per z) get a 4x4-supertile
// XCD swizzle. epi: 0 none, 1 += res.
// ---------------------------------------------------------------------------
template <typename OutT, bool PARTIAL>
__global__ __launch_bounds__(256) void mfma_gemm(
    const ushort* __restrict__ A, const ushort* __restrict__ BT, OutT* __restrict__ C,
    const float* res, int M, int Ntot, int K, int klen, int epi) {
    __shared__ ushort As[2][128 * 32];
    __shared__ ushort Bs[2][128 * 32];
    const int tid = threadIdx.x;
    const int wave = tid >> 6, lane = tid & 63;
    const int wr = wave >> 1, wc = wave & 1;
    const int lrow = lane & 15, quad = lane >> 4;
    int bx = blockIdx.x, by = blockIdx.y;
    if (gridDim.x == 8 && gridDim.y == 16) {
        const int bid = by * 8 + bx;
        const int k = bid & 7, i = bid >> 3;
        bx = ((k & 1) << 2) + (i & 3);
        by = ((k >> 1) << 2) + (i >> 2);
    }
    const int m0 = by * 128, n0 = bx * 128;
    const int kbase = blockIdx.z * klen;
    const int srow = lane >> 2;
    const int scol = (lane & 3) << 3;

    f32x4 acc[4][4] = {};

    auto stage = [&](int buf, int kk) {
#pragma unroll
        for (int j = 0; j < 2; j++) {
            const int chunk = 2 * wave + j;  // 0..7
            const ushort* ga = A + (size_t)(m0 + chunk * 16 + srow) * K + kk + scol;
            __builtin_amdgcn_global_load_lds((glb_u32_t*)ga,
                                             (lds_u32_t*)&As[buf][chunk * 512], 16, 0, 0);
            const int brow = n0 + chunk * 16 + srow;
            if (brow < Ntot) {
                const ushort* gb = BT + (size_t)brow * K + kk + scol;
                __builtin_amdgcn_global_load_lds((glb_u32_t*)gb,
                                                 (lds_u32_t*)&Bs[buf][chunk * 512], 16, 0, 0);
            }
        }
    };

    stage(0, kbase);
    __syncthreads();
    int cur = 0;
    for (int k0 = kbase; k0 < kbase + klen; k0 += 32) {
        if (k0 + 32 < kbase + klen) stage(cur ^ 1, k0 + 32);
        bf16x8 af[4], bfr[4];
#pragma unroll
        for (int mi = 0; mi < 4; mi++)
            af[mi] = *(const bf16x8*)&As[cur][(wr * 64 + mi * 16 + lrow) * 32 + quad * 8];
#pragma unroll
        for (int ni = 0; ni < 4; ni++)
            bfr[ni] = *(const bf16x8*)&Bs[cur][(wc * 64 + ni * 16 + lrow) * 32 + quad * 8];
#pragma unroll
        for (int mi = 0; mi < 4; mi++)
#pragma unroll
            for (int ni = 0; ni < 4; ni++)
                acc[mi][ni] = __builtin_amdgcn_mfma_f32_16x16x32_bf16(af[mi], bfr[ni], acc[mi][ni], 0, 0, 0);
        __syncthreads();
        cur ^= 1;
    }

    const size_t zoff = PARTIAL ? (size_t)blockIdx.z * M * Ntot : 0;
#pragma unroll
    for (int mi = 0; mi < 4; mi++) {
#pragma unroll
        for (int r = 0; r < 4; r++) {
            const int row = m0 + wr * 64 + mi * 16 + quad * 4 + r;
#pragma unroll
            for (int ni = 0; ni < 4; ni++) {
                const int col = n0 + wc * 64 + ni * 16 + lrow;
                if (col < Ntot) {
                    const size_t idx = (size_t)row * Ntot + col;
                    float val = acc[mi][ni][r];
                    if constexpr (PARTIAL) {
                        ((float*)C)[idx + zoff] = val;
                    } else {
                        if (epi == 1) val += res[idx];
                        if constexpr (sizeof(OutT) == 2) C[idx] = (OutT)f2bf(val);
                        else C[idx] = (OutT)val;
                    }
                }
            }
        }
    }
}

// ---------------------------------------------------------------------------
// Multi-GEMM: z-indexed descriptors, same 2-phase pipeline. Non-atomic.
// epi: 0 none, 3 tanh, 4 sig, 5 sig(bias+v), 6 exp(-e^-.5*sig(bias+v)),
//      7 res+(res2-res)*sig(bias+v)
// ---------------------------------------------------------------------------
struct MMDesc {
    const ushort* A; const ushort* BT;
    float* Cf; ushort* Cb;
    const float* res; const float* res2; const float* bias;
    int Ntot, K, epi;
};
template <int NZ>
struct MMPack { MMDesc d[NZ]; };

template <int NZ>
__global__ __launch_bounds__(256) void mfma_gemm_multi(MMPack<NZ> p) {
    const MMDesc d = p.d[blockIdx.z];
    const int n0 = blockIdx.x * 128;
    if (n0 >= d.Ntot) return;  // uniform across block; no barrier crossed yet
    __shared__ ushort As[2][128 * 32];
    __shared__ ushort Bs[2][128 * 32];
    const int tid = threadIdx.x;
    const int wave = tid >> 6, lane = tid & 63;
    const int wr = wave >> 1, wc = wave & 1;
    const int lrow = lane & 15, quad = lane >> 4;
    const int m0 = blockIdx.y * 128;
    const int srow = lane >> 2;
    const int scol = (lane & 3) << 3;
    const int K = d.K, Ntot = d.Ntot;

    f32x4 acc[4][4] = {};

    auto stage = [&](int buf, int kk) {
#pragma unroll
        for (int j = 0; j < 2; j++) {
            const int chunk = 2 * wave + j;
            const ushort* ga = d.A + (size_t)(m0 + chunk * 16 + srow) * K + kk + scol;
            __builtin_amdgcn_global_load_lds((glb_u32_t*)ga,
                                             (lds_u32_t*)&As[buf][chunk * 512], 16, 0, 0);
            const int brow = n0 + chunk * 16 + srow;
            if (brow < Ntot) {
                const ushort* gb = d.BT + (size_t)brow * K + kk + scol;
                __builtin_amdgcn_global_load_lds((glb_u32_t*)gb,
                                                 (lds_u32_t*)&Bs[buf][chunk * 512], 16, 0, 0);
            }
        }
    };

    stage(0, 0);
    __syncthreads();
    int cur = 0;
    for (int k0 = 0; k0 < K; k0 += 32) {
        if (k0 + 32 < K) stage(cur ^ 1, k0 + 32);
        bf16x8 af[4], bfr[4];
#pragma unroll
        for (int mi = 0; mi < 4; mi++)
            af[mi] = *(const bf16x8*)&As[cur][(wr * 64 + mi * 16 + lrow) * 32 + quad * 8];
#pragma unroll
        for (int ni = 0; ni < 4; ni++)
            bfr[ni] = *(const bf16x8*)&Bs[cur][(wc * 64 + ni * 16 + lrow) * 32 + quad * 8];
#pragma unroll
        for (int mi = 0; mi < 4; mi++)
#pragma unroll
            for (int ni = 0; ni < 4; ni++)
                acc[mi][ni] = __builtin_amdgcn_mfma_f32_16x16x32_bf16(af[mi], bfr[ni], acc[mi][ni], 0, 0, 0);
        __syncthreads();
        cur ^= 1;
    }

#pragma unroll
    for (int mi = 0; mi < 4; mi++) {
#pragma unroll
        for (int r = 0; r < 4; r++) {
            const int row = m0 + wr * 64 + mi * 16 + quad * 4 + r;
#pragma unroll
            for (int ni = 0; ni < 4; ni++) {
                const int col = n0 + wc * 64 + ni * 16 + lrow;
                if (col < Ntot) {
                    const size_t idx = (size_t)row * Ntot + col;
                    float val = acc[mi][ni][r];
                    switch (d.epi) {
                        case 3: val = tanhf(val); break;
                        case 4: val = sigf(val); break;
                        case 5: val = sigf(d.bias[col] + val); break;
                        case 6: val = __expf(-0.60653065971263342f * sigf(d.bias[col] + val)); break;
                        case 7: {
                            float vr = d.res[idx];
                            val = vr + (d.res2[idx] - vr) * sigf(d.bias[col] + val);
                        } break;
                        default: break;
                    }
                    if (d.Cb) d.Cb[idx] = f2bf(val);
                    else d.Cf[idx] = val;
                }
            }
        }
    }
}

// ---------------------------------------------------------------------------
// kk = normalize_per_head(k * k_k); mb = -kk*a_sig; k *= (1+(a-1)*k_a).
// ---------------------------------------------------------------------------
__global__ __launch_bounds__(256) void kk_kernel(float* __restrict__ k,
                                                 const float* __restrict__ a_sig,
                                                 const float* __restrict__ k_k,
                                                 const float* __restrict__ k_a,
                                                 float* __restrict__ kk,
                                                 float* __restrict__ mb) {
    const int b = blockIdx.x * 4 + (threadIdx.x >> 6);
    const int t = b >> 4, h = b & 15;
    const int lane = threadIdx.x & 63;
    const size_t idx = (size_t)t * D_ + h * N_ + lane;
    const int wi = h * N_ + lane;
    const float kraw = k[idx];
    const float kv = kraw * k_k[wi];
    float ss = kv * kv;
    ss += __shfl_xor(ss, 1);
    ss += __shfl_xor(ss, 2);
    ss += __shfl_xor(ss, 4);
    ss += __shfl_xor(ss, 8);
    ss += __shfl_xor(ss, 16);
    ss += __shfl_xor(ss, 32);
    const float nrm = fmaxf(sqrtf(ss), 1e-12f);
    const float kkn = kv / nrm;
    kk[idx] = kkn;
    mb[idx] = -kkn * a_sig[idx];
    k[idx] = kraw * (1.0f + (a_sig[idx] - 1.0f) * k_a[wi]);
}

// ---------------------------------------------------------------------------
// Chunked scan pass 1, MERGED P+L roles, CLEN=32 / NCHUNK=64.
// One wave per (c,h) holds BOTH the identity-init propagator state (P) and
// the zero-init local state (L); both consume the SAME broadcast streams so
// the per-CU ds_read_b128 issue count (the R0-R4 measured wall: 844 cyc/iter
// = 80 reads x 10.5cyc) is paid ONCE for both. CLEN halved to keep 1024
// blocks = 4 waves/CU = 1/SIMD -- R6 showed 2 waves/CU goes latency-bound.
// ---------------------------------------------------------------------------
#define FOR16(M) M(0) M(1) M(2) M(3) M(4) M(5) M(6) M(7) \
                 M(8) M(9) M(10) M(11) M(12) M(13) M(14) M(15)

__global__ __launch_bounds__(64, 1) void scan_pass1(
    const float* __restrict__ gR, const float* __restrict__ gD, const float* __restrict__ gK,
    const float* __restrict__ gV, const float* __restrict__ gKK, const float* __restrict__ gMB,
    float* __restrict__ Pbuf, float* __restrict__ Lbuf,
    float* __restrict__ zbuf, float* __restrict__ olbuf) {
    const int bid = blockIdx.x;          // 0..NCHUNK*H-1
    const int h = bid & 15;
    const int c = bid >> 4;
    const int lane = threadIdx.x;        // row index
    const int hb = h * N_;
    const int t0 = c * CLEN;
    const int tend = t0 + CLEN - 1;

    __shared__ __align__(16) unsigned char ring[2 * 2048];

    const int rsel = lane >> 4;
    const int sub4 = (lane & 15) << 2;
    const float* p1 = (rsel == 0 ? gR : rsel == 1 ? gD : rsel == 2 ? gK : gKK)
                      + (size_t)t0 * D_ + hb + sub4;
    const float* p2 = (rsel == 1 ? gV : gMB) + (size_t)t0 * D_ + hb + sub4;

    // P state: identity rows; L state: zero.
#define DECLP(q) f32x4 sp##q = {(lane == 4 * q + 0) ? 1.0f : 0.0f, \
                                (lane == 4 * q + 1) ? 1.0f : 0.0f, \
                                (lane == 4 * q + 2) ? 1.0f : 0.0f, \
                                (lane == 4 * q + 3) ? 1.0f : 0.0f};
    FOR16(DECLP)
#undef DECLP
#define DECLL(q) f32x4 sl##q = {0.f, 0.f, 0.f, 0.f};
    FOR16(DECLL)
#undef DECLL

    float4 r0a, r0b, r1a, r1b, r2a, r2b, r3a, r3b;

#define LOADQ(qa, qb, tt) {                                                  \
        const size_t _adv = (size_t)((tt) - t0) * D_;                        \
        qa = *(const float4*)(p1 + _adv);                                    \
        qb = *(const float4*)(p2 + _adv); }
#define WRITEQ(sl, qa, qb) {                                                 \
        *(float4*)(ring + (sl) * 2048 + lane * 16) = qa;                     \
        *(float4*)(ring + (sl) * 2048 + 1024 + lane * 16) = qb; }
#define PA(q) { const f32x4 kk4 = sKKr[q];                                   \
        pacc += sp##q * kk4; lacc += sl##q * kk4; }
#define PB(q) {                                                   \
        const f32x4 d4 = sDr[q];                                  \
        const f32x4 k4 = sKr[q];                                  \
        const f32x4 m4 = sMBr[q];                                 \
        const f32x4 r4 = sRr[q];                                  \
        sp##q = sp##q * d4 + m4 * sapP;                           \
        sl##q = sl##q * d4 + (m4 * sapL + k4 * vv);               \
        oP += sp##q * r4;                                         \
        oL += sl##q * r4;                                         \
    }
#define COMPUTE(sl, tt) {                                                    \
        const unsigned char* sb = (const unsigned char*)ring + (sl) * 2048;  \
        const f32x4* sRr = (const f32x4*)(sb);                               \
        const f32x4* sDr = (const f32x4*)(sb + 256);                         \
        const f32x4* sKr = (const f32x4*)(sb + 512);                         \
        const f32x4* sKKr = (const f32x4*)(sb + 768);                        \
        const f32x4* sMBr = (const f32x4*)(sb + 1024);                       \
        const float* sVr = (const float*)(sb + 1280);                        \
        f32x4 pacc = {0.f, 0.f, 0.f, 0.f};                                   \
        f32x4 lacc = {0.f, 0.f, 0.f, 0.f};                                   \
        FOR16(PA)                                                            \
        const float sapP = (pacc.x + pacc.y) + (pacc.z + pacc.w);            \
        const float sapL = (lacc.x + lacc.y) + (lacc.z + lacc.w);            \
        const float vv = sVr[lane];                                          \
        f32x4 oP = {0.f, 0.f, 0.f, 0.f};                                     \
        f32x4 oL = {0.f, 0.f, 0.f, 0.f};                                     \
        FOR16(PB)                                                            \
        zbuf[(size_t)(tt) * D_ + hb + lane] = (oP.x + oP.y) + (oP.z + oP.w); \
        olbuf[(size_t)(tt) * D_ + hb + lane] = (oL.x + oL.y) + (oL.z + oL.w); }

    // prologue: 4-deep register pipeline; slot0 primed with t0
    LOADQ(r0a, r0b, t0)
    LOADQ(r1a, r1b, t0 + 1)
    LOADQ(r2a, r2b, t0 + 2)
    LOADQ(r3a, r3b, t0 + 3)
    WRITEQ(0, r0a, r0b)

    for (int t = t0; t < t0 + CLEN; t += 4) {
        WRITEQ(1, r1a, r1b)                                    // data t+1
        LOADQ(r0a, r0b, (t + 4 > tend ? tend : t + 4))
        COMPUTE(0, t)
        WRITEQ(0, r2a, r2b)                                    // data t+2
        LOADQ(r1a, r1b, (t + 5 > tend ? tend : t + 5))
        COMPUTE(1, t + 1)
        WRITEQ(1, r3a, r3b)                                    // data t+3
        LOADQ(r2a, r2b, (t + 6 > tend ? tend : t + 6))
        COMPUTE(0, t + 2)
        WRITEQ(0, r0a, r0b)                                    // data t+4
        LOADQ(r3a, r3b, (t + 7 > tend ? tend : t + 7))
        COMPUTE(1, t + 3)
    }
#undef COMPUTE
#undef PB
#undef PA
#undef WRITEQ
#undef LOADQ

    const size_t base = ((size_t)c * 16 + h) * 4096 + (size_t)lane * 64;
#define STP(q) *(f32x4*)(Pbuf + base + 4 * q) = sp##q;
    FOR16(STP)
#undef STP
#define STL(q) *(f32x4*)(Lbuf + base + 4 * q) = sl##q;
    FOR16(STL)
#undef STL
}

// ---------------------------------------------------------------------------
// Serial chunk combine: S_{c+1} = S_c @ P_c + L_c, S_0 = state_in.
// ---------------------------------------------------------------------------
__global__ __launch_bounds__(256) void scan_combine(
    const float* __restrict__ state_in, const float* __restrict__ Pbuf,
    const float* __restrict__ Lbuf, float* __restrict__ SstT, float* __restrict__ state_out) {
    const int h = blockIdx.x >> 2, rg = blockIdx.x & 3;
    const int tid = threadIdx.x;
    const int i = tid >> 4, j4 = (tid & 15) << 2;
    const int gi = rg * 16 + i;
    __shared__ float Sl[16][68];
    __shared__ float Pl[64][68];

    float4 sv = *(const float4*)(state_in + (size_t)h * 4096 + gi * 64 + j4);
    *(float4*)&Sl[i][j4] = sv;
    __syncthreads();

    for (int c = 0; c < NCHUNK; c++) {
        const size_t cb = ((size_t)c * 16 + h) * 4096;
        float4 scur = *(const float4*)&Sl[i][j4];
        SstT[cb + (size_t)(j4 + 0) * 64 + gi] = scur.x;
        SstT[cb + (size_t)(j4 + 1) * 64 + gi] = scur.y;
        SstT[cb + (size_t)(j4 + 2) * 64 + gi] = scur.z;
        SstT[cb + (size_t)(j4 + 3) * 64 + gi] = scur.w;
#pragma unroll
        for (int q = 0; q < 4; q++) {
            const int pr = (tid >> 4) + q * 16;
            *(float4*)&Pl[pr][j4] = *(const float4*)(Pbuf + cb + (size_t)pr * 64 + j4);
        }
        __syncthreads();
        float4 acc = *(const float4*)(Lbuf + cb + (size_t)gi * 64 + j4);
#pragma unroll 8
        for (int m = 0; m < 64; m++) {
            const float smv = Sl[i][m];
            const float4 p4 = *(const float4*)&Pl[m][j4];
            acc.x = fmaf(smv, p4.x, acc.x);
            acc.y = fmaf(smv, p4.y, acc.y);
            acc.z = fmaf(smv, p4.z, acc.z);
            acc.w = fmaf(smv, p4.w, acc.w);
        }
        __syncthreads();
        *(float4*)&Sl[i][j4] = acc;
        __syncthreads();
    }
    *(float4*)(state_out + (size_t)h * 4096 + gi * 64 + j4) = *(const float4*)&Sl[i][j4];
}

// ---------------------------------------------------------------------------
// Fix pass: o[t] = o_local[t] + S_start_c @ z[t] (per head).
// ---------------------------------------------------------------------------
__global__ __launch_bounds__(256) void scan_fix(
    const float* __restrict__ zbuf, const float* __restrict__ olbuf,
    const float* __restrict__ SstT, float* __restrict__ o) {
    const int tg = blockIdx.x >> 4, h = blockIdx.x & 15;
    const int hb = h * N_;
    const int tid = threadIdx.x;
    const int tok = tid >> 4, i4 = (tid & 15) << 2;
    const int tbase = tg * 16;
    const int c = tbase / CLEN;
    __shared__ float zl[16][68];
    __shared__ float Sl[64][68];

    *(float4*)&zl[tok][i4] = *(const float4*)(zbuf + (size_t)(tbase + tok) * D_ + hb + i4);
    const size_t cb = ((size_t)c * 16 + h) * 4096;
#pragma unroll
    for (int q = 0; q < 4; q++) {
        const int jr = (tid >> 4) + q * 16;
        *(float4*)&Sl[jr][i4] = *(const float4*)(SstT + cb + (size_t)jr * 64 + i4);
    }
    __syncthreads();
    float4 acc = *(const float4*)(olbuf + (size_t)(tbase + tok) * D_ + hb + i4);
#pragma unroll 8
    for (int j = 0; j < 64; j++) {
        const float zv = zl[tok][j];
        const float4 p4 = *(const float4*)&Sl[j][i4];
        acc.x = fmaf(zv, p4.x, acc.x);
        acc.y = fmaf(zv, p4.y, acc.y);
        acc.z = fmaf(zv, p4.z, acc.z);
        acc.w = fmaf(zv, p4.w, acc.w);
    }
    *(float4*)(o + (size_t)(tbase + tok) * D_ + hb + i4) = acc;
}

// ---------------------------------------------------------------------------
// bonus + gate: og = bf16((o + (sum_j r*k*r_k) * v) * g).
// ---------------------------------------------------------------------------
__global__ __launch_bounds__(256) void bonus_kernel(const float* __restrict__ o,
                                                    const float* __restrict__ r,
                                                    const float* __restrict__ k,
                                                    const float* __restrict__ v,
                                                    const float* __restrict__ g,
                                                    const float* __restrict__ r_k,
                                                    ushort* __restrict__ og) {
    const int b = blockIdx.x * 4 + (threadIdx.x >> 6);
    const int t = b >> 4, h = b & 15;
    const int lane = threadIdx.x & 63;
    const size_t idx = (size_t)t * D_ + h * N_ + lane;
    float c = r[idx] * k[idx] * r_k[h * N_ + lane];
    c += __shfl_xor(c, 1);
    c += __shfl_xor(c, 2);
    c += __shfl_xor(c, 4);
    c += __shfl_xor(c, 8);
    c += __shfl_xor(c, 16);
    c += __shfl_xor(c, 32);
    const float on = o[idx] + c * v[idx];
    og[idx] = f2bf(on * g[idx]);
}

// H[t,j] = silu(Z[t,j]) * Z[t,j+4096]  (Z = merged [gate|up], [T,8192] bf16)
__global__ __launch_bounds__(256) void mulz_kernel(const ushort* __restrict__ Z,
                                                   ushort* __restrict__ Hb) {
    const int idx = blockIdx.x * 256 + threadIdx.x;  // ushort4 index over T*1024
    const int t = idx >> 10;
    const int j = (idx & 1023) << 2;
    const ushort4 zg = *(const ushort4*)(Z + (size_t)t * 8192 + j);
    const ushort4 zu = *(const ushort4*)(Z + (size_t)t * 8192 + 4096 + j);
    ushort4 o;
    float g0 = bf2f(zg.x), g1 = bf2f(zg.y), g2 = bf2f(zg.z), g3 = bf2f(zg.w);
    o.x = f2bf(g0 * sigf(g0) * bf2f(zu.x));
    o.y = f2bf(g1 * sigf(g1) * bf2f(zu.y));
    o.z = f2bf(g2 * sigf(g2) * bf2f(zu.z));
    o.w = f2bf(g3 * sigf(g3) * bf2f(zu.w));
    *(ushort4*)(Hb + (size_t)t * 4096 + j) = o;
}

// ---------------------------------------------------------------------------
extern "C" void kernel_launch(void* const* d_in, const int* in_sizes, int n_in,
                              void* d_out, int out_size, void* d_ws, size_t ws_size,
                              hipStream_t stream) {
    const float* x      = (const float*)d_in[0];
    const float* x_prev = (const float*)d_in[1];
    const float* v_first= (const float*)d_in[2];
    const float* state  = (const float*)d_in[3];
    const float* ln1_w  = (const float*)d_in[4];
    const float* ln2_w  = (const float*)d_in[5];
    const float* x_r    = (const float*)d_in[6];
    const float* x_w    = (const float*)d_in[7];
    const float* x_k    = (const float*)d_in[8];
    const float* x_v    = (const float*)d_in[9];
    const float* x_a    = (const float*)d_in[10];
    const float* x_g    = (const float*)d_in[11];
    const float* w0     = (const float*)d_in[12];
    const float* w1     = (const float*)d_in[13];
    const float* w2     = (const float*)d_in[14];
    const float* a0     = (const float*)d_in[15];
    const float* a1     = (const float*)d_in[16];
    const float* a2     = (const float*)d_in[17];
    const float* v0     = (const float*)d_in[18];
    const float* v1     = (const float*)d_in[19];
    const float* v2     = (const float*)d_in[20];
    const float* g1     = (const float*)d_in[21];
    const float* g2     = (const float*)d_in[22];
    const float* k_k    = (const float*)d_in[23];
    const float* k_a    = (const float*)d_in[24];
    const float* r_k    = (const float*)d_in[25];
    const float* R_     = (const float*)d_in[26];
    const float* K_     = (const float*)d_in[27];
    const float* V_     = (const float*)d_in[28];
    const float* O_     = (const float*)d_in[29];
    const float* gate_w = (const float*)d_in[30];
    const float* up_w   = (const float*)d_in[31];
    const float* down_w = (const float*)d_in[32];

    float* ws = (float*)d_ws;
    const size_t U = (size_t)T_ * D_;  // 2M floats (8 MB)
    // --- persistent fp32 slots (8 x 8 MB) ---
    float* u_r  = ws;           // r            (live until bonus)
    float* u_k  = ws + 1 * U;   // k            (live until bonus)
    float* u_v  = ws + 2 * U;   // v            (live until bonus)
    float* u_dc = ws + 3 * U;   // decay        (dead after pass1)  -> SstT[0:8MB]
    float* u_kk = ws + 4 * U;   // kk           (dead after pass1)  -> SstT[8:16MB] -> Opart0 -> Hbuf
    float* u_mb = ws + 5 * U;   // -kk*a        (dead after pass1)  -> obuf -> Opart1 -> Hbuf
    float* u_g  = ws + 6 * U;   // Lbuf[0:8MB] during scan; g AFTER combine (deferred GEMM)
    float* u_ao = ws + 7 * U;   // a_sig        (dead after kk)     -> Lbuf[8:16MB]
    // --- bf16 activation region XB = ws+8U..11U (24 MB) ---
    ushort* XB = (ushort*)(ws + 8 * U);
    const size_t TD = U;
    ushort* XR = XB + 0 * TD;
    ushort* XW = XB + 1 * TD;
    ushort* XK = XB + 2 * TD;
    ushort* XV = XB + 3 * TD;
    ushort* XA = XB + 4 * TD;
    ushort* XG = XB + 5 * TD;
    // --- scan overlays (NCHUNK=64: Pbuf/Lbuf/SstT are 16 MB each) ---
    float* Pbuf  = (float*)XB;         // XB[0:16MB] (XR..XV dead after pa)
    float* Lbuf  = u_g;                // ws+6U..8U (u_g free: g deferred; u_ao dead)
    float* zbuf  = ws + 10 * U;        // XB[16:24MB] (XA/XG dead after pa)
    float* olbuf = (float*)d_out;      // d_out[0:8MB] (xn dead after shift)
    float* SstT  = u_dc;               // ws+3U..5U contiguous 16 MB
    float* obuf  = u_mb;               // ws+5U (fix output; read by bonus)
    // --- late-phase overlays ---
    ushort* OG   = XB;                 // bf16 4 MB (Pbuf dead after combine)
    ushort* XM   = (ushort*)(ws + 10 * U);  // bf16 4 MB (zbuf dead after fix)
    float* Opart = ws + 4 * U;         // 2 x 8 MB (u_kk/u_mb dead; after bonus)
    ushort* Zbuf = (ushort*)ws;        // 32 MB = ws..4U (u_r..u_dc dead after bonus/fix)
    ushort* Hbuf = (ushort*)(ws + 4 * U);   // 16 MB = ws+4U..6U (Opart dead after reduce2)
    float* Dpart = ws;                 // 4 x 8 MB = ws..4U (Zbuf dead after mulz)
    // --- transposed bf16 weights ---
    ushort* WT = (ushort*)(ws + 11 * U);
    const size_t DD = (size_t)D_ * D_;
    const size_t DF = (size_t)D_ * F_;
    ushort* WTR = WT;
    ushort* WTK = WTR + DD;
    ushort* WTV = WTK + DD;
    ushort* WTO = WTV + DD;
    ushort* WTG = WTO + DD;
    ushort* WTU = WTG + DF;
    ushort* WTD = WTU + DF;
    ushort* WTw1 = WTD + DF;
    ushort* WTw2 = WTw1 + 64 * 1024;
    ushort* WTa1 = WTw2 + 64 * 1024;
    ushort* WTa2 = WTa1 + 64 * 1024;
    ushort* WTv1 = WTa2 + 64 * 1024;
    ushort* WTv2 = WTv1 + 32 * 1024;
    ushort* WTg1 = WTv2 + 32 * 1024;
    ushort* WTg2 = WTg1 + 128 * 1024;
    ushort* Lw = WTg2 + 128 * 1024;
    ushort* La = Lw + (size_t)T_ * 64;
    ushort* Lv = La + (size_t)T_ * 64;
    ushort* Lg = Lv + (size_t)T_ * 32;

    float* out_x = (float*)d_out;
    float* out_xn_last = out_x + (size_t)T_ * D_;
    float* out_state = out_xn_last + D_;

    // --- all 15 weight transposes in ONE launch ---
    TPack tp;
    int toff = 0, ti = 0;
    auto addT = [&](const float* in, ushort* out, int K, int N) {
        tp.d[ti].in = in; tp.d[ti].out = out; tp.d[ti].K = K; tp.d[ti].N = N; tp.d[ti].off = toff;
        toff += (N / 32) * (K / 32); ++ti;
    };
    addT(R_, WTR, D_, D_);
    addT(K_, WTK, D_, D_);
    addT(V_, WTV, D_, D_);
    addT(O_, WTO, D_, D_);
    addT(gate_w, WTG, D_, F_);
    addT(up_w, WTU, D_, F_);
    addT(down_w, WTD, F_, D_);
    addT(w1, WTw1, D_, 64);
    addT(w2, WTw2, 64, D_);
    addT(a1, WTa1, D_, 64);
    addT(a2, WTa2, 64, D_);
    addT(v1, WTv1, D_, 32);
    addT(v2, WTv2, 32, D_);
    addT(g1, WTg1, D_, 128);
    addT(g2, WTg2, 128, D_);
    transpose_cast_multi<<<toff, 256, 0, stream>>>(tp);

    // 1. ln1 -> xn (in d_out) + xn_last
    rmsnorm_kernel<float><<<T_, 256, 0, stream>>>(x, ln1_w, out_x, out_xn_last);
    // 2. token shift -> bf16 xr..xg
    shift_kernel<<<T_, 256, 0, stream>>>(out_x, x_prev, x_r, x_w, x_k, x_v, x_a, x_g,
                                         XR, XW, XK, XV, XA, XG);
    // 3-6. r/k/v + 4 LoRA stage-1 GEMMs in ONE launch
    auto mkmm = [](const ushort* A, const ushort* BT, float* Cf, ushort* Cb,
                   const float* res, const float* res2, const float* bias,
                   int Ntot, int K, int epi) {
        MMDesc m{A, BT, Cf, Cb, res, res2, bias, Ntot, K, epi};
        return m;
    };
    MMPack<7> pa;
    pa.d[0] = mkmm(XR, WTR, u_r, nullptr, nullptr, nullptr, nullptr, D_, D_, 0);
    pa.d[1] = mkmm(XK, WTK, u_k, nullptr, nullptr, nullptr, nullptr, D_, D_, 0);
    pa.d[2] = mkmm(XV, WTV, u_v, nullptr, nullptr, nullptr, nullptr, D_, D_, 0);
    pa.d[3] = mkmm(XW, WTw1, nullptr, Lw, nullptr, nullptr, nullptr, 64,  D_, 3);  // tanh
    pa.d[4] = mkmm(XA, WTa1, nullptr, La, nullptr, nullptr, nullptr, 64,  D_, 0);
    pa.d[5] = mkmm(XV, WTv1, nullptr, Lv, nullptr, nullptr, nullptr, 32,  D_, 0);
    pa.d[6] = mkmm(XG, WTg1, nullptr, Lg, nullptr, nullptr, nullptr, 128, D_, 4);  // sigmoid
    mfma_gemm_multi<7><<<dim3(8, 16, 7), 256, 0, stream>>>(pa);
    // 7. LoRA stage-2 fused epilogues (decay / a_sig / v-lerp). g is DEFERRED
    //    until after scan_combine so u_g can serve as Lbuf's low half.
    MMPack<3> pb;
    pb.d[0] = mkmm(Lw, WTw2, u_dc, nullptr, nullptr, nullptr, w0, D_, 64,  6);  // decay
    pb.d[1] = mkmm(La, WTa2, u_ao, nullptr, nullptr, nullptr, a0, D_, 64,  5);  // a_sig
    pb.d[2] = mkmm(Lv, WTv2, u_v,  nullptr, u_v, v_first,     v0, D_, 32,  7);  // v lerp
    mfma_gemm_multi<3><<<dim3(8, 16, 3), 256, 0, stream>>>(pb);
    // 8. kk / mb / k-mod
    kk_kernel<<<T_ * H_ / 4, 256, 0, stream>>>(u_k, u_ao, k_k, k_a, u_kk, u_mb);
    // 9. chunked scan (merged P+L, CLEN=32: 1024 blocks = 4 waves/CU)
    scan_pass1<<<NCHUNK * H_, 64, 0, stream>>>(u_r, u_dc, u_k, u_v, u_kk, u_mb,
                                               Pbuf, Lbuf, zbuf, olbuf);
    scan_combine<<<H_ * 4, 256, 0, stream>>>(state, Pbuf, Lbuf, SstT, out_state);
    // 9b. deferred g GEMM (Lbuf now dead -> u_g writable)
    mfma_gemm<float, false><<<dim3(8, 16), 256, 0, stream>>>(
        Lg, WTg2, u_g, nullptr, T_, D_, 128, 128, 0);
    scan_fix<<<(T_ / 16) * H_, 256, 0, stream>>>(zbuf, olbuf, SstT, obuf);
    // 10. bonus + gate -> OG bf16 (Pbuf dead -> XB front reusable)
    bonus_kernel<<<T_ * H_ / 4, 256, 0, stream>>>(obuf, u_r, u_k, u_v, u_g, r_k, OG);
    // 11. O-proj split-K2 -> fp32 partials at ws+4U (u_kk/u_mb dead), 256 blocks
    mfma_gemm<float, true><<<dim3(8, 16, 2), 256, 0, stream>>>(
        OG, WTO, Opart, nullptr, T_, D_, D_, 512, 0);
    // 12. fused: out_x = x + p0 + p1; ln2(out_x) -> XM bf16 (zbuf region dead)
    rmsnorm_reduce2<<<T_, 256, 0, stream>>>(x, Opart, Opart + U, ln2_w, out_x, XM);
    // 13. MLP: merged gate|up (N=8192, 1024 blocks) -> Zbuf (ws..4U dead), swiglu
    mfma_gemm<ushort, false><<<dim3(64, 16), 256, 0, stream>>>(
        XM, WTG, Zbuf, nullptr, T_, 2 * F_, D_, D_, 0);
    mulz_kernel<<<(T_ * (F_ / 4)) / 256, 256, 0, stream>>>(Zbuf, Hbuf);
    // 14. down split-K4 -> fp32 partials over dead Zbuf region (ws..4U), 512 blocks
    mfma_gemm<float, true><<<dim3(8, 16, 4), 256, 0, stream>>>(
        Hbuf, WTD, Dpart, nullptr, T_, D_, F_, 1024, 0);
    // 15. out_x += sum of 4 partials
    add4_kernel<<<(int)(U / 4 / 256), 256, 0, stream>>>(out_x, Dpart, (int)(U / 4));
}

// Round 8
// 620.137 us; speedup vs baseline: 1.0446x; 1.0446x over previous
//
#include <hip/hip_runtime.h>
#include <math.h>

// Problem constants (B=1)
#define T_ 2048
#define D_ 1024
#define H_ 16
#define N_ 64
#define F_ 4096
#define NCHUNK 64
#define CLEN 32

typedef __attribute__((ext_vector_type(8))) short bf16x8;
typedef __attribute__((ext_vector_type(4))) float f32x4;
typedef __attribute__((address_space(3))) unsigned int lds_u32_t;
typedef __attribute__((address_space(1))) const unsigned int glb_u32_t;

static __device__ __forceinline__ float sigf(float x) { return 1.0f / (1.0f + __expf(-x)); }

static __device__ __forceinline__ ushort f2bf(float f) {
    union { float f; unsigned u; } c; c.f = f;
    unsigned r = (c.u + 0x7FFFu + ((c.u >> 16) & 1u)) >> 16;
    return (ushort)r;
}
static __device__ __forceinline__ float bf2f(ushort h) {
    union { unsigned u; float f; } c; c.u = ((unsigned)h) << 16;
    return c.f;
}

static __device__ __forceinline__ void st4(float* p, float4 v) { *(float4*)p = v; }
static __device__ __forceinline__ void st4(ushort* p, float4 v) {
    ushort4 o; o.x = f2bf(v.x); o.y = f2bf(v.y); o.z = f2bf(v.z); o.w = f2bf(v.w);
    *(ushort4*)p = o;
}

// ---------------------------------------------------------------------------
// RMSNorm: one block per token row. out = w * x * rsqrt(mean(x^2)+eps)
// ---------------------------------------------------------------------------
template <typename OutT>
__global__ __launch_bounds__(256) void rmsnorm_kernel(const float* __restrict__ x,
                                                      const float* __restrict__ w,
                                                      OutT* __restrict__ out,
                                                      float* __restrict__ last) {
    const int t = blockIdx.x;
    const int tid = threadIdx.x;
    const float4* xr = (const float4*)(x + (size_t)t * D_);
    float4 v = xr[tid];
    float ss = v.x * v.x + v.y * v.y + v.z * v.z + v.w * v.w;
    ss += __shfl_xor(ss, 1);
    ss += __shfl_xor(ss, 2);
    ss += __shfl_xor(ss, 4);
    ss += __shfl_xor(ss, 8);
    ss += __shfl_xor(ss, 16);
    ss += __shfl_xor(ss, 32);
    __shared__ float red[4];
    if ((tid & 63) == 0) red[tid >> 6] = ss;
    __syncthreads();
    float tot = red[0] + red[1] + red[2] + red[3];
    float scale = rsqrtf(tot * (1.0f / (float)D_) + 1e-6f);
    float4 wv = ((const float4*)w)[tid];
    float4 o;
    o.x = wv.x * v.x * scale;
    o.y = wv.y * v.y * scale;
    o.z = wv.z * v.z * scale;
    o.w = wv.w * v.w * scale;
    st4(out + (size_t)t * D_ + tid * 4, o);
    if (last != nullptr && t == T_ - 1) ((float4*)last)[tid] = o;
}

// ---------------------------------------------------------------------------
// Fused: v = x + p0 + p1 (split-K reduce of O-proj + residual); write v to
// resid_out AND rmsnorm(v)*w -> bf16 xm.
// ---------------------------------------------------------------------------
__global__ __launch_bounds__(256) void rmsnorm_reduce2(
    const float* __restrict__ x, const float* __restrict__ p0, const float* __restrict__ p1,
    const float* __restrict__ w, float* __restrict__ resid_out, ushort* __restrict__ xm) {
    const int t = blockIdx.x;
    const int tid = threadIdx.x;
    const size_t base = (size_t)t * D_ + tid * 4;
    float4 v = *(const float4*)(x + base);
    float4 a = *(const float4*)(p0 + base);
    float4 b = *(const float4*)(p1 + base);
    v.x += a.x + b.x; v.y += a.y + b.y; v.z += a.z + b.z; v.w += a.w + b.w;
    st4(resid_out + base, v);
    float ss = v.x * v.x + v.y * v.y + v.z * v.z + v.w * v.w;
    ss += __shfl_xor(ss, 1);
    ss += __shfl_xor(ss, 2);
    ss += __shfl_xor(ss, 4);
    ss += __shfl_xor(ss, 8);
    ss += __shfl_xor(ss, 16);
    ss += __shfl_xor(ss, 32);
    __shared__ float red[4];
    if ((tid & 63) == 0) red[tid >> 6] = ss;
    __syncthreads();
    float tot = red[0] + red[1] + red[2] + red[3];
    float scale = rsqrtf(tot * (1.0f / (float)D_) + 1e-6f);
    float4 wv = ((const float4*)w)[tid];
    float4 o;
    o.x = wv.x * v.x * scale;
    o.y = wv.y * v.y * scale;
    o.z = wv.z * v.z * scale;
    o.w = wv.w * v.w * scale;
    st4(xm + base, o);
}

// out[i] += p0[i]+p1[i]+p2[i]+p3[i]  (split-K4 reduce, float4-strided)
__global__ __launch_bounds__(256) void add4_kernel(float* __restrict__ out,
                                                   const float* __restrict__ p,
                                                   int n4slice) {
    const int i = blockIdx.x * 256 + threadIdx.x;  // float4 index
    const float4* p4 = (const float4*)p;
    float4 o = ((const float4*)out)[i];
    float4 a = p4[i], b = p4[i + n4slice], c = p4[i + 2 * n4slice], d = p4[i + 3 * n4slice];
    o.x += (a.x + b.x) + (c.x + d.x);
    o.y += (a.y + b.y) + (c.y + d.y);
    o.z += (a.z + b.z) + (c.z + d.z);
    o.w += (a.w + b.w) + (c.w + d.w);
    ((float4*)out)[i] = o;
}

// ---------------------------------------------------------------------------
// Token shift -> six bf16 activation buffers (GEMM A operands).
// ---------------------------------------------------------------------------
__global__ __launch_bounds__(256) void shift_kernel(
    const float* __restrict__ xn, const float* __restrict__ x_prev,
    const float* __restrict__ cr, const float* __restrict__ cw, const float* __restrict__ ck,
    const float* __restrict__ cv, const float* __restrict__ ca, const float* __restrict__ cg,
    ushort* __restrict__ xr, ushort* __restrict__ xw, ushort* __restrict__ xk,
    ushort* __restrict__ xv, ushort* __restrict__ xa, ushort* __restrict__ xg) {
    const int i = blockIdx.x * 256 + threadIdx.x;  // float4 index over T*256
    const int t = i >> 8, j = i & 255;
    const float4* xn4 = (const float4*)xn;
    float4 cur = xn4[i];
    float4 prev = (t == 0) ? ((const float4*)x_prev)[j] : xn4[i - 256];
    float4 xx;
    xx.x = prev.x - cur.x;
    xx.y = prev.y - cur.y;
    xx.z = prev.z - cur.z;
    xx.w = prev.w - cur.w;
#define APPLY(dst, c)                                   \
    {                                                   \
        float4 cc = ((const float4*)c)[j];              \
        float4 o;                                       \
        o.x = cur.x + xx.x * cc.x;                      \
        o.y = cur.y + xx.y * cc.y;                      \
        o.z = cur.z + xx.z * cc.z;                      \
        o.w = cur.w + xx.w * cc.w;                      \
        st4(dst + (size_t)i * 4, o);                    \
    }
    APPLY(xr, cr)
    APPLY(xw, cw)
    APPLY(xk, ck)
    APPLY(xv, cv)
    APPLY(xa, ca)
    APPLY(xg, cg)
#undef APPLY
}

// ---------------------------------------------------------------------------
// Merged weight transpose + cast: all 15 weights in ONE launch.
// ---------------------------------------------------------------------------
struct TDesc { const float* in; ushort* out; int K, N, off; };
struct TPack { TDesc d[15]; };

__global__ __launch_bounds__(256) void transpose_cast_multi(TPack p) {
    __shared__ float tile[32][33];
    const int bid = blockIdx.x;
    int di = 0;
#pragma unroll
    for (int i = 1; i < 15; i++)
        if (bid >= p.d[i].off) di = i;
    const TDesc d = p.d[di];
    const int local = bid - d.off;
    const int nt = d.N >> 5;
    const int bx = local % nt, by = local / nt;
    const int tx = threadIdx.x & 31, ty = threadIdx.x >> 5;  // 32 x 8
    const int n0 = bx * 32, k0 = by * 32;
#pragma unroll
    for (int i = 0; i < 4; i++)
        tile[ty + i * 8][tx] = d.in[(size_t)(k0 + ty + i * 8) * d.N + n0 + tx];
    __syncthreads();
#pragma unroll
    for (int i = 0; i < 4; i++)
        d.out[(size_t)(n0 + ty + i * 8) * d.K + k0 + tx] = f2bf(tile[tx][ty + i * 8]);
}

// ---------------------------------------------------------------------------
// bf16 MFMA GEMM, 2-phase double-buffered global_load_lds pipeline.
// 128x128 tile, 4 waves 2x2, BK=32. PARTIAL=true: split-K slice z writes fp32
// partials at C + z*M*Ntot. Grids of exactly 8x16 (per z) get a 4x4-supertile
// XCD swizzle. epi: 0 none, 1 += res.
// ---------------------------------------------------------------------------
template <typename OutT, bool PARTIAL>
__global__ __launch_bounds__(256) void mfma_gemm(
    const ushort* __restrict__ A, const ushort* __restrict__ BT, OutT* __restrict__ C,
    const float* res, int M, int Ntot, int K, int klen, int epi) {
    __shared__ ushort As[2][128 * 32];
    __shared__ ushort Bs[2][128 * 32];
    const int tid = threadIdx.x;
    const int wave = tid >> 6, lane = tid & 63;
    const int wr = wave >> 1, wc = wave & 1;
    const int lrow = lane & 15, quad = lane >> 4;
    int bx = blockIdx.x, by = blockIdx.y;
    if (gridDim.x == 8 && gridDim.y == 16) {
        const int bid = by * 8 + bx;
        const int k = bid & 7, i = bid >> 3;
        bx = ((k & 1) << 2) + (i & 3);
        by = ((k >> 1) << 2) + (i >> 2);
    }
    const int m0 = by * 128, n0 = bx * 128;
    const int kbase = blockIdx.z * klen;
    const int srow = lane >> 2;
    const int scol = (lane & 3) << 3;

    f32x4 acc[4][4] = {};

    auto stage = [&](int buf, int kk) {
#pragma unroll
        for (int j = 0; j < 2; j++) {
            const int chunk = 2 * wave + j;  // 0..7
            const ushort* ga = A + (size_t)(m0 + chunk * 16 + srow) * K + kk + scol;
            __builtin_amdgcn_global_load_lds((glb_u32_t*)ga,
                                             (lds_u32_t*)&As[buf][chunk * 512], 16, 0, 0);
            const int brow = n0 + chunk * 16 + srow;
            if (brow < Ntot) {
                const ushort* gb = BT + (size_t)brow * K + kk + scol;
                __builtin_amdgcn_global_load_lds((glb_u32_t*)gb,
                                                 (lds_u32_t*)&Bs[buf][chunk * 512], 16, 0, 0);
            }
        }
    };

    stage(0, kbase);
    __syncthreads();
    int cur = 0;
    for (int k0 = kbase; k0 < kbase + klen; k0 += 32) {
        if (k0 + 32 < kbase + klen) stage(cur ^ 1, k0 + 32);
        bf16x8 af[4], bfr[4];
#pragma unroll
        for (int mi = 0; mi < 4; mi++)
            af[mi] = *(const bf16x8*)&As[cur][(wr * 64 + mi * 16 + lrow) * 32 + quad * 8];
#pragma unroll
        for (int ni = 0; ni < 4; ni++)
            bfr[ni] = *(const bf16x8*)&Bs[cur][(wc * 64 + ni * 16 + lrow) * 32 + quad * 8];
#pragma unroll
        for (int mi = 0; mi < 4; mi++)
#pragma unroll
            for (int ni = 0; ni < 4; ni++)
                acc[mi][ni] = __builtin_amdgcn_mfma_f32_16x16x32_bf16(af[mi], bfr[ni], acc[mi][ni], 0, 0, 0);
        __syncthreads();
        cur ^= 1;
    }

    const size_t zoff = PARTIAL ? (size_t)blockIdx.z * M * Ntot : 0;
#pragma unroll
    for (int mi = 0; mi < 4; mi++) {
#pragma unroll
        for (int r = 0; r < 4; r++) {
            const int row = m0 + wr * 64 + mi * 16 + quad * 4 + r;
#pragma unroll
            for (int ni = 0; ni < 4; ni++) {
                const int col = n0 + wc * 64 + ni * 16 + lrow;
                if (col < Ntot) {
                    const size_t idx = (size_t)row * Ntot + col;
                    float val = acc[mi][ni][r];
                    if constexpr (PARTIAL) {
                        ((float*)C)[idx + zoff] = val;
                    } else {
                        if (epi == 1) val += res[idx];
                        if constexpr (sizeof(OutT) == 2) C[idx] = (OutT)f2bf(val);
                        else C[idx] = (OutT)val;
                    }
                }
            }
        }
    }
}

// ---------------------------------------------------------------------------
// Multi-GEMM: z-indexed descriptors, same 2-phase pipeline. Non-atomic.
// epi: 0 none, 3 tanh, 4 sig, 5 sig(bias+v), 6 exp(-e^-.5*sig(bias+v)),
//      7 res+(res2-res)*sig(bias+v)
// ---------------------------------------------------------------------------
struct MMDesc {
    const ushort* A; const ushort* BT;
    float* Cf; ushort* Cb;
    const float* res; const float* res2; const float* bias;
    int Ntot, K, epi;
};
template <int NZ>
struct MMPack { MMDesc d[NZ]; };

template <int NZ>
__global__ __launch_bounds__(256) void mfma_gemm_multi(MMPack<NZ> p) {
    const MMDesc d = p.d[blockIdx.z];
    const int n0 = blockIdx.x * 128;
    if (n0 >= d.Ntot) return;  // uniform across block; no barrier crossed yet
    __shared__ ushort As[2][128 * 32];
    __shared__ ushort Bs[2][128 * 32];
    const int tid = threadIdx.x;
    const int wave = tid >> 6, lane = tid & 63;
    const int wr = wave >> 1, wc = wave & 1;
    const int lrow = lane & 15, quad = lane >> 4;
    const int m0 = blockIdx.y * 128;
    const int srow = lane >> 2;
    const int scol = (lane & 3) << 3;
    const int K = d.K, Ntot = d.Ntot;

    f32x4 acc[4][4] = {};

    auto stage = [&](int buf, int kk) {
#pragma unroll
        for (int j = 0; j < 2; j++) {
            const int chunk = 2 * wave + j;
            const ushort* ga = d.A + (size_t)(m0 + chunk * 16 + srow) * K + kk + scol;
            __builtin_amdgcn_global_load_lds((glb_u32_t*)ga,
                                             (lds_u32_t*)&As[buf][chunk * 512], 16, 0, 0);
            const int brow = n0 + chunk * 16 + srow;
            if (brow < Ntot) {
                const ushort* gb = d.BT + (size_t)brow * K + kk + scol;
                __builtin_amdgcn_global_load_lds((glb_u32_t*)gb,
                                                 (lds_u32_t*)&Bs[buf][chunk * 512], 16, 0, 0);
            }
        }
    };

    stage(0, 0);
    __syncthreads();
    int cur = 0;
    for (int k0 = 0; k0 < K; k0 += 32) {
        if (k0 + 32 < K) stage(cur ^ 1, k0 + 32);
        bf16x8 af[4], bfr[4];
#pragma unroll
        for (int mi = 0; mi < 4; mi++)
            af[mi] = *(const bf16x8*)&As[cur][(wr * 64 + mi * 16 + lrow) * 32 + quad * 8];
#pragma unroll
        for (int ni = 0; ni < 4; ni++)
            bfr[ni] = *(const bf16x8*)&Bs[cur][(wc * 64 + ni * 16 + lrow) * 32 + quad * 8];
#pragma unroll
        for (int mi = 0; mi < 4; mi++)
#pragma unroll
            for (int ni = 0; ni < 4; ni++)
                acc[mi][ni] = __builtin_amdgcn_mfma_f32_16x16x32_bf16(af[mi], bfr[ni], acc[mi][ni], 0, 0, 0);
        __syncthreads();
        cur ^= 1;
    }

#pragma unroll
    for (int mi = 0; mi < 4; mi++) {
#pragma unroll
        for (int r = 0; r < 4; r++) {
            const int row = m0 + wr * 64 + mi * 16 + quad * 4 + r;
#pragma unroll
            for (int ni = 0; ni < 4; ni++) {
                const int col = n0 + wc * 64 + ni * 16 + lrow;
                if (col < Ntot) {
                    const size_t idx = (size_t)row * Ntot + col;
                    float val = acc[mi][ni][r];
                    switch (d.epi) {
                        case 3: val = tanhf(val); break;
                        case 4: val = sigf(val); break;
                        case 5: val = sigf(d.bias[col] + val); break;
                        case 6: val = __expf(-0.60653065971263342f * sigf(d.bias[col] + val)); break;
                        case 7: {
                            float vr = d.res[idx];
                            val = vr + (d.res2[idx] - vr) * sigf(d.bias[col] + val);
                        } break;
                        default: break;
                    }
                    if (d.Cb) d.Cb[idx] = f2bf(val);
                    else d.Cf[idx] = val;
                }
            }
        }
    }
}

// ---------------------------------------------------------------------------
// kk = normalize_per_head(k * k_k); mb = -kk*a_sig; k *= (1+(a-1)*k_a).
// ---------------------------------------------------------------------------
__global__ __launch_bounds__(256) void kk_kernel(float* __restrict__ k,
                                                 const float* __restrict__ a_sig,
                                                 const float* __restrict__ k_k,
                                                 const float* __restrict__ k_a,
                                                 float* __restrict__ kk,
                                                 float* __restrict__ mb) {
    const int b = blockIdx.x * 4 + (threadIdx.x >> 6);
    const int t = b >> 4, h = b & 15;
    const int lane = threadIdx.x & 63;
    const size_t idx = (size_t)t * D_ + h * N_ + lane;
    const int wi = h * N_ + lane;
    const float kraw = k[idx];
    const float kv = kraw * k_k[wi];
    float ss = kv * kv;
    ss += __shfl_xor(ss, 1);
    ss += __shfl_xor(ss, 2);
    ss += __shfl_xor(ss, 4);
    ss += __shfl_xor(ss, 8);
    ss += __shfl_xor(ss, 16);
    ss += __shfl_xor(ss, 32);
    const float nrm = fmaxf(sqrtf(ss), 1e-12f);
    const float kkn = kv / nrm;
    kk[idx] = kkn;
    mb[idx] = -kkn * a_sig[idx];
    k[idx] = kraw * (1.0f + (a_sig[idx] - 1.0f) * k_a[wi]);
}

// ---------------------------------------------------------------------------
// Chunked scan pass 1, MERGED P+L roles, CLEN=32 / NCHUNK=64 (unchanged from
// R7 -- measured ~58us, at the per-CU LDS-broadcast-issue limit).
// ---------------------------------------------------------------------------
#define FOR16(M) M(0) M(1) M(2) M(3) M(4) M(5) M(6) M(7) \
                 M(8) M(9) M(10) M(11) M(12) M(13) M(14) M(15)

__global__ __launch_bounds__(64, 1) void scan_pass1(
    const float* __restrict__ gR, const float* __restrict__ gD, const float* __restrict__ gK,
    const float* __restrict__ gV, const float* __restrict__ gKK, const float* __restrict__ gMB,
    float* __restrict__ Pbuf, float* __restrict__ Lbuf,
    float* __restrict__ zbuf, float* __restrict__ olbuf) {
    const int bid = blockIdx.x;          // 0..NCHUNK*H-1
    const int h = bid & 15;
    const int c = bid >> 4;
    const int lane = threadIdx.x;        // row index
    const int hb = h * N_;
    const int t0 = c * CLEN;
    const int tend = t0 + CLEN - 1;

    __shared__ __align__(16) unsigned char ring[2 * 2048];

    const int rsel = lane >> 4;
    const int sub4 = (lane & 15) << 2;
    const float* p1 = (rsel == 0 ? gR : rsel == 1 ? gD : rsel == 2 ? gK : gKK)
                      + (size_t)t0 * D_ + hb + sub4;
    const float* p2 = (rsel == 1 ? gV : gMB) + (size_t)t0 * D_ + hb + sub4;

    // P state: identity rows; L state: zero.
#define DECLP(q) f32x4 sp##q = {(lane == 4 * q + 0) ? 1.0f : 0.0f, \
                                (lane == 4 * q + 1) ? 1.0f : 0.0f, \
                                (lane == 4 * q + 2) ? 1.0f : 0.0f, \
                                (lane == 4 * q + 3) ? 1.0f : 0.0f};
    FOR16(DECLP)
#undef DECLP
#define DECLL(q) f32x4 sl##q = {0.f, 0.f, 0.f, 0.f};
    FOR16(DECLL)
#undef DECLL

    float4 r0a, r0b, r1a, r1b, r2a, r2b, r3a, r3b;

#define LOADQ(qa, qb, tt) {                                                  \
        const size_t _adv = (size_t)((tt) - t0) * D_;                        \
        qa = *(const float4*)(p1 + _adv);                                    \
        qb = *(const float4*)(p2 + _adv); }
#define WRITEQ(sl, qa, qb) {                                                 \
        *(float4*)(ring + (sl) * 2048 + lane * 16) = qa;                     \
        *(float4*)(ring + (sl) * 2048 + 1024 + lane * 16) = qb; }
#define PA(q) { const f32x4 kk4 = sKKr[q];                                   \
        pacc += sp##q * kk4; lacc += sl##q * kk4; }
#define PB(q) {                                                   \
        const f32x4 d4 = sDr[q];                                  \
        const f32x4 k4 = sKr[q];                                  \
        const f32x4 m4 = sMBr[q];                                 \
        const f32x4 r4 = sRr[q];                                  \
        sp##q = sp##q * d4 + m4 * sapP;                           \
        sl##q = sl##q * d4 + (m4 * sapL + k4 * vv);               \
        oP += sp##q * r4;                                         \
        oL += sl##q * r4;                                         \
    }
#define COMPUTE(sl, tt) {                                                    \
        const unsigned char* sb = (const unsigned char*)ring + (sl) * 2048;  \
        const f32x4* sRr = (const f32x4*)(sb);                               \
        const f32x4* sDr = (const f32x4*)(sb + 256);                         \
        const f32x4* sKr = (const f32x4*)(sb + 512);                         \
        const f32x4* sKKr = (const f32x4*)(sb + 768);                        \
        const f32x4* sMBr = (const f32x4*)(sb + 1024);                       \
        const float* sVr = (const float*)(sb + 1280);                        \
        f32x4 pacc = {0.f, 0.f, 0.f, 0.f};                                   \
        f32x4 lacc = {0.f, 0.f, 0.f, 0.f};                                   \
        FOR16(PA)                                                            \
        const float sapP = (pacc.x + pacc.y) + (pacc.z + pacc.w);            \
        const float sapL = (lacc.x + lacc.y) + (lacc.z + lacc.w);            \
        const float vv = sVr[lane];                                          \
        f32x4 oP = {0.f, 0.f, 0.f, 0.f};                                     \
        f32x4 oL = {0.f, 0.f, 0.f, 0.f};                                     \
        FOR16(PB)                                                            \
        zbuf[(size_t)(tt) * D_ + hb + lane] = (oP.x + oP.y) + (oP.z + oP.w); \
        olbuf[(size_t)(tt) * D_ + hb + lane] = (oL.x + oL.y) + (oL.z + oL.w); }

    // prologue: 4-deep register pipeline; slot0 primed with t0
    LOADQ(r0a, r0b, t0)
    LOADQ(r1a, r1b, t0 + 1)
    LOADQ(r2a, r2b, t0 + 2)
    LOADQ(r3a, r3b, t0 + 3)
    WRITEQ(0, r0a, r0b)

    for (int t = t0; t < t0 + CLEN; t += 4) {
        WRITEQ(1, r1a, r1b)                                    // data t+1
        LOADQ(r0a, r0b, (t + 4 > tend ? tend : t + 4))
        COMPUTE(0, t)
        WRITEQ(0, r2a, r2b)                                    // data t+2
        LOADQ(r1a, r1b, (t + 5 > tend ? tend : t + 5))
        COMPUTE(1, t + 1)
        WRITEQ(1, r3a, r3b)                                    // data t+3
        LOADQ(r2a, r2b, (t + 6 > tend ? tend : t + 6))
        COMPUTE(0, t + 2)
        WRITEQ(0, r0a, r0b)                                    // data t+4
        LOADQ(r3a, r3b, (t + 7 > tend ? tend : t + 7))
        COMPUTE(1, t + 3)
    }
#undef COMPUTE
#undef PB
#undef PA
#undef WRITEQ
#undef LOADQ

    const size_t base = ((size_t)c * 16 + h) * 4096 + (size_t)lane * 64;
#define STP(q) *(f32x4*)(Pbuf + base + 4 * q) = sp##q;
    FOR16(STP)
#undef STP
#define STL(q) *(f32x4*)(Lbuf + base + 4 * q) = sl##q;
    FOR16(STL)
#undef STL
}

// ---------------------------------------------------------------------------
// Parallel pair merge: (P',L') for super-chunk j = (P_{2j}@P_{2j+1},
// L_{2j}@P_{2j+1} + L_{2j+1}), written IN-PLACE into the odd slots (2j+1).
// Even slots preserved for the odd-fill pass. All global reads of the pair
// are staged into LDS (or per-thread exclusive) BEFORE any write -> no race.
// One 64-thread block per (h,j); thread computes a 4x16 tile of both outputs.
// ---------------------------------------------------------------------------
__global__ __launch_bounds__(64) void merge_pairs(float* __restrict__ Pbuf,
                                                  float* __restrict__ Lbuf) {
    const int h = blockIdx.x & 15, j = blockIdx.x >> 4;  // j 0..31
    const int t = threadIdx.x;
    __shared__ float PaT[64][65];  // [m][row] transposed (conflict-free row reads)
    __shared__ float LaT[64][65];
    __shared__ float Pb[64][68];   // [m][col] natural (float4 col reads)
    const size_t ca = ((size_t)(2 * j) * 16 + h) * 4096;
    const size_t cb = ((size_t)(2 * j + 1) * 16 + h) * 4096;
#pragma unroll
    for (int q = 0; q < 16; q++) {
        const int idx = t + q * 64;  // float4 index 0..1023
        const int r = idx >> 4, c4 = (idx & 15) << 2;
        float4 pa = *(const float4*)(Pbuf + ca + (size_t)r * 64 + c4);
        float4 la = *(const float4*)(Lbuf + ca + (size_t)r * 64 + c4);
        float4 pb = *(const float4*)(Pbuf + cb + (size_t)r * 64 + c4);
        PaT[c4 + 0][r] = pa.x; PaT[c4 + 1][r] = pa.y;
        PaT[c4 + 2][r] = pa.z; PaT[c4 + 3][r] = pa.w;
        LaT[c4 + 0][r] = la.x; LaT[c4 + 1][r] = la.y;
        LaT[c4 + 2][r] = la.z; LaT[c4 + 3][r] = la.w;
        *(float4*)&Pb[r][c4] = pb;
    }
    __syncthreads();
    const int cg = (t & 3) << 4;  // col base 0/16/32/48
    const int r0 = (t >> 2) << 2; // row base 0..60 step 4
    float4 accP[4][4] = {};
    float4 accL[4][4];
#pragma unroll
    for (int rr = 0; rr < 4; rr++)
#pragma unroll
        for (int e = 0; e < 4; e++)
            accL[rr][e] = *(const float4*)(Lbuf + cb + (size_t)(r0 + rr) * 64 + cg + 4 * e);
    for (int m = 0; m < 64; m++) {
        float4 pb4[4];
#pragma unroll
        for (int e = 0; e < 4; e++) pb4[e] = *(const float4*)&Pb[m][cg + 4 * e];
#pragma unroll
        for (int rr = 0; rr < 4; rr++) {
            const float pa = PaT[m][r0 + rr];
            const float la = LaT[m][r0 + rr];
#pragma unroll
            for (int e = 0; e < 4; e++) {
                accP[rr][e].x = fmaf(pa, pb4[e].x, accP[rr][e].x);
                accP[rr][e].y = fmaf(pa, pb4[e].y, accP[rr][e].y);
                accP[rr][e].z = fmaf(pa, pb4[e].z, accP[rr][e].z);
                accP[rr][e].w = fmaf(pa, pb4[e].w, accP[rr][e].w);
                accL[rr][e].x = fmaf(la, pb4[e].x, accL[rr][e].x);
                accL[rr][e].y = fmaf(la, pb4[e].y, accL[rr][e].y);
                accL[rr][e].z = fmaf(la, pb4[e].z, accL[rr][e].z);
                accL[rr][e].w = fmaf(la, pb4[e].w, accL[rr][e].w);
            }
        }
    }
#pragma unroll
    for (int rr = 0; rr < 4; rr++)
#pragma unroll
        for (int e = 0; e < 4; e++) {
            *(float4*)(Pbuf + cb + (size_t)(r0 + rr) * 64 + cg + 4 * e) = accP[rr][e];
            *(float4*)(Lbuf + cb + (size_t)(r0 + rr) * 64 + cg + 4 * e) = accL[rr][e];
        }
}

// ---------------------------------------------------------------------------
// Serial combine over 32 SUPER-chunks (odd slots hold merged (P',L')).
// Register prefetch double-buffer: next step's P/L global loads issue before
// the current 64-FMA loop -> load latency hides under compute. Writes SstT
// at EVEN chunk boundaries (start of chunk 2c).
// ---------------------------------------------------------------------------
__global__ __launch_bounds__(256) void scan_combine(
    const float* __restrict__ state_in, const float* __restrict__ Pbuf,
    const float* __restrict__ Lbuf, float* __restrict__ SstT, float* __restrict__ state_out) {
    const int h = blockIdx.x >> 2, rg = blockIdx.x & 3;
    const int tid = threadIdx.x;
    const int i = tid >> 4, j4 = (tid & 15) << 2;
    const int gi = rg * 16 + i;
    __shared__ float Sl[16][68];
    __shared__ float Pl[64][68];

    float4 sv = *(const float4*)(state_in + (size_t)h * 4096 + gi * 64 + j4);
    *(float4*)&Sl[i][j4] = sv;

    float4 rp0, rp1, rp2, rp3, rl;
    {
        const size_t cb = ((size_t)1 * 16 + h) * 4096;  // super-chunk 0 = slot 1
        rp0 = *(const float4*)(Pbuf + cb + (size_t)(i +  0) * 64 + j4);
        rp1 = *(const float4*)(Pbuf + cb + (size_t)(i + 16) * 64 + j4);
        rp2 = *(const float4*)(Pbuf + cb + (size_t)(i + 32) * 64 + j4);
        rp3 = *(const float4*)(Pbuf + cb + (size_t)(i + 48) * 64 + j4);
        rl  = *(const float4*)(Lbuf + cb + (size_t)gi * 64 + j4);
    }
    __syncthreads();

    for (int c = 0; c < NCHUNK / 2; c++) {
        *(float4*)&Pl[i +  0][j4] = rp0;
        *(float4*)&Pl[i + 16][j4] = rp1;
        *(float4*)&Pl[i + 32][j4] = rp2;
        *(float4*)&Pl[i + 48][j4] = rp3;
        float4 acc = rl;
        const size_t so = ((size_t)(2 * c) * 16 + h) * 4096;
        float4 scur = *(const float4*)&Sl[i][j4];
        SstT[so + (size_t)(j4 + 0) * 64 + gi] = scur.x;
        SstT[so + (size_t)(j4 + 1) * 64 + gi] = scur.y;
        SstT[so + (size_t)(j4 + 2) * 64 + gi] = scur.z;
        SstT[so + (size_t)(j4 + 3) * 64 + gi] = scur.w;
        __syncthreads();  // Pl visible to all waves
        if (c + 1 < NCHUNK / 2) {  // prefetch next super-chunk (slot 2c+3)
            const size_t cb = ((size_t)(2 * c + 3) * 16 + h) * 4096;
            rp0 = *(const float4*)(Pbuf + cb + (size_t)(i +  0) * 64 + j4);
            rp1 = *(const float4*)(Pbuf + cb + (size_t)(i + 16) * 64 + j4);
            rp2 = *(const float4*)(Pbuf + cb + (size_t)(i + 32) * 64 + j4);
            rp3 = *(const float4*)(Pbuf + cb + (size_t)(i + 48) * 64 + j4);
            rl  = *(const float4*)(Lbuf + cb + (size_t)gi * 64 + j4);
        }
#pragma unroll 8
        for (int m = 0; m < 64; m++) {
            const float smv = Sl[i][m];
            const float4 p4 = *(const float4*)&Pl[m][j4];
            acc.x = fmaf(smv, p4.x, acc.x);
            acc.y = fmaf(smv, p4.y, acc.y);
            acc.z = fmaf(smv, p4.z, acc.z);
            acc.w = fmaf(smv, p4.w, acc.w);
        }
        __syncthreads();  // all waves done reading Pl before next overwrite
        *(float4*)&Sl[i][j4] = acc;  // Sl rows are wave-private: no extra sync
    }
    *(float4*)(state_out + (size_t)h * 4096 + gi * 64 + j4) = *(const float4*)&Sl[i][j4];
}

// ---------------------------------------------------------------------------
// Odd-fill: S_{2j+1} = S_{2j} @ P_{2j} + L_{2j} (even slots, preserved).
// Fully parallel: 2048 blocks. SstT stored transposed (col*64+row).
// ---------------------------------------------------------------------------
__global__ __launch_bounds__(256) void scan_oddfill(
    const float* __restrict__ Pbuf, const float* __restrict__ Lbuf,
    float* __restrict__ SstT) {
    const int b = blockIdx.x;
    const int rg = b & 3, h = (b >> 2) & 15, j = b >> 6;  // j 0..31
    const int tid = threadIdx.x;
    const int i = tid >> 4, j4 = (tid & 15) << 2;
    const int gi = rg * 16 + i;
    __shared__ float Sl[16][68];
    __shared__ float Pl[64][68];
    const size_t ce = ((size_t)(2 * j) * 16 + h) * 4096;
    const size_t co = ((size_t)(2 * j + 1) * 16 + h) * 4096;
    {
        float4 s;
        s.x = SstT[ce + (size_t)(j4 + 0) * 64 + gi];
        s.y = SstT[ce + (size_t)(j4 + 1) * 64 + gi];
        s.z = SstT[ce + (size_t)(j4 + 2) * 64 + gi];
        s.w = SstT[ce + (size_t)(j4 + 3) * 64 + gi];
        *(float4*)&Sl[i][j4] = s;
    }
#pragma unroll
    for (int q = 0; q < 4; q++) {
        const int prq = i + q * 16;
        *(float4*)&Pl[prq][j4] = *(const float4*)(Pbuf + ce + (size_t)prq * 64 + j4);
    }
    __syncthreads();
    float4 acc = *(const float4*)(Lbuf + ce + (size_t)gi * 64 + j4);
#pragma unroll 8
    for (int m = 0; m < 64; m++) {
        const float smv = Sl[i][m];
        const float4 p4 = *(const float4*)&Pl[m][j4];
        acc.x = fmaf(smv, p4.x, acc.x);
        acc.y = fmaf(smv, p4.y, acc.y);
        acc.z = fmaf(smv, p4.z, acc.z);
        acc.w = fmaf(smv, p4.w, acc.w);
    }
    SstT[co + (size_t)(j4 + 0) * 64 + gi] = acc.x;
    SstT[co + (size_t)(j4 + 1) * 64 + gi] = acc.y;
    SstT[co + (size_t)(j4 + 2) * 64 + gi] = acc.z;
    SstT[co + (size_t)(j4 + 3) * 64 + gi] = acc.w;
}

// ---------------------------------------------------------------------------
// Fix pass: o[t] = o_local[t] + S_start_c @ z[t] (per head).
// ---------------------------------------------------------------------------
__global__ __launch_bounds__(256) void scan_fix(
    const float* __restrict__ zbuf, const float* __restrict__ olbuf,
    const float* __restrict__ SstT, float* __restrict__ o) {
    const int tg = blockIdx.x >> 4, h = blockIdx.x & 15;
    const int hb = h * N_;
    const int tid = threadIdx.x;
    const int tok = tid >> 4, i4 = (tid & 15) << 2;
    const int tbase = tg * 16;
    const int c = tbase / CLEN;
    __shared__ float zl[16][68];
    __shared__ float Sl[64][68];

    *(float4*)&zl[tok][i4] = *(const float4*)(zbuf + (size_t)(tbase + tok) * D_ + hb + i4);
    const size_t cb = ((size_t)c * 16 + h) * 4096;
#pragma unroll
    for (int q = 0; q < 4; q++) {
        const int jr = (tid >> 4) + q * 16;
        *(float4*)&Sl[jr][i4] = *(const float4*)(SstT + cb + (size_t)jr * 64 + i4);
    }
    __syncthreads();
    float4 acc = *(const float4*)(olbuf + (size_t)(tbase + tok) * D_ + hb + i4);
#pragma unroll 8
    for (int j = 0; j < 64; j++) {
        const float zv = zl[tok][j];
        const float4 p4 = *(const float4*)&Sl[j][i4];
        acc.x = fmaf(zv, p4.x, acc.x);
        acc.y = fmaf(zv, p4.y, acc.y);
        acc.z = fmaf(zv, p4.z, acc.z);
        acc.w = fmaf(zv, p4.w, acc.w);
    }
    *(float4*)(o + (size_t)(tbase + tok) * D_ + hb + i4) = acc;
}

// ---------------------------------------------------------------------------
// bonus + gate: og = bf16((o + (sum_j r*k*r_k) * v) * g).
// ---------------------------------------------------------------------------
__global__ __launch_bounds__(256) void bonus_kernel(const float* __restrict__ o,
                                                    const float* __restrict__ r,
                                                    const float* __restrict__ k,
                                                    const float* __restrict__ v,
                                                    const float* __restrict__ g,
                                                    const float* __restrict__ r_k,
                                                    ushort* __restrict__ og) {
    const int b = blockIdx.x * 4 + (threadIdx.x >> 6);
    const int t = b >> 4, h = b & 15;
    const int lane = threadIdx.x & 63;
    const size_t idx = (size_t)t * D_ + h * N_ + lane;
    float c = r[idx] * k[idx] * r_k[h * N_ + lane];
    c += __shfl_xor(c, 1);
    c += __shfl_xor(c, 2);
    c += __shfl_xor(c, 4);
    c += __shfl_xor(c, 8);
    c += __shfl_xor(c, 16);
    c += __shfl_xor(c, 32);
    const float on = o[idx] + c * v[idx];
    og[idx] = f2bf(on * g[idx]);
}

// H[t,j] = silu(Z[t,j]) * Z[t,j+4096]  (Z = merged [gate|up], [T,8192] bf16)
__global__ __launch_bounds__(256) void mulz_kernel(const ushort* __restrict__ Z,
                                                   ushort* __restrict__ Hb) {
    const int idx = blockIdx.x * 256 + threadIdx.x;  // ushort4 index over T*1024
    const int t = idx >> 10;
    const int j = (idx & 1023) << 2;
    const ushort4 zg = *(const ushort4*)(Z + (size_t)t * 8192 + j);
    const ushort4 zu = *(const ushort4*)(Z + (size_t)t * 8192 + 4096 + j);
    ushort4 o;
    float g0 = bf2f(zg.x), g1 = bf2f(zg.y), g2 = bf2f(zg.z), g3 = bf2f(zg.w);
    o.x = f2bf(g0 * sigf(g0) * bf2f(zu.x));
    o.y = f2bf(g1 * sigf(g1) * bf2f(zu.y));
    o.z = f2bf(g2 * sigf(g2) * bf2f(zu.z));
    o.w = f2bf(g3 * sigf(g3) * bf2f(zu.w));
    *(ushort4*)(Hb + (size_t)t * 4096 + j) = o;
}

// ---------------------------------------------------------------------------
extern "C" void kernel_launch(void* const* d_in, const int* in_sizes, int n_in,
                              void* d_out, int out_size, void* d_ws, size_t ws_size,
                              hipStream_t stream) {
    const float* x      = (const float*)d_in[0];
    const float* x_prev = (const float*)d_in[1];
    const float* v_first= (const float*)d_in[2];
    const float* state  = (const float*)d_in[3];
    const float* ln1_w  = (const float*)d_in[4];
    const float* ln2_w  = (const float*)d_in[5];
    const float* x_r    = (const float*)d_in[6];
    const float* x_w    = (const float*)d_in[7];
    const float* x_k    = (const float*)d_in[8];
    const float* x_v    = (const float*)d_in[9];
    const float* x_a    = (const float*)d_in[10];
    const float* x_g    = (const float*)d_in[11];
    const float* w0     = (const float*)d_in[12];
    const float* w1     = (const float*)d_in[13];
    const float* w2     = (const float*)d_in[14];
    const float* a0     = (const float*)d_in[15];
    const float* a1     = (const float*)d_in[16];
    const float* a2     = (const float*)d_in[17];
    const float* v0     = (const float*)d_in[18];
    const float* v1     = (const float*)d_in[19];
    const float* v2     = (const float*)d_in[20];
    const float* g1     = (const float*)d_in[21];
    const float* g2     = (const float*)d_in[22];
    const float* k_k    = (const float*)d_in[23];
    const float* k_a    = (const float*)d_in[24];
    const float* r_k    = (const float*)d_in[25];
    const float* R_     = (const float*)d_in[26];
    const float* K_     = (const float*)d_in[27];
    const float* V_     = (const float*)d_in[28];
    const float* O_     = (const float*)d_in[29];
    const float* gate_w = (const float*)d_in[30];
    const float* up_w   = (const float*)d_in[31];
    const float* down_w = (const float*)d_in[32];

    float* ws = (float*)d_ws;
    const size_t U = (size_t)T_ * D_;  // 2M floats (8 MB)
    float* u_r  = ws;
    float* u_k  = ws + 1 * U;
    float* u_v  = ws + 2 * U;
    float* u_dc = ws + 3 * U;   // decay -> SstT[0:8MB]
    float* u_kk = ws + 4 * U;   // kk    -> SstT[8:16MB] -> Opart0 -> Hbuf
    float* u_mb = ws + 5 * U;   // -kk*a -> obuf -> Opart1 -> Hbuf
    float* u_g  = ws + 6 * U;   // Lbuf[0:8MB] during scan; g AFTER oddfill
    float* u_ao = ws + 7 * U;   // a_sig -> Lbuf[8:16MB]
    ushort* XB = (ushort*)(ws + 8 * U);
    const size_t TD = U;
    ushort* XR = XB + 0 * TD;
    ushort* XW = XB + 1 * TD;
    ushort* XK = XB + 2 * TD;
    ushort* XV = XB + 3 * TD;
    ushort* XA = XB + 4 * TD;
    ushort* XG = XB + 5 * TD;
    float* Pbuf  = (float*)XB;         // XB[0:16MB]
    float* Lbuf  = u_g;                // ws+6U..8U (16MB)
    float* zbuf  = ws + 10 * U;        // XB[16:24MB]
    float* olbuf = (float*)d_out;      // d_out[0:8MB]
    float* SstT  = u_dc;               // ws+3U..5U (16MB)
    float* obuf  = u_mb;               // ws+5U
    ushort* OG   = XB;                 // bf16 4 MB (Pbuf dead after oddfill)
    ushort* XM   = (ushort*)(ws + 10 * U);
    float* Opart = ws + 4 * U;         // 2 x 8 MB
    ushort* Zbuf = (ushort*)ws;        // 32 MB
    ushort* Hbuf = (ushort*)(ws + 4 * U);
    float* Dpart = ws;                 // 4 x 8 MB
    ushort* WT = (ushort*)(ws + 11 * U);
    const size_t DD = (size_t)D_ * D_;
    const size_t DF = (size_t)D_ * F_;
    ushort* WTR = WT;
    ushort* WTK = WTR + DD;
    ushort* WTV = WTK + DD;
    ushort* WTO = WTV + DD;
    ushort* WTG = WTO + DD;
    ushort* WTU = WTG + DF;
    ushort* WTD = WTU + DF;
    ushort* WTw1 = WTD + DF;
    ushort* WTw2 = WTw1 + 64 * 1024;
    ushort* WTa1 = WTw2 + 64 * 1024;
    ushort* WTa2 = WTa1 + 64 * 1024;
    ushort* WTv1 = WTa2 + 64 * 1024;
    ushort* WTv2 = WTv1 + 32 * 1024;
    ushort* WTg1 = WTv2 + 32 * 1024;
    ushort* WTg2 = WTg1 + 128 * 1024;
    ushort* Lw = WTg2 + 128 * 1024;
    ushort* La = Lw + (size_t)T_ * 64;
    ushort* Lv = La + (size_t)T_ * 64;
    ushort* Lg = Lv + (size_t)T_ * 32;

    float* out_x = (float*)d_out;
    float* out_xn_last = out_x + (size_t)T_ * D_;
    float* out_state = out_xn_last + D_;

    // --- all 15 weight transposes in ONE launch ---
    TPack tp;
    int toff = 0, ti = 0;
    auto addT = [&](const float* in, ushort* out, int K, int N) {
        tp.d[ti].in = in; tp.d[ti].out = out; tp.d[ti].K = K; tp.d[ti].N = N; tp.d[ti].off = toff;
        toff += (N / 32) * (K / 32); ++ti;
    };
    addT(R_, WTR, D_, D_);
    addT(K_, WTK, D_, D_);
    addT(V_, WTV, D_, D_);
    addT(O_, WTO, D_, D_);
    addT(gate_w, WTG, D_, F_);
    addT(up_w, WTU, D_, F_);
    addT(down_w, WTD, F_, D_);
    addT(w1, WTw1, D_, 64);
    addT(w2, WTw2, 64, D_);
    addT(a1, WTa1, D_, 64);
    addT(a2, WTa2, 64, D_);
    addT(v1, WTv1, D_, 32);
    addT(v2, WTv2, 32, D_);
    addT(g1, WTg1, D_, 128);
    addT(g2, WTg2, 128, D_);
    transpose_cast_multi<<<toff, 256, 0, stream>>>(tp);

    // 1. ln1 -> xn (in d_out) + xn_last
    rmsnorm_kernel<float><<<T_, 256, 0, stream>>>(x, ln1_w, out_x, out_xn_last);
    // 2. token shift -> bf16 xr..xg
    shift_kernel<<<T_, 256, 0, stream>>>(out_x, x_prev, x_r, x_w, x_k, x_v, x_a, x_g,
                                         XR, XW, XK, XV, XA, XG);
    // 3-6. r/k/v + 4 LoRA stage-1 GEMMs in ONE launch
    auto mkmm = [](const ushort* A, const ushort* BT, float* Cf, ushort* Cb,
                   const float* res, const float* res2, const float* bias,
                   int Ntot, int K, int epi) {
        MMDesc m{A, BT, Cf, Cb, res, res2, bias, Ntot, K, epi};
        return m;
    };
    MMPack<7> pa;
    pa.d[0] = mkmm(XR, WTR, u_r, nullptr, nullptr, nullptr, nullptr, D_, D_, 0);
    pa.d[1] = mkmm(XK, WTK, u_k, nullptr, nullptr, nullptr, nullptr, D_, D_, 0);
    pa.d[2] = mkmm(XV, WTV, u_v, nullptr, nullptr, nullptr, nullptr, D_, D_, 0);
    pa.d[3] = mkmm(XW, WTw1, nullptr, Lw, nullptr, nullptr, nullptr, 64,  D_, 3);  // tanh
    pa.d[4] = mkmm(XA, WTa1, nullptr, La, nullptr, nullptr, nullptr, 64,  D_, 0);
    pa.d[5] = mkmm(XV, WTv1, nullptr, Lv, nullptr, nullptr, nullptr, 32,  D_, 0);
    pa.d[6] = mkmm(XG, WTg1, nullptr, Lg, nullptr, nullptr, nullptr, 128, D_, 4);  // sigmoid
    mfma_gemm_multi<7><<<dim3(8, 16, 7), 256, 0, stream>>>(pa);
    // 7. LoRA stage-2 (decay / a_sig / v-lerp); g deferred (u_g = Lbuf)
    MMPack<3> pb;
    pb.d[0] = mkmm(Lw, WTw2, u_dc, nullptr, nullptr, nullptr, w0, D_, 64,  6);  // decay
    pb.d[1] = mkmm(La, WTa2, u_ao, nullptr, nullptr, nullptr, a0, D_, 64,  5);  // a_sig
    pb.d[2] = mkmm(Lv, WTv2, u_v,  nullptr, u_v, v_first,     v0, D_, 32,  7);  // v lerp
    mfma_gemm_multi<3><<<dim3(8, 16, 3), 256, 0, stream>>>(pb);
    // 8. kk / mb / k-mod
    kk_kernel<<<T_ * H_ / 4, 256, 0, stream>>>(u_k, u_ao, k_k, k_a, u_kk, u_mb);
    // 9. chunked scan: pass1 (1024 blocks) -> pair-merge -> serial-32 -> odd-fill
    scan_pass1<<<NCHUNK * H_, 64, 0, stream>>>(u_r, u_dc, u_k, u_v, u_kk, u_mb,
                                               Pbuf, Lbuf, zbuf, olbuf);
    merge_pairs<<<16 * 32, 64, 0, stream>>>(Pbuf, Lbuf);
    scan_combine<<<H_ * 4, 256, 0, stream>>>(state, Pbuf, Lbuf, SstT, out_state);
    scan_oddfill<<<16 * 32 * 4, 256, 0, stream>>>(Pbuf, Lbuf, SstT);
    // 9b. deferred g GEMM (Lbuf fully dead after oddfill -> u_g writable)
    mfma_gemm<float, false><<<dim3(8, 16), 256, 0, stream>>>(
        Lg, WTg2, u_g, nullptr, T_, D_, 128, 128, 0);
    scan_fix<<<(T_ / 16) * H_, 256, 0, stream>>>(zbuf, olbuf, SstT, obuf);
    // 10. bonus + gate -> OG bf16 (Pbuf dead -> XB front reusable)
    bonus_kernel<<<T_ * H_ / 4, 256, 0, stream>>>(obuf, u_r, u_k, u_v, u_g, r_k, OG);
    // 11. O-proj split-K2 -> fp32 partials at ws+4U, 256 blocks
    mfma_gemm<float, true><<<dim3(8, 16, 2), 256, 0, stream>>>(
        OG, WTO, Opart, nullptr, T_, D_, D_, 512, 0);
    // 12. fused: out_x = x + p0 + p1; ln2(out_x) -> XM bf16
    rmsnorm_reduce2<<<T_, 256, 0, stream>>>(x, Opart, Opart + U, ln2_w, out_x, XM);
    // 13. MLP: merged gate|up (N=8192, 1024 blocks) -> Zbuf, swiglu
    mfma_gemm<ushort, false><<<dim3(64, 16), 256, 0, stream>>>(
        XM, WTG, Zbuf, nullptr, T_, 2 * F_, D_, D_, 0);
    mulz_kernel<<<(T_ * (F_ / 4)) / 256, 256, 0, stream>>>(Zbuf, Hbuf);
    // 14. down split-K4 -> fp32 partials over dead Zbuf region, 512 blocks
    mfma_gemm<float, true><<<dim3(8, 16, 4), 256, 0, stream>>>(
        Hbuf, WTD, Dpart, nullptr, T_, D_, F_, 1024, 0);
    // 15. out_x += sum of 4 partials
    add4_kernel<<<(int)(U / 4 / 256), 256, 0, stream>>>(out_x, Dpart, (int)(U / 4));
}

// Round 9
// 612.608 us; speedup vs baseline: 1.0575x; 1.0123x over previous
//
#include <hip/hip_runtime.h>
#include <math.h>

// Problem constants (B=1)
#define T_ 2048
#define D_ 1024
#define H_ 16
#define N_ 64
#define F_ 4096
#define NCHUNK 64
#define CLEN 32

typedef __attribute__((ext_vector_type(8))) short bf16x8;
typedef __attribute__((ext_vector_type(4))) float f32x4;
typedef __attribute__((address_space(3))) unsigned int lds_u32_t;
typedef __attribute__((address_space(1))) const unsigned int glb_u32_t;

static __device__ __forceinline__ float sigf(float x) { return 1.0f / (1.0f + __expf(-x)); }

static __device__ __forceinline__ ushort f2bf(float f) {
    union { float f; unsigned u; } c; c.f = f;
    unsigned r = (c.u + 0x7FFFu + ((c.u >> 16) & 1u)) >> 16;
    return (ushort)r;
}
static __device__ __forceinline__ float bf2f(ushort h) {
    union { unsigned u; float f; } c; c.u = ((unsigned)h) << 16;
    return c.f;
}

static __device__ __forceinline__ void st4(float* p, float4 v) { *(float4*)p = v; }
static __device__ __forceinline__ void st4(ushort* p, float4 v) {
    ushort4 o; o.x = f2bf(v.x); o.y = f2bf(v.y); o.z = f2bf(v.z); o.w = f2bf(v.w);
    *(ushort4*)p = o;
}

// ---------------------------------------------------------------------------
// FUSED ln1 + token shift: block t computes rmsnorm(x[t]) AND rmsnorm(x[t-1])
// (recompute, 1KB extra load) -> xx = prev - cur -> six bf16 buffers.
// Removes the xn materialization (8MB write + 16MB read) and one dispatch.
// ---------------------------------------------------------------------------
__global__ __launch_bounds__(256) void ln_shift_kernel(
    const float* __restrict__ x, const float* __restrict__ x_prev,
    const float* __restrict__ w,
    const float* __restrict__ cr, const float* __restrict__ cw, const float* __restrict__ ck,
    const float* __restrict__ cv, const float* __restrict__ ca, const float* __restrict__ cg,
    ushort* __restrict__ xr, ushort* __restrict__ xw, ushort* __restrict__ xk,
    ushort* __restrict__ xv, ushort* __restrict__ xa, ushort* __restrict__ xg,
    float* __restrict__ last) {
    const int t = blockIdx.x;
    const int tid = threadIdx.x;
    const float4* x4 = (const float4*)x;
    float4 xc = x4[t * 256 + tid];
    float4 xp = (t == 0) ? ((const float4*)x_prev)[tid] : x4[(t - 1) * 256 + tid];
    float ssc = xc.x * xc.x + xc.y * xc.y + xc.z * xc.z + xc.w * xc.w;
    float ssp = xp.x * xp.x + xp.y * xp.y + xp.z * xp.z + xp.w * xp.w;
    ssc += __shfl_xor(ssc, 1); ssp += __shfl_xor(ssp, 1);
    ssc += __shfl_xor(ssc, 2); ssp += __shfl_xor(ssp, 2);
    ssc += __shfl_xor(ssc, 4); ssp += __shfl_xor(ssp, 4);
    ssc += __shfl_xor(ssc, 8); ssp += __shfl_xor(ssp, 8);
    ssc += __shfl_xor(ssc, 16); ssp += __shfl_xor(ssp, 16);
    ssc += __shfl_xor(ssc, 32); ssp += __shfl_xor(ssp, 32);
    __shared__ float redc[4], redp[4];
    if ((tid & 63) == 0) { redc[tid >> 6] = ssc; redp[tid >> 6] = ssp; }
    __syncthreads();
    const float totc = redc[0] + redc[1] + redc[2] + redc[3];
    const float totp = redp[0] + redp[1] + redp[2] + redp[3];
    const float sc = rsqrtf(totc * (1.0f / (float)D_) + 1e-6f);
    const float sp = rsqrtf(totp * (1.0f / (float)D_) + 1e-6f);
    float4 wv = ((const float4*)w)[tid];
    float4 cur, prev;
    cur.x = wv.x * xc.x * sc; cur.y = wv.y * xc.y * sc;
    cur.z = wv.z * xc.z * sc; cur.w = wv.w * xc.w * sc;
    if (t == 0) {
        prev = xp;  // raw x_prev per reference
    } else {
        prev.x = wv.x * xp.x * sp; prev.y = wv.y * xp.y * sp;
        prev.z = wv.z * xp.z * sp; prev.w = wv.w * xp.w * sp;
    }
    float4 xx;
    xx.x = prev.x - cur.x; xx.y = prev.y - cur.y;
    xx.z = prev.z - cur.z; xx.w = prev.w - cur.w;
    const size_t ob = (size_t)t * D_ + tid * 4;
#define APPLY(dst, c)                                   \
    {                                                   \
        float4 cc = ((const float4*)c)[tid];            \
        float4 o;                                       \
        o.x = cur.x + xx.x * cc.x;                      \
        o.y = cur.y + xx.y * cc.y;                      \
        o.z = cur.z + xx.z * cc.z;                      \
        o.w = cur.w + xx.w * cc.w;                      \
        st4(dst + ob, o);                               \
    }
    APPLY(xr, cr)
    APPLY(xw, cw)
    APPLY(xk, ck)
    APPLY(xv, cv)
    APPLY(xa, ca)
    APPLY(xg, cg)
#undef APPLY
    if (t == T_ - 1) ((float4*)last)[tid] = cur;
}

// ---------------------------------------------------------------------------
// Fused: v = x + p0 + p1 (split-K reduce of O-proj + residual); write v to
// resid_out AND rmsnorm(v)*w -> bf16 xm.
// ---------------------------------------------------------------------------
__global__ __launch_bounds__(256) void rmsnorm_reduce2(
    const float* __restrict__ x, const float* __restrict__ p0, const float* __restrict__ p1,
    const float* __restrict__ w, float* __restrict__ resid_out, ushort* __restrict__ xm) {
    const int t = blockIdx.x;
    const int tid = threadIdx.x;
    const size_t base = (size_t)t * D_ + tid * 4;
    float4 v = *(const float4*)(x + base);
    float4 a = *(const float4*)(p0 + base);
    float4 b = *(const float4*)(p1 + base);
    v.x += a.x + b.x; v.y += a.y + b.y; v.z += a.z + b.z; v.w += a.w + b.w;
    st4(resid_out + base, v);
    float ss = v.x * v.x + v.y * v.y + v.z * v.z + v.w * v.w;
    ss += __shfl_xor(ss, 1);
    ss += __shfl_xor(ss, 2);
    ss += __shfl_xor(ss, 4);
    ss += __shfl_xor(ss, 8);
    ss += __shfl_xor(ss, 16);
    ss += __shfl_xor(ss, 32);
    __shared__ float red[4];
    if ((tid & 63) == 0) red[tid >> 6] = ss;
    __syncthreads();
    float tot = red[0] + red[1] + red[2] + red[3];
    float scale = rsqrtf(tot * (1.0f / (float)D_) + 1e-6f);
    float4 wv = ((const float4*)w)[tid];
    float4 o;
    o.x = wv.x * v.x * scale;
    o.y = wv.y * v.y * scale;
    o.z = wv.z * v.z * scale;
    o.w = wv.w * v.w * scale;
    st4(xm + base, o);
}

// out[i] += p0[i]+p1[i]+p2[i]+p3[i]  (split-K4 reduce, float4-strided)
__global__ __launch_bounds__(256) void add4_kernel(float* __restrict__ out,
                                                   const float* __restrict__ p,
                                                   int n4slice) {
    const int i = blockIdx.x * 256 + threadIdx.x;  // float4 index
    const float4* p4 = (const float4*)p;
    float4 o = ((const float4*)out)[i];
    float4 a = p4[i], b = p4[i + n4slice], c = p4[i + 2 * n4slice], d = p4[i + 3 * n4slice];
    o.x += (a.x + b.x) + (c.x + d.x);
    o.y += (a.y + b.y) + (c.y + d.y);
    o.z += (a.z + b.z) + (c.z + d.z);
    o.w += (a.w + b.w) + (c.w + d.w);
    ((float4*)out)[i] = o;
}

// ---------------------------------------------------------------------------
// Merged weight transpose + cast: all weights in ONE launch.
// mode 0: out row = n. mode 1 (gate): row = (n>>4)*32+(n&15).
// mode 2 (up): row = (n>>4)*32+16+(n&15). 16-col interleave so that in the
// gateup GEMM one lane holds gate (ni even) and up (ni odd) for the SAME
// output columns -> swiglu fuses into the epilogue with no LDS exchange.
// ---------------------------------------------------------------------------
struct TDesc { const float* in; ushort* out; int K, N, off, mode; };
struct TPack { TDesc d[15]; };

__global__ __launch_bounds__(256) void transpose_cast_multi(TPack p) {
    __shared__ float tile[32][33];
    const int bid = blockIdx.x;
    int di = 0;
#pragma unroll
    for (int i = 1; i < 15; i++)
        if (bid >= p.d[i].off) di = i;
    const TDesc d = p.d[di];
    const int local = bid - d.off;
    const int nt = d.N >> 5;
    const int bx = local % nt, by = local / nt;
    const int tx = threadIdx.x & 31, ty = threadIdx.x >> 5;  // 32 x 8
    const int n0 = bx * 32, k0 = by * 32;
#pragma unroll
    for (int i = 0; i < 4; i++)
        tile[ty + i * 8][tx] = d.in[(size_t)(k0 + ty + i * 8) * d.N + n0 + tx];
    __syncthreads();
#pragma unroll
    for (int i = 0; i < 4; i++) {
        const int n = n0 + ty + i * 8;
        int ro = n;
        if (d.mode == 1) ro = ((n >> 4) << 5) + (n & 15);
        else if (d.mode == 2) ro = ((n >> 4) << 5) + 16 + (n & 15);
        d.out[(size_t)ro * d.K + k0 + tx] = f2bf(tile[tx][ty + i * 8]);
    }
}

// ---------------------------------------------------------------------------
// bf16 MFMA GEMM, 2-phase double-buffered global_load_lds pipeline.
// 128x128 tile, 4 waves 2x2, BK=32. PARTIAL=true: split-K slice z -> fp32
// partials at C + z*M*Ntot. 8x16 grids get the 4x4-supertile XCD swizzle.
// epi: 0 none, 1 += res, 2 fused swiglu on 16-col interleaved gate|up B
//      (output bf16 at stride Ntot/2, only even-ni cols written).
// ---------------------------------------------------------------------------
template <typename OutT, bool PARTIAL>
__global__ __launch_bounds__(256) void mfma_gemm(
    const ushort* __restrict__ A, const ushort* __restrict__ BT, OutT* __restrict__ C,
    const float* res, int M, int Ntot, int K, int klen, int epi) {
    __shared__ ushort As[2][128 * 32];
    __shared__ ushort Bs[2][128 * 32];
    const int tid = threadIdx.x;
    const int wave = tid >> 6, lane = tid & 63;
    const int wr = wave >> 1, wc = wave & 1;
    const int lrow = lane & 15, quad = lane >> 4;
    int bx = blockIdx.x, by = blockIdx.y;
    if (gridDim.x == 8 && gridDim.y == 16) {
        const int bid = by * 8 + bx;
        const int k = bid & 7, i = bid >> 3;
        bx = ((k & 1) << 2) + (i & 3);
        by = ((k >> 1) << 2) + (i >> 2);
    }
    const int m0 = by * 128, n0 = bx * 128;
    const int kbase = blockIdx.z * klen;
    const int srow = lane >> 2;
    const int scol = (lane & 3) << 3;

    f32x4 acc[4][4] = {};

    auto stage = [&](int buf, int kk) {
#pragma unroll
        for (int j = 0; j < 2; j++) {
            const int chunk = 2 * wave + j;  // 0..7
            const ushort* ga = A + (size_t)(m0 + chunk * 16 + srow) * K + kk + scol;
            __builtin_amdgcn_global_load_lds((glb_u32_t*)ga,
                                             (lds_u32_t*)&As[buf][chunk * 512], 16, 0, 0);
            const int brow = n0 + chunk * 16 + srow;
            if (brow < Ntot) {
                const ushort* gb = BT + (size_t)brow * K + kk + scol;
                __builtin_amdgcn_global_load_lds((glb_u32_t*)gb,
                                                 (lds_u32_t*)&Bs[buf][chunk * 512], 16, 0, 0);
            }
        }
    };

    stage(0, kbase);
    __syncthreads();
    int cur = 0;
    for (int k0 = kbase; k0 < kbase + klen; k0 += 32) {
        if (k0 + 32 < kbase + klen) stage(cur ^ 1, k0 + 32);
        bf16x8 af[4], bfr[4];
#pragma unroll
        for (int mi = 0; mi < 4; mi++)
            af[mi] = *(const bf16x8*)&As[cur][(wr * 64 + mi * 16 + lrow) * 32 + quad * 8];
#pragma unroll
        for (int ni = 0; ni < 4; ni++)
            bfr[ni] = *(const bf16x8*)&Bs[cur][(wc * 64 + ni * 16 + lrow) * 32 + quad * 8];
#pragma unroll
        for (int mi = 0; mi < 4; mi++)
#pragma unroll
            for (int ni = 0; ni < 4; ni++)
                acc[mi][ni] = __builtin_amdgcn_mfma_f32_16x16x32_bf16(af[mi], bfr[ni], acc[mi][ni], 0, 0, 0);
        __syncthreads();
        cur ^= 1;
    }

    const size_t zoff = PARTIAL ? (size_t)blockIdx.z * M * Ntot : 0;
    const int hstride = Ntot >> 1;  // epi==2 output stride
#pragma unroll
    for (int mi = 0; mi < 4; mi++) {
#pragma unroll
        for (int r = 0; r < 4; r++) {
            const int row = m0 + wr * 64 + mi * 16 + quad * 4 + r;
            if (epi == 2) {
                if constexpr (!PARTIAL && sizeof(OutT) == 2) {
#pragma unroll
                    for (int ni = 0; ni < 4; ni += 2) {
                        const int ci = n0 + wc * 64 + ni * 16 + lrow;  // gate col (interleaved)
                        const float gv = acc[mi][ni][r];
                        const float uv = acc[mi][ni + 1][r];
                        const int co = ((ci >> 5) << 4) + (ci & 15);
                        C[(size_t)row * hstride + co] = (OutT)f2bf(gv * sigf(gv) * uv);
                    }
                }
                continue;
            }
#pragma unroll
            for (int ni = 0; ni < 4; ni++) {
                const int col = n0 + wc * 64 + ni * 16 + lrow;
                if (col < Ntot) {
                    const size_t idx = (size_t)row * Ntot + col;
                    float val = acc[mi][ni][r];
                    if constexpr (PARTIAL) {
                        ((float*)C)[idx + zoff] = val;
                    } else {
                        if (epi == 1) val += res[idx];
                        if constexpr (sizeof(OutT) == 2) C[idx] = (OutT)f2bf(val);
                        else C[idx] = (OutT)val;
                    }
                }
            }
        }
    }
}

// ---------------------------------------------------------------------------
// Multi-GEMM: z-indexed descriptors, same 2-phase pipeline. Non-atomic.
// epi: 0 none, 3 tanh, 4 sig, 5 sig(bias+v), 6 exp(-e^-.5*sig(bias+v)),
//      7 res+(res2-res)*sig(bias+v)
// ---------------------------------------------------------------------------
struct MMDesc {
    const ushort* A; const ushort* BT;
    float* Cf; ushort* Cb;
    const float* res; const float* res2; const float* bias;
    int Ntot, K, epi;
};
template <int NZ>
struct MMPack { MMDesc d[NZ]; };

template <int NZ>
__global__ __launch_bounds__(256) void mfma_gemm_multi(MMPack<NZ> p) {
    const MMDesc d = p.d[blockIdx.z];
    const int n0 = blockIdx.x * 128;
    if (n0 >= d.Ntot) return;  // uniform across block; no barrier crossed yet
    __shared__ ushort As[2][128 * 32];
    __shared__ ushort Bs[2][128 * 32];
    const int tid = threadIdx.x;
    const int wave = tid >> 6, lane = tid & 63;
    const int wr = wave >> 1, wc = wave & 1;
    const int lrow = lane & 15, quad = lane >> 4;
    const int m0 = blockIdx.y * 128;
    const int srow = lane >> 2;
    const int scol = (lane & 3) << 3;
    const int K = d.K, Ntot = d.Ntot;

    f32x4 acc[4][4] = {};

    auto stage = [&](int buf, int kk) {
#pragma unroll
        for (int j = 0; j < 2; j++) {
            const int chunk = 2 * wave + j;
            const ushort* ga = d.A + (size_t)(m0 + chunk * 16 + srow) * K + kk + scol;
            __builtin_amdgcn_global_load_lds((glb_u32_t*)ga,
                                             (lds_u32_t*)&As[buf][chunk * 512], 16, 0, 0);
            const int brow = n0 + chunk * 16 + srow;
            if (brow < Ntot) {
                const ushort* gb = d.BT + (size_t)brow * K + kk + scol;
                __builtin_amdgcn_global_load_lds((glb_u32_t*)gb,
                                                 (lds_u32_t*)&Bs[buf][chunk * 512], 16, 0, 0);
            }
        }
    };

    stage(0, 0);
    __syncthreads();
    int cur = 0;
    for (int k0 = 0; k0 < K; k0 += 32) {
        if (k0 + 32 < K) stage(cur ^ 1, k0 + 32);
        bf16x8 af[4], bfr[4];
#pragma unroll
        for (int mi = 0; mi < 4; mi++)
            af[mi] = *(const bf16x8*)&As[cur][(wr * 64 + mi * 16 + lrow) * 32 + quad * 8];
#pragma unroll
        for (int ni = 0; ni < 4; ni++)
            bfr[ni] = *(const bf16x8*)&Bs[cur][(wc * 64 + ni * 16 + lrow) * 32 + quad * 8];
#pragma unroll
        for (int mi = 0; mi < 4; mi++)
#pragma unroll
            for (int ni = 0; ni < 4; ni++)
                acc[mi][ni] = __builtin_amdgcn_mfma_f32_16x16x32_bf16(af[mi], bfr[ni], acc[mi][ni], 0, 0, 0);
        __syncthreads();
        cur ^= 1;
    }

#pragma unroll
    for (int mi = 0; mi < 4; mi++) {
#pragma unroll
        for (int r = 0; r < 4; r++) {
            const int row = m0 + wr * 64 + mi * 16 + quad * 4 + r;
#pragma unroll
            for (int ni = 0; ni < 4; ni++) {
                const int col = n0 + wc * 64 + ni * 16 + lrow;
                if (col < Ntot) {
                    const size_t idx = (size_t)row * Ntot + col;
                    float val = acc[mi][ni][r];
                    switch (d.epi) {
                        case 3: val = tanhf(val); break;
                        case 4: val = sigf(val); break;
                        case 5: val = sigf(d.bias[col] + val); break;
                        case 6: val = __expf(-0.60653065971263342f * sigf(d.bias[col] + val)); break;
                        case 7: {
                            float vr = d.res[idx];
                            val = vr + (d.res2[idx] - vr) * sigf(d.bias[col] + val);
                        } break;
                        default: break;
                    }
                    if (d.Cb) d.Cb[idx] = f2bf(val);
                    else d.Cf[idx] = val;
                }
            }
        }
    }
}

// ---------------------------------------------------------------------------
// kk = normalize_per_head(k * k_k); mb = -kk*a_sig; k *= (1+(a-1)*k_a).
// ---------------------------------------------------------------------------
__global__ __launch_bounds__(256) void kk_kernel(float* __restrict__ k,
                                                 const float* __restrict__ a_sig,
                                                 const float* __restrict__ k_k,
                                                 const float* __restrict__ k_a,
                                                 float* __restrict__ kk,
                                                 float* __restrict__ mb) {
    const int b = blockIdx.x * 4 + (threadIdx.x >> 6);
    const int t = b >> 4, h = b & 15;
    const int lane = threadIdx.x & 63;
    const size_t idx = (size_t)t * D_ + h * N_ + lane;
    const int wi = h * N_ + lane;
    const float kraw = k[idx];
    const float kv = kraw * k_k[wi];
    float ss = kv * kv;
    ss += __shfl_xor(ss, 1);
    ss += __shfl_xor(ss, 2);
    ss += __shfl_xor(ss, 4);
    ss += __shfl_xor(ss, 8);
    ss += __shfl_xor(ss, 16);
    ss += __shfl_xor(ss, 32);
    const float nrm = fmaxf(sqrtf(ss), 1e-12f);
    const float kkn = kv / nrm;
    kk[idx] = kkn;
    mb[idx] = -kkn * a_sig[idx];
    k[idx] = kraw * (1.0f + (a_sig[idx] - 1.0f) * k_a[wi]);
}

// ---------------------------------------------------------------------------
// Chunked scan pass 1, MERGED P+L roles, CLEN=32 / NCHUNK=64 (unchanged from
// R8 -- ~81us, at the per-CU LDS broadcast floor: 80 b128 x ~19cyc x 4 waves).
// ---------------------------------------------------------------------------
#define FOR16(M) M(0) M(1) M(2) M(3) M(4) M(5) M(6) M(7) \
                 M(8) M(9) M(10) M(11) M(12) M(13) M(14) M(15)

__global__ __launch_bounds__(64, 1) void scan_pass1(
    const float* __restrict__ gR, const float* __restrict__ gD, const float* __restrict__ gK,
    const float* __restrict__ gV, const float* __restrict__ gKK, const float* __restrict__ gMB,
    float* __restrict__ Pbuf, float* __restrict__ Lbuf,
    float* __restrict__ zbuf, float* __restrict__ olbuf) {
    const int bid = blockIdx.x;          // 0..NCHUNK*H-1
    const int h = bid & 15;
    const int c = bid >> 4;
    const int lane = threadIdx.x;        // row index
    const int hb = h * N_;
    const int t0 = c * CLEN;
    const int tend = t0 + CLEN - 1;

    __shared__ __align__(16) unsigned char ring[2 * 2048];

    const int rsel = lane >> 4;
    const int sub4 = (lane & 15) << 2;
    const float* p1 = (rsel == 0 ? gR : rsel == 1 ? gD : rsel == 2 ? gK : gKK)
                      + (size_t)t0 * D_ + hb + sub4;
    const float* p2 = (rsel == 1 ? gV : gMB) + (size_t)t0 * D_ + hb + sub4;

    // P state: identity rows; L state: zero.
#define DECLP(q) f32x4 sp##q = {(lane == 4 * q + 0) ? 1.0f : 0.0f, \
                                (lane == 4 * q + 1) ? 1.0f : 0.0f, \
                                (lane == 4 * q + 2) ? 1.0f : 0.0f, \
                                (lane == 4 * q + 3) ? 1.0f : 0.0f};
    FOR16(DECLP)
#undef DECLP
#define DECLL(q) f32x4 sl##q = {0.f, 0.f, 0.f, 0.f};
    FOR16(DECLL)
#undef DECLL

    float4 r0a, r0b, r1a, r1b, r2a, r2b, r3a, r3b;

#define LOADQ(qa, qb, tt) {                                                  \
        const size_t _adv = (size_t)((tt) - t0) * D_;                        \
        qa = *(const float4*)(p1 + _adv);                                    \
        qb = *(const float4*)(p2 + _adv); }
#define WRITEQ(sl, qa, qb) {                                                 \
        *(float4*)(ring + (sl) * 2048 + lane * 16) = qa;                     \
        *(float4*)(ring + (sl) * 2048 + 1024 + lane * 16) = qb; }
#define PA(q) { const f32x4 kk4 = sKKr[q];                                   \
        pacc += sp##q * kk4; lacc += sl##q * kk4; }
#define PB(q) {                                                   \
        const f32x4 d4 = sDr[q];                                  \
        const f32x4 k4 = sKr[q];                                  \
        const f32x4 m4 = sMBr[q];                                 \
        const f32x4 r4 = sRr[q];                                  \
        sp##q = sp##q * d4 + m4 * sapP;                           \
        sl##q = sl##q * d4 + (m4 * sapL + k4 * vv);               \
        oP += sp##q * r4;                                         \
        oL += sl##q * r4;                                         \
    }
#define COMPUTE(sl, tt) {                                                    \
        const unsigned char* sb = (const unsigned char*)ring + (sl) * 2048;  \
        const f32x4* sRr = (const f32x4*)(sb);                               \
        const f32x4* sDr = (const f32x4*)(sb + 256);                         \
        const f32x4* sKr = (const f32x4*)(sb + 512);                         \
        const f32x4* sKKr = (const f32x4*)(sb + 768);                        \
        const f32x4* sMBr = (const f32x4*)(sb + 1024);                       \
        const float* sVr = (const float*)(sb + 1280);                        \
        f32x4 pacc = {0.f, 0.f, 0.f, 0.f};                                   \
        f32x4 lacc = {0.f, 0.f, 0.f, 0.f};                                   \
        FOR16(PA)                                                            \
        const float sapP = (pacc.x + pacc.y) + (pacc.z + pacc.w);            \
        const float sapL = (lacc.x + lacc.y) + (lacc.z + lacc.w);            \
        const float vv = sVr[lane];                                          \
        f32x4 oP = {0.f, 0.f, 0.f, 0.f};                                     \
        f32x4 oL = {0.f, 0.f, 0.f, 0.f};                                     \
        FOR16(PB)                                                            \
        zbuf[(size_t)(tt) * D_ + hb + lane] = (oP.x + oP.y) + (oP.z + oP.w); \
        olbuf[(size_t)(tt) * D_ + hb + lane] = (oL.x + oL.y) + (oL.z + oL.w); }

    // prologue: 4-deep register pipeline; slot0 primed with t0
    LOADQ(r0a, r0b, t0)
    LOADQ(r1a, r1b, t0 + 1)
    LOADQ(r2a, r2b, t0 + 2)
    LOADQ(r3a, r3b, t0 + 3)
    WRITEQ(0, r0a, r0b)

    for (int t = t0; t < t0 + CLEN; t += 4) {
        WRITEQ(1, r1a, r1b)                                    // data t+1
        LOADQ(r0a, r0b, (t + 4 > tend ? tend : t + 4))
        COMPUTE(0, t)
        WRITEQ(0, r2a, r2b)                                    // data t+2
        LOADQ(r1a, r1b, (t + 5 > tend ? tend : t + 5))
        COMPUTE(1, t + 1)
        WRITEQ(1, r3a, r3b)                                    // data t+3
        LOADQ(r2a, r2b, (t + 6 > tend ? tend : t + 6))
        COMPUTE(0, t + 2)
        WRITEQ(0, r0a, r0b)                                    // data t+4
        LOADQ(r3a, r3b, (t + 7 > tend ? tend : t + 7))
        COMPUTE(1, t + 3)
    }
#undef COMPUTE
#undef PB
#undef PA
#undef WRITEQ
#undef LOADQ

    const size_t base = ((size_t)c * 16 + h) * 4096 + (size_t)lane * 64;
#define STP(q) *(f32x4*)(Pbuf + base + 4 * q) = sp##q;
    FOR16(STP)
#undef STP
#define STL(q) *(f32x4*)(Lbuf + base + 4 * q) = sl##q;
    FOR16(STL)
#undef STL
}

// ---------------------------------------------------------------------------
// Parallel pair merge: (P',L') for super-chunk j written in-place into odd
// slots; even slots preserved for odd-fill. (unchanged from R8)
// ---------------------------------------------------------------------------
__global__ __launch_bounds__(64) void merge_pairs(float* __restrict__ Pbuf,
                                                  float* __restrict__ Lbuf) {
    const int h = blockIdx.x & 15, j = blockIdx.x >> 4;  // j 0..31
    const int t = threadIdx.x;
    __shared__ float PaT[64][65];
    __shared__ float LaT[64][65];
    __shared__ float Pb[64][68];
    const size_t ca = ((size_t)(2 * j) * 16 + h) * 4096;
    const size_t cb = ((size_t)(2 * j + 1) * 16 + h) * 4096;
#pragma unroll
    for (int q = 0; q < 16; q++) {
        const int idx = t + q * 64;  // float4 index 0..1023
        const int r = idx >> 4, c4 = (idx & 15) << 2;
        float4 pa = *(const float4*)(Pbuf + ca + (size_t)r * 64 + c4);
        float4 la = *(const float4*)(Lbuf + ca + (size_t)r * 64 + c4);
        float4 pb = *(const float4*)(Pbuf + cb + (size_t)r * 64 + c4);
        PaT[c4 + 0][r] = pa.x; PaT[c4 + 1][r] = pa.y;
        PaT[c4 + 2][r] = pa.z; PaT[c4 + 3][r] = pa.w;
        LaT[c4 + 0][r] = la.x; LaT[c4 + 1][r] = la.y;
        LaT[c4 + 2][r] = la.z; LaT[c4 + 3][r] = la.w;
        *(float4*)&Pb[r][c4] = pb;
    }
    __syncthreads();
    const int cg = (t & 3) << 4;  // col base 0/16/32/48
    const int r0 = (t >> 2) << 2; // row base 0..60 step 4
    float4 accP[4][4] = {};
    float4 accL[4][4];
#pragma unroll
    for (int rr = 0; rr < 4; rr++)
#pragma unroll
        for (int e = 0; e < 4; e++)
            accL[rr][e] = *(const float4*)(Lbuf + cb + (size_t)(r0 + rr) * 64 + cg + 4 * e);
    for (int m = 0; m < 64; m++) {
        float4 pb4[4];
#pragma unroll
        for (int e = 0; e < 4; e++) pb4[e] = *(const float4*)&Pb[m][cg + 4 * e];
#pragma unroll
        for (int rr = 0; rr < 4; rr++) {
            const float pa = PaT[m][r0 + rr];
            const float la = LaT[m][r0 + rr];
#pragma unroll
            for (int e = 0; e < 4; e++) {
                accP[rr][e].x = fmaf(pa, pb4[e].x, accP[rr][e].x);
                accP[rr][e].y = fmaf(pa, pb4[e].y, accP[rr][e].y);
                accP[rr][e].z = fmaf(pa, pb4[e].z, accP[rr][e].z);
                accP[rr][e].w = fmaf(pa, pb4[e].w, accP[rr][e].w);
                accL[rr][e].x = fmaf(la, pb4[e].x, accL[rr][e].x);
                accL[rr][e].y = fmaf(la, pb4[e].y, accL[rr][e].y);
                accL[rr][e].z = fmaf(la, pb4[e].z, accL[rr][e].z);
                accL[rr][e].w = fmaf(la, pb4[e].w, accL[rr][e].w);
            }
        }
    }
#pragma unroll
    for (int rr = 0; rr < 4; rr++)
#pragma unroll
        for (int e = 0; e < 4; e++) {
            *(float4*)(Pbuf + cb + (size_t)(r0 + rr) * 64 + cg + 4 * e) = accP[rr][e];
            *(float4*)(Lbuf + cb + (size_t)(r0 + rr) * 64 + cg + 4 * e) = accL[rr][e];
        }
}

// ---------------------------------------------------------------------------
// Serial combine over 32 SUPER-chunks with register prefetch. (unchanged)
// ---------------------------------------------------------------------------
__global__ __launch_bounds__(256) void scan_combine(
    const float* __restrict__ state_in, const float* __restrict__ Pbuf,
    const float* __restrict__ Lbuf, float* __restrict__ SstT, float* __restrict__ state_out) {
    const int h = blockIdx.x >> 2, rg = blockIdx.x & 3;
    const int tid = threadIdx.x;
    const int i = tid >> 4, j4 = (tid & 15) << 2;
    const int gi = rg * 16 + i;
    __shared__ float Sl[16][68];
    __shared__ float Pl[64][68];

    float4 sv = *(const float4*)(state_in + (size_t)h * 4096 + gi * 64 + j4);
    *(float4*)&Sl[i][j4] = sv;

    float4 rp0, rp1, rp2, rp3, rl;
    {
        const size_t cb = ((size_t)1 * 16 + h) * 4096;  // super-chunk 0 = slot 1
        rp0 = *(const float4*)(Pbuf + cb + (size_t)(i +  0) * 64 + j4);
        rp1 = *(const float4*)(Pbuf + cb + (size_t)(i + 16) * 64 + j4);
        rp2 = *(const float4*)(Pbuf + cb + (size_t)(i + 32) * 64 + j4);
        rp3 = *(const float4*)(Pbuf + cb + (size_t)(i + 48) * 64 + j4);
        rl  = *(const float4*)(Lbuf + cb + (size_t)gi * 64 + j4);
    }
    __syncthreads();

    for (int c = 0; c < NCHUNK / 2; c++) {
        *(float4*)&Pl[i +  0][j4] = rp0;
        *(float4*)&Pl[i + 16][j4] = rp1;
        *(float4*)&Pl[i + 32][j4] = rp2;
        *(float4*)&Pl[i + 48][j4] = rp3;
        float4 acc = rl;
        const size_t so = ((size_t)(2 * c) * 16 + h) * 4096;
        float4 scur = *(const float4*)&Sl[i][j4];
        SstT[so + (size_t)(j4 + 0) * 64 + gi] = scur.x;
        SstT[so + (size_t)(j4 + 1) * 64 + gi] = scur.y;
        SstT[so + (size_t)(j4 + 2) * 64 + gi] = scur.z;
        SstT[so + (size_t)(j4 + 3) * 64 + gi] = scur.w;
        __syncthreads();  // Pl visible to all waves
        if (c + 1 < NCHUNK / 2) {  // prefetch next super-chunk (slot 2c+3)
            const size_t cb = ((size_t)(2 * c + 3) * 16 + h) * 4096;
            rp0 = *(const float4*)(Pbuf + cb + (size_t)(i +  0) * 64 + j4);
            rp1 = *(const float4*)(Pbuf + cb + (size_t)(i + 16) * 64 + j4);
            rp2 = *(const float4*)(Pbuf + cb + (size_t)(i + 32) * 64 + j4);
            rp3 = *(const float4*)(Pbuf + cb + (size_t)(i + 48) * 64 + j4);
            rl  = *(const float4*)(Lbuf + cb + (size_t)gi * 64 + j4);
        }
#pragma unroll 8
        for (int m = 0; m < 64; m++) {
            const float smv = Sl[i][m];
            const float4 p4 = *(const float4*)&Pl[m][j4];
            acc.x = fmaf(smv, p4.x, acc.x);
            acc.y = fmaf(smv, p4.y, acc.y);
            acc.z = fmaf(smv, p4.z, acc.z);
            acc.w = fmaf(smv, p4.w, acc.w);
        }
        __syncthreads();
        *(float4*)&Sl[i][j4] = acc;
    }
    *(float4*)(state_out + (size_t)h * 4096 + gi * 64 + j4) = *(const float4*)&Sl[i][j4];
}

// ---------------------------------------------------------------------------
// Odd-fill: S_{2j+1} = S_{2j} @ P_{2j} + L_{2j} (even slots). (unchanged)
// ---------------------------------------------------------------------------
__global__ __launch_bounds__(256) void scan_oddfill(
    const float* __restrict__ Pbuf, const float* __restrict__ Lbuf,
    float* __restrict__ SstT) {
    const int b = blockIdx.x;
    const int rg = b & 3, h = (b >> 2) & 15, j = b >> 6;  // j 0..31
    const int tid = threadIdx.x;
    const int i = tid >> 4, j4 = (tid & 15) << 2;
    const int gi = rg * 16 + i;
    __shared__ float Sl[16][68];
    __shared__ float Pl[64][68];
    const size_t ce = ((size_t)(2 * j) * 16 + h) * 4096;
    const size_t co = ((size_t)(2 * j + 1) * 16 + h) * 4096;
    {
        float4 s;
        s.x = SstT[ce + (size_t)(j4 + 0) * 64 + gi];
        s.y = SstT[ce + (size_t)(j4 + 1) * 64 + gi];
        s.z = SstT[ce + (size_t)(j4 + 2) * 64 + gi];
        s.w = SstT[ce + (size_t)(j4 + 3) * 64 + gi];
        *(float4*)&Sl[i][j4] = s;
    }
#pragma unroll
    for (int q = 0; q < 4; q++) {
        const int prq = i + q * 16;
        *(float4*)&Pl[prq][j4] = *(const float4*)(Pbuf + ce + (size_t)prq * 64 + j4);
    }
    __syncthreads();
    float4 acc = *(const float4*)(Lbuf + ce + (size_t)gi * 64 + j4);
#pragma unroll 8
    for (int m = 0; m < 64; m++) {
        const float smv = Sl[i][m];
        const float4 p4 = *(const float4*)&Pl[m][j4];
        acc.x = fmaf(smv, p4.x, acc.x);
        acc.y = fmaf(smv, p4.y, acc.y);
        acc.z = fmaf(smv, p4.z, acc.z);
        acc.w = fmaf(smv, p4.w, acc.w);
    }
    SstT[co + (size_t)(j4 + 0) * 64 + gi] = acc.x;
    SstT[co + (size_t)(j4 + 1) * 64 + gi] = acc.y;
    SstT[co + (size_t)(j4 + 2) * 64 + gi] = acc.z;
    SstT[co + (size_t)(j4 + 3) * 64 + gi] = acc.w;
}

// ---------------------------------------------------------------------------
// FUSED fix + bonus + gate: o = o_local + S_start@z; c = sum(r*k*r_k) per
// token; og = bf16((o + c*v) * g). Threads of one token are 16 consecutive
// lanes -> shfl_xor 1/2/4/8 reduce. Writes OG bf16 directly (obuf removed).
// ---------------------------------------------------------------------------
__global__ __launch_bounds__(256) void scan_fix(
    const float* __restrict__ zbuf, const float* __restrict__ olbuf,
    const float* __restrict__ SstT,
    const float* __restrict__ r, const float* __restrict__ k,
    const float* __restrict__ v, const float* __restrict__ g,
    const float* __restrict__ r_k, ushort* __restrict__ og) {
    const int tg = blockIdx.x >> 4, h = blockIdx.x & 15;
    const int hb = h * N_;
    const int tid = threadIdx.x;
    const int tok = tid >> 4, i4 = (tid & 15) << 2;
    const int tbase = tg * 16;
    const int c = tbase / CLEN;
    __shared__ float zl[16][68];
    __shared__ float Sl[64][68];

    *(float4*)&zl[tok][i4] = *(const float4*)(zbuf + (size_t)(tbase + tok) * D_ + hb + i4);
    const size_t cb = ((size_t)c * 16 + h) * 4096;
#pragma unroll
    for (int q = 0; q < 4; q++) {
        const int jr = (tid >> 4) + q * 16;
        *(float4*)&Sl[jr][i4] = *(const float4*)(SstT + cb + (size_t)jr * 64 + i4);
    }
    __syncthreads();
    const size_t tix = (size_t)(tbase + tok) * D_ + hb + i4;
    float4 acc = *(const float4*)(olbuf + tix);
#pragma unroll 8
    for (int j = 0; j < 64; j++) {
        const float zv = zl[tok][j];
        const float4 p4 = *(const float4*)&Sl[j][i4];
        acc.x = fmaf(zv, p4.x, acc.x);
        acc.y = fmaf(zv, p4.y, acc.y);
        acc.z = fmaf(zv, p4.z, acc.z);
        acc.w = fmaf(zv, p4.w, acc.w);
    }
    // bonus + gate
    float4 rv = *(const float4*)(r + tix);
    float4 kv = *(const float4*)(k + tix);
    float4 rk = *(const float4*)(r_k + hb + i4);
    float cc = rv.x * kv.x * rk.x + rv.y * kv.y * rk.y +
               rv.z * kv.z * rk.z + rv.w * kv.w * rk.w;
    cc += __shfl_xor(cc, 1);
    cc += __shfl_xor(cc, 2);
    cc += __shfl_xor(cc, 4);
    cc += __shfl_xor(cc, 8);
    float4 vv = *(const float4*)(v + tix);
    float4 gv = *(const float4*)(g + tix);
    float4 o;
    o.x = (acc.x + cc * vv.x) * gv.x;
    o.y = (acc.y + cc * vv.y) * gv.y;
    o.z = (acc.z + cc * vv.z) * gv.z;
    o.w = (acc.w + cc * vv.w) * gv.w;
    st4(og + tix, o);
}

// ---------------------------------------------------------------------------
extern "C" void kernel_launch(void* const* d_in, const int* in_sizes, int n_in,
                              void* d_out, int out_size, void* d_ws, size_t ws_size,
                              hipStream_t stream) {
    const float* x      = (const float*)d_in[0];
    const float* x_prev = (const float*)d_in[1];
    const float* v_first= (const float*)d_in[2];
    const float* state  = (const float*)d_in[3];
    const float* ln1_w  = (const float*)d_in[4];
    const float* ln2_w  = (const float*)d_in[5];
    const float* x_r    = (const float*)d_in[6];
    const float* x_w    = (const float*)d_in[7];
    const float* x_k    = (const float*)d_in[8];
    const float* x_v    = (const float*)d_in[9];
    const float* x_a    = (const float*)d_in[10];
    const float* x_g    = (const float*)d_in[11];
    const float* w0     = (const float*)d_in[12];
    const float* w1     = (const float*)d_in[13];
    const float* w2     = (const float*)d_in[14];
    const float* a0     = (const float*)d_in[15];
    const float* a1     = (const float*)d_in[16];
    const float* a2     = (const float*)d_in[17];
    const float* v0     = (const float*)d_in[18];
    const float* v1     = (const float*)d_in[19];
    const float* v2     = (const float*)d_in[20];
    const float* g1     = (const float*)d_in[21];
    const float* g2     = (const float*)d_in[22];
    const float* k_k    = (const float*)d_in[23];
    const float* k_a    = (const float*)d_in[24];
    const float* r_k    = (const float*)d_in[25];
    const float* R_     = (const float*)d_in[26];
    const float* K_     = (const float*)d_in[27];
    const float* V_     = (const float*)d_in[28];
    const float* O_     = (const float*)d_in[29];
    const float* gate_w = (const float*)d_in[30];
    const float* up_w   = (const float*)d_in[31];
    const float* down_w = (const float*)d_in[32];

    float* ws = (float*)d_ws;
    const size_t U = (size_t)T_ * D_;  // 2M floats (8 MB)
    float* u_r  = ws;
    float* u_k  = ws + 1 * U;
    float* u_v  = ws + 2 * U;
    float* u_dc = ws + 3 * U;   // decay -> SstT[0:8MB]
    float* u_kk = ws + 4 * U;   // kk    -> SstT[8:16MB] -> Opart0 -> Hbuf
    float* u_mb = ws + 5 * U;   // -kk*a -> Opart1 -> Hbuf
    float* u_g  = ws + 6 * U;   // Lbuf[0:8MB] during scan; g AFTER oddfill
    float* u_ao = ws + 7 * U;   // a_sig -> Lbuf[8:16MB]
    ushort* XB = (ushort*)(ws + 8 * U);
    const size_t TD = U;
    ushort* XR = XB + 0 * TD;
    ushort* XW = XB + 1 * TD;
    ushort* XK = XB + 2 * TD;
    ushort* XV = XB + 3 * TD;
    ushort* XA = XB + 4 * TD;
    ushort* XG = XB + 5 * TD;
    float* Pbuf  = (float*)XB;         // XB[0:16MB]
    float* Lbuf  = u_g;                // ws+6U..8U (16MB)
    float* zbuf  = ws + 10 * U;        // XB[16:24MB]
    float* olbuf = (float*)d_out;      // d_out[0:8MB]
    float* SstT  = u_dc;               // ws+3U..5U (16MB)
    ushort* OG   = XB;                 // bf16 4 MB (Pbuf dead after oddfill)
    ushort* XM   = (ushort*)(ws + 10 * U);
    float* Opart = ws + 4 * U;         // 2 x 8 MB (u_kk/u_mb dead after pass1)
    ushort* Hbuf = (ushort*)(ws + 4 * U);   // 16 MB (Opart dead after reduce2)
    float* Dpart = ws;                 // 4 x 8 MB (u_r..u_dc dead after fix)
    ushort* WT = (ushort*)(ws + 11 * U);
    const size_t DD = (size_t)D_ * D_;
    const size_t DF = (size_t)D_ * F_;
    ushort* WTR = WT;
    ushort* WTK = WTR + DD;
    ushort* WTV = WTK + DD;
    ushort* WTO = WTV + DD;
    ushort* WTGU = WTO + DD;          // interleaved gate|up [8192,1024]
    ushort* WTD = WTGU + 2 * DF;
    ushort* WTw1 = WTD + DF;
    ushort* WTw2 = WTw1 + 64 * 1024;
    ushort* WTa1 = WTw2 + 64 * 1024;
    ushort* WTa2 = WTa1 + 64 * 1024;
    ushort* WTv1 = WTa2 + 64 * 1024;
    ushort* WTv2 = WTv1 + 32 * 1024;
    ushort* WTg1 = WTv2 + 32 * 1024;
    ushort* WTg2 = WTg1 + 128 * 1024;
    ushort* Lw = WTg2 + 128 * 1024;
    ushort* La = Lw + (size_t)T_ * 64;
    ushort* Lv = La + (size_t)T_ * 64;
    ushort* Lg = Lv + (size_t)T_ * 32;

    float* out_x = (float*)d_out;
    float* out_xn_last = out_x + (size_t)T_ * D_;
    float* out_state = out_xn_last + D_;

    // --- all 15 weight transposes in ONE launch (gate/up -> interleaved) ---
    TPack tp;
    int toff = 0, ti = 0;
    auto addT = [&](const float* in, ushort* out, int K, int N, int mode) {
        tp.d[ti].in = in; tp.d[ti].out = out; tp.d[ti].K = K; tp.d[ti].N = N;
        tp.d[ti].off = toff; tp.d[ti].mode = mode;
        toff += (N / 32) * (K / 32); ++ti;
    };
    addT(R_, WTR, D_, D_, 0);
    addT(K_, WTK, D_, D_, 0);
    addT(V_, WTV, D_, D_, 0);
    addT(O_, WTO, D_, D_, 0);
    addT(gate_w, WTGU, D_, F_, 1);
    addT(up_w, WTGU, D_, F_, 2);
    addT(down_w, WTD, F_, D_, 0);
    addT(w1, WTw1, D_, 64, 0);
    addT(w2, WTw2, 64, D_, 0);
    addT(a1, WTa1, D_, 64, 0);
    addT(a2, WTa2, 64, D_, 0);
    addT(v1, WTv1, D_, 32, 0);
    addT(v2, WTv2, 32, D_, 0);
    addT(g1, WTg1, D_, 128, 0);
    addT(g2, WTg2, 128, D_, 0);
    transpose_cast_multi<<<toff, 256, 0, stream>>>(tp);

    // 1. fused ln1 + token shift -> bf16 xr..xg + xn_last
    ln_shift_kernel<<<T_, 256, 0, stream>>>(x, x_prev, ln1_w,
                                            x_r, x_w, x_k, x_v, x_a, x_g,
                                            XR, XW, XK, XV, XA, XG, out_xn_last);
    // 2-5. r/k/v + 4 LoRA stage-1 GEMMs in ONE launch
    auto mkmm = [](const ushort* A, const ushort* BT, float* Cf, ushort* Cb,
                   const float* res, const float* res2, const float* bias,
                   int Ntot, int K, int epi) {
        MMDesc m{A, BT, Cf, Cb, res, res2, bias, Ntot, K, epi};
        return m;
    };
    MMPack<7> pa;
    pa.d[0] = mkmm(XR, WTR, u_r, nullptr, nullptr, nullptr, nullptr, D_, D_, 0);
    pa.d[1] = mkmm(XK, WTK, u_k, nullptr, nullptr, nullptr, nullptr, D_, D_, 0);
    pa.d[2] = mkmm(XV, WTV, u_v, nullptr, nullptr, nullptr, nullptr, D_, D_, 0);
    pa.d[3] = mkmm(XW, WTw1, nullptr, Lw, nullptr, nullptr, nullptr, 64,  D_, 3);  // tanh
    pa.d[4] = mkmm(XA, WTa1, nullptr, La, nullptr, nullptr, nullptr, 64,  D_, 0);
    pa.d[5] = mkmm(XV, WTv1, nullptr, Lv, nullptr, nullptr, nullptr, 32,  D_, 0);
    pa.d[6] = mkmm(XG, WTg1, nullptr, Lg, nullptr, nullptr, nullptr, 128, D_, 4);  // sigmoid
    mfma_gemm_multi<7><<<dim3(8, 16, 7), 256, 0, stream>>>(pa);
    // 6. LoRA stage-2 (decay / a_sig / v-lerp); g deferred (u_g = Lbuf)
    MMPack<3> pb;
    pb.d[0] = mkmm(Lw, WTw2, u_dc, nullptr, nullptr, nullptr, w0, D_, 64,  6);  // decay
    pb.d[1] = mkmm(La, WTa2, u_ao, nullptr, nullptr, nullptr, a0, D_, 64,  5);  // a_sig
    pb.d[2] = mkmm(Lv, WTv2, u_v,  nullptr, u_v, v_first,     v0, D_, 32,  7);  // v lerp
    mfma_gemm_multi<3><<<dim3(8, 16, 3), 256, 0, stream>>>(pb);
    // 7. kk / mb / k-mod
    kk_kernel<<<T_ * H_ / 4, 256, 0, stream>>>(u_k, u_ao, k_k, k_a, u_kk, u_mb);
    // 8. chunked scan: pass1 -> pair-merge -> serial-32 -> odd-fill
    scan_pass1<<<NCHUNK * H_, 64, 0, stream>>>(u_r, u_dc, u_k, u_v, u_kk, u_mb,
                                               Pbuf, Lbuf, zbuf, olbuf);
    merge_pairs<<<16 * 32, 64, 0, stream>>>(Pbuf, Lbuf);
    scan_combine<<<H_ * 4, 256, 0, stream>>>(state, Pbuf, Lbuf, SstT, out_state);
    scan_oddfill<<<16 * 32 * 4, 256, 0, stream>>>(Pbuf, Lbuf, SstT);
    // 8b. deferred g GEMM (Lbuf dead -> u_g writable)
    mfma_gemm<float, false><<<dim3(8, 16), 256, 0, stream>>>(
        Lg, WTg2, u_g, nullptr, T_, D_, 128, 128, 0);
    // 9. fused fix + bonus + gate -> OG bf16
    scan_fix<<<(T_ / 16) * H_, 256, 0, stream>>>(zbuf, olbuf, SstT,
                                                 u_r, u_k, u_v, u_g, r_k, OG);
    // 10. O-proj split-K2 -> fp32 partials at ws+4U, 256 blocks
    mfma_gemm<float, true><<<dim3(8, 16, 2), 256, 0, stream>>>(
        OG, WTO, Opart, nullptr, T_, D_, D_, 512, 0);
    // 11. fused: out_x = x + p0 + p1; ln2(out_x) -> XM bf16
    rmsnorm_reduce2<<<T_, 256, 0, stream>>>(x, Opart, Opart + U, ln2_w, out_x, XM);
    // 12. MLP gate|up with FUSED swiglu epilogue -> Hbuf bf16 [T,4096]
    mfma_gemm<ushort, false><<<dim3(64, 16), 256, 0, stream>>>(
        XM, WTGU, Hbuf, nullptr, T_, 2 * F_, D_, D_, 2);
    // 13. down split-K4 -> fp32 partials over ws..4U, 512 blocks
    mfma_gemm<float, true><<<dim3(8, 16, 4), 256, 0, stream>>>(
        Hbuf, WTD, Dpart, nullptr, T_, D_, F_, 1024, 0);
    // 14. out_x += sum of 4 partials
    add4_kernel<<<(int)(U / 4 / 256), 256, 0, stream>>>(out_x, Dpart, (int)(U / 4));
}

// Round 10
// 591.947 us; speedup vs baseline: 1.0944x; 1.0349x over previous
//
#include <hip/hip_runtime.h>
#include <math.h>

// Problem constants (B=1)
#define T_ 2048
#define D_ 1024
#define H_ 16
#define N_ 64
#define F_ 4096
#define NCHUNK 64
#define CLEN 32

typedef __attribute__((ext_vector_type(8))) short bf16x8;
typedef __attribute__((ext_vector_type(4))) float f32x4;
typedef __attribute__((address_space(3))) unsigned int lds_u32_t;
typedef __attribute__((address_space(1))) const unsigned int glb_u32_t;

static __device__ __forceinline__ float sigf(float x) { return 1.0f / (1.0f + __expf(-x)); }

static __device__ __forceinline__ ushort f2bf(float f) {
    union { float f; unsigned u; } c; c.f = f;
    unsigned r = (c.u + 0x7FFFu + ((c.u >> 16) & 1u)) >> 16;
    return (ushort)r;
}
static __device__ __forceinline__ float bf2f(ushort h) {
    union { unsigned u; float f; } c; c.u = ((unsigned)h) << 16;
    return c.f;
}

static __device__ __forceinline__ void st4(float* p, float4 v) { *(float4*)p = v; }
static __device__ __forceinline__ void st4(ushort* p, float4 v) {
    ushort4 o; o.x = f2bf(v.x); o.y = f2bf(v.y); o.z = f2bf(v.z); o.w = f2bf(v.w);
    *(ushort4*)p = o;
}

// ---------------------------------------------------------------------------
// FUSED ln1 + token shift (unchanged from R9).
// ---------------------------------------------------------------------------
__global__ __launch_bounds__(256) void ln_shift_kernel(
    const float* __restrict__ x, const float* __restrict__ x_prev,
    const float* __restrict__ w,
    const float* __restrict__ cr, const float* __restrict__ cw, const float* __restrict__ ck,
    const float* __restrict__ cv, const float* __restrict__ ca, const float* __restrict__ cg,
    ushort* __restrict__ xr, ushort* __restrict__ xw, ushort* __restrict__ xk,
    ushort* __restrict__ xv, ushort* __restrict__ xa, ushort* __restrict__ xg,
    float* __restrict__ last) {
    const int t = blockIdx.x;
    const int tid = threadIdx.x;
    const float4* x4 = (const float4*)x;
    float4 xc = x4[t * 256 + tid];
    float4 xp = (t == 0) ? ((const float4*)x_prev)[tid] : x4[(t - 1) * 256 + tid];
    float ssc = xc.x * xc.x + xc.y * xc.y + xc.z * xc.z + xc.w * xc.w;
    float ssp = xp.x * xp.x + xp.y * xp.y + xp.z * xp.z + xp.w * xp.w;
    ssc += __shfl_xor(ssc, 1); ssp += __shfl_xor(ssp, 1);
    ssc += __shfl_xor(ssc, 2); ssp += __shfl_xor(ssp, 2);
    ssc += __shfl_xor(ssc, 4); ssp += __shfl_xor(ssp, 4);
    ssc += __shfl_xor(ssc, 8); ssp += __shfl_xor(ssp, 8);
    ssc += __shfl_xor(ssc, 16); ssp += __shfl_xor(ssp, 16);
    ssc += __shfl_xor(ssc, 32); ssp += __shfl_xor(ssp, 32);
    __shared__ float redc[4], redp[4];
    if ((tid & 63) == 0) { redc[tid >> 6] = ssc; redp[tid >> 6] = ssp; }
    __syncthreads();
    const float totc = redc[0] + redc[1] + redc[2] + redc[3];
    const float totp = redp[0] + redp[1] + redp[2] + redp[3];
    const float sc = rsqrtf(totc * (1.0f / (float)D_) + 1e-6f);
    const float sp = rsqrtf(totp * (1.0f / (float)D_) + 1e-6f);
    float4 wv = ((const float4*)w)[tid];
    float4 cur, prev;
    cur.x = wv.x * xc.x * sc; cur.y = wv.y * xc.y * sc;
    cur.z = wv.z * xc.z * sc; cur.w = wv.w * xc.w * sc;
    if (t == 0) {
        prev = xp;  // raw x_prev per reference
    } else {
        prev.x = wv.x * xp.x * sp; prev.y = wv.y * xp.y * sp;
        prev.z = wv.z * xp.z * sp; prev.w = wv.w * xp.w * sp;
    }
    float4 xx;
    xx.x = prev.x - cur.x; xx.y = prev.y - cur.y;
    xx.z = prev.z - cur.z; xx.w = prev.w - cur.w;
    const size_t ob = (size_t)t * D_ + tid * 4;
#define APPLY(dst, c)                                   \
    {                                                   \
        float4 cc = ((const float4*)c)[tid];            \
        float4 o;                                       \
        o.x = cur.x + xx.x * cc.x;                      \
        o.y = cur.y + xx.y * cc.y;                      \
        o.z = cur.z + xx.z * cc.z;                      \
        o.w = cur.w + xx.w * cc.w;                      \
        st4(dst + ob, o);                               \
    }
    APPLY(xr, cr)
    APPLY(xw, cw)
    APPLY(xk, ck)
    APPLY(xv, cv)
    APPLY(xa, ca)
    APPLY(xg, cg)
#undef APPLY
    if (t == T_ - 1) ((float4*)last)[tid] = cur;
}

// ---------------------------------------------------------------------------
// Fused: v = x + p0 + p1; write resid AND rmsnorm(v)*w -> bf16 xm.
// ---------------------------------------------------------------------------
__global__ __launch_bounds__(256) void rmsnorm_reduce2(
    const float* __restrict__ x, const float* __restrict__ p0, const float* __restrict__ p1,
    const float* __restrict__ w, float* __restrict__ resid_out, ushort* __restrict__ xm) {
    const int t = blockIdx.x;
    const int tid = threadIdx.x;
    const size_t base = (size_t)t * D_ + tid * 4;
    float4 v = *(const float4*)(x + base);
    float4 a = *(const float4*)(p0 + base);
    float4 b = *(const float4*)(p1 + base);
    v.x += a.x + b.x; v.y += a.y + b.y; v.z += a.z + b.z; v.w += a.w + b.w;
    st4(resid_out + base, v);
    float ss = v.x * v.x + v.y * v.y + v.z * v.z + v.w * v.w;
    ss += __shfl_xor(ss, 1);
    ss += __shfl_xor(ss, 2);
    ss += __shfl_xor(ss, 4);
    ss += __shfl_xor(ss, 8);
    ss += __shfl_xor(ss, 16);
    ss += __shfl_xor(ss, 32);
    __shared__ float red[4];
    if ((tid & 63) == 0) red[tid >> 6] = ss;
    __syncthreads();
    float tot = red[0] + red[1] + red[2] + red[3];
    float scale = rsqrtf(tot * (1.0f / (float)D_) + 1e-6f);
    float4 wv = ((const float4*)w)[tid];
    float4 o;
    o.x = wv.x * v.x * scale;
    o.y = wv.y * v.y * scale;
    o.z = wv.z * v.z * scale;
    o.w = wv.w * v.w * scale;
    st4(xm + base, o);
}

// out[i] += p0[i]+p1[i]+p2[i]+p3[i]  (split-K4 reduce, float4-strided)
__global__ __launch_bounds__(256) void add4_kernel(float* __restrict__ out,
                                                   const float* __restrict__ p,
                                                   int n4slice) {
    const int i = blockIdx.x * 256 + threadIdx.x;  // float4 index
    const float4* p4 = (const float4*)p;
    float4 o = ((const float4*)out)[i];
    float4 a = p4[i], b = p4[i + n4slice], c = p4[i + 2 * n4slice], d = p4[i + 3 * n4slice];
    o.x += (a.x + b.x) + (c.x + d.x);
    o.y += (a.y + b.y) + (c.y + d.y);
    o.z += (a.z + b.z) + (c.z + d.z);
    o.w += (a.w + b.w) + (c.w + d.w);
    ((float4*)out)[i] = o;
}

// ---------------------------------------------------------------------------
// Merged weight transpose + cast (mode 1/2 = gate/up 16-col interleave).
// ---------------------------------------------------------------------------
struct TDesc { const float* in; ushort* out; int K, N, off, mode; };
struct TPack { TDesc d[15]; };

__global__ __launch_bounds__(256) void transpose_cast_multi(TPack p) {
    __shared__ float tile[32][33];
    const int bid = blockIdx.x;
    int di = 0;
#pragma unroll
    for (int i = 1; i < 15; i++)
        if (bid >= p.d[i].off) di = i;
    const TDesc d = p.d[di];
    const int local = bid - d.off;
    const int nt = d.N >> 5;
    const int bx = local % nt, by = local / nt;
    const int tx = threadIdx.x & 31, ty = threadIdx.x >> 5;  // 32 x 8
    const int n0 = bx * 32, k0 = by * 32;
#pragma unroll
    for (int i = 0; i < 4; i++)
        tile[ty + i * 8][tx] = d.in[(size_t)(k0 + ty + i * 8) * d.N + n0 + tx];
    __syncthreads();
#pragma unroll
    for (int i = 0; i < 4; i++) {
        const int n = n0 + ty + i * 8;
        int ro = n;
        if (d.mode == 1) ro = ((n >> 4) << 5) + (n & 15);
        else if (d.mode == 2) ro = ((n >> 4) << 5) + 16 + (n & 15);
        d.out[(size_t)ro * d.K + k0 + tx] = f2bf(tile[tx][ty + i * 8]);
    }
}

// ---------------------------------------------------------------------------
// bf16 MFMA GEMM, 2-phase double-buffered global_load_lds pipeline.
// epi: 0 none, 1 += res, 2 fused swiglu (16-col interleaved gate|up).
// ---------------------------------------------------------------------------
template <typename OutT, bool PARTIAL>
__global__ __launch_bounds__(256) void mfma_gemm(
    const ushort* __restrict__ A, const ushort* __restrict__ BT, OutT* __restrict__ C,
    const float* res, int M, int Ntot, int K, int klen, int epi) {
    __shared__ ushort As[2][128 * 32];
    __shared__ ushort Bs[2][128 * 32];
    const int tid = threadIdx.x;
    const int wave = tid >> 6, lane = tid & 63;
    const int wr = wave >> 1, wc = wave & 1;
    const int lrow = lane & 15, quad = lane >> 4;
    int bx = blockIdx.x, by = blockIdx.y;
    if (gridDim.x == 8 && gridDim.y == 16) {
        const int bid = by * 8 + bx;
        const int k = bid & 7, i = bid >> 3;
        bx = ((k & 1) << 2) + (i & 3);
        by = ((k >> 1) << 2) + (i >> 2);
    }
    const int m0 = by * 128, n0 = bx * 128;
    const int kbase = blockIdx.z * klen;
    const int srow = lane >> 2;
    const int scol = (lane & 3) << 3;

    f32x4 acc[4][4] = {};

    auto stage = [&](int buf, int kk) {
#pragma unroll
        for (int j = 0; j < 2; j++) {
            const int chunk = 2 * wave + j;  // 0..7
            const ushort* ga = A + (size_t)(m0 + chunk * 16 + srow) * K + kk + scol;
            __builtin_amdgcn_global_load_lds((glb_u32_t*)ga,
                                             (lds_u32_t*)&As[buf][chunk * 512], 16, 0, 0);
            const int brow = n0 + chunk * 16 + srow;
            if (brow < Ntot) {
                const ushort* gb = BT + (size_t)brow * K + kk + scol;
                __builtin_amdgcn_global_load_lds((glb_u32_t*)gb,
                                                 (lds_u32_t*)&Bs[buf][chunk * 512], 16, 0, 0);
            }
        }
    };

    stage(0, kbase);
    __syncthreads();
    int cur = 0;
    for (int k0 = kbase; k0 < kbase + klen; k0 += 32) {
        if (k0 + 32 < kbase + klen) stage(cur ^ 1, k0 + 32);
        bf16x8 af[4], bfr[4];
#pragma unroll
        for (int mi = 0; mi < 4; mi++)
            af[mi] = *(const bf16x8*)&As[cur][(wr * 64 + mi * 16 + lrow) * 32 + quad * 8];
#pragma unroll
        for (int ni = 0; ni < 4; ni++)
            bfr[ni] = *(const bf16x8*)&Bs[cur][(wc * 64 + ni * 16 + lrow) * 32 + quad * 8];
#pragma unroll
        for (int mi = 0; mi < 4; mi++)
#pragma unroll
            for (int ni = 0; ni < 4; ni++)
                acc[mi][ni] = __builtin_amdgcn_mfma_f32_16x16x32_bf16(af[mi], bfr[ni], acc[mi][ni], 0, 0, 0);
        __syncthreads();
        cur ^= 1;
    }

    const size_t zoff = PARTIAL ? (size_t)blockIdx.z * M * Ntot : 0;
    const int hstride = Ntot >> 1;  // epi==2 output stride
#pragma unroll
    for (int mi = 0; mi < 4; mi++) {
#pragma unroll
        for (int r = 0; r < 4; r++) {
            const int row = m0 + wr * 64 + mi * 16 + quad * 4 + r;
            if (epi == 2) {
                if constexpr (!PARTIAL && sizeof(OutT) == 2) {
#pragma unroll
                    for (int ni = 0; ni < 4; ni += 2) {
                        const int ci = n0 + wc * 64 + ni * 16 + lrow;  // gate col (interleaved)
                        const float gv = acc[mi][ni][r];
                        const float uv = acc[mi][ni + 1][r];
                        const int co = ((ci >> 5) << 4) + (ci & 15);
                        C[(size_t)row * hstride + co] = (OutT)f2bf(gv * sigf(gv) * uv);
                    }
                }
                continue;
            }
#pragma unroll
            for (int ni = 0; ni < 4; ni++) {
                const int col = n0 + wc * 64 + ni * 16 + lrow;
                if (col < Ntot) {
                    const size_t idx = (size_t)row * Ntot + col;
                    float val = acc[mi][ni][r];
                    if constexpr (PARTIAL) {
                        ((float*)C)[idx + zoff] = val;
                    } else {
                        if (epi == 1) val += res[idx];
                        if constexpr (sizeof(OutT) == 2) C[idx] = (OutT)f2bf(val);
                        else C[idx] = (OutT)val;
                    }
                }
            }
        }
    }
}

// ---------------------------------------------------------------------------
// Multi-GEMM: z-indexed descriptors. Writes Cf (fp32) and/or Cb (bf16) --
// BOTH when both set (r-GEMM dual-writes for the bf16 scan stream).
// epi: 0 none, 3 tanh, 4 sig, 5 sig(bias+v), 6 exp(-e^-.5*sig(bias+v)),
//      7 res+(res2-res)*sig(bias+v)
// ---------------------------------------------------------------------------
struct MMDesc {
    const ushort* A; const ushort* BT;
    float* Cf; ushort* Cb;
    const float* res; const float* res2; const float* bias;
    int Ntot, K, epi;
};
template <int NZ>
struct MMPack { MMDesc d[NZ]; };

template <int NZ>
__global__ __launch_bounds__(256) void mfma_gemm_multi(MMPack<NZ> p) {
    const MMDesc d = p.d[blockIdx.z];
    const int n0 = blockIdx.x * 128;
    if (n0 >= d.Ntot) return;  // uniform across block; no barrier crossed yet
    __shared__ ushort As[2][128 * 32];
    __shared__ ushort Bs[2][128 * 32];
    const int tid = threadIdx.x;
    const int wave = tid >> 6, lane = tid & 63;
    const int wr = wave >> 1, wc = wave & 1;
    const int lrow = lane & 15, quad = lane >> 4;
    const int m0 = blockIdx.y * 128;
    const int srow = lane >> 2;
    const int scol = (lane & 3) << 3;
    const int K = d.K, Ntot = d.Ntot;

    f32x4 acc[4][4] = {};

    auto stage = [&](int buf, int kk) {
#pragma unroll
        for (int j = 0; j < 2; j++) {
            const int chunk = 2 * wave + j;
            const ushort* ga = d.A + (size_t)(m0 + chunk * 16 + srow) * K + kk + scol;
            __builtin_amdgcn_global_load_lds((glb_u32_t*)ga,
                                             (lds_u32_t*)&As[buf][chunk * 512], 16, 0, 0);
            const int brow = n0 + chunk * 16 + srow;
            if (brow < Ntot) {
                const ushort* gb = d.BT + (size_t)brow * K + kk + scol;
                __builtin_amdgcn_global_load_lds((glb_u32_t*)gb,
                                                 (lds_u32_t*)&Bs[buf][chunk * 512], 16, 0, 0);
            }
        }
    };

    stage(0, 0);
    __syncthreads();
    int cur = 0;
    for (int k0 = 0; k0 < K; k0 += 32) {
        if (k0 + 32 < K) stage(cur ^ 1, k0 + 32);
        bf16x8 af[4], bfr[4];
#pragma unroll
        for (int mi = 0; mi < 4; mi++)
            af[mi] = *(const bf16x8*)&As[cur][(wr * 64 + mi * 16 + lrow) * 32 + quad * 8];
#pragma unroll
        for (int ni = 0; ni < 4; ni++)
            bfr[ni] = *(const bf16x8*)&Bs[cur][(wc * 64 + ni * 16 + lrow) * 32 + quad * 8];
#pragma unroll
        for (int mi = 0; mi < 4; mi++)
#pragma unroll
            for (int ni = 0; ni < 4; ni++)
                acc[mi][ni] = __builtin_amdgcn_mfma_f32_16x16x32_bf16(af[mi], bfr[ni], acc[mi][ni], 0, 0, 0);
        __syncthreads();
        cur ^= 1;
    }

#pragma unroll
    for (int mi = 0; mi < 4; mi++) {
#pragma unroll
        for (int r = 0; r < 4; r++) {
            const int row = m0 + wr * 64 + mi * 16 + quad * 4 + r;
#pragma unroll
            for (int ni = 0; ni < 4; ni++) {
                const int col = n0 + wc * 64 + ni * 16 + lrow;
                if (col < Ntot) {
                    const size_t idx = (size_t)row * Ntot + col;
                    float val = acc[mi][ni][r];
                    switch (d.epi) {
                        case 3: val = tanhf(val); break;
                        case 4: val = sigf(val); break;
                        case 5: val = sigf(d.bias[col] + val); break;
                        case 6: val = __expf(-0.60653065971263342f * sigf(d.bias[col] + val)); break;
                        case 7: {
                            float vr = d.res[idx];
                            val = vr + (d.res2[idx] - vr) * sigf(d.bias[col] + val);
                        } break;
                        default: break;
                    }
                    if (d.Cb) d.Cb[idx] = f2bf(val);
                    if (d.Cf) d.Cf[idx] = val;
                }
            }
        }
    }
}

// ---------------------------------------------------------------------------
// kk: normalize_per_head(k*k_k) -> bf16 kkb; mbb = bf16(-kk*a_sig);
// k-mod written BOTH fp32 (scan_fix bonus) and bf16 (scan stream).
// ---------------------------------------------------------------------------
__global__ __launch_bounds__(256) void kk_kernel(float* __restrict__ k,
                                                 const float* __restrict__ a_sig,
                                                 const float* __restrict__ k_k,
                                                 const float* __restrict__ k_a,
                                                 ushort* __restrict__ kkb,
                                                 ushort* __restrict__ mbb,
                                                 ushort* __restrict__ kb) {
    const int b = blockIdx.x * 4 + (threadIdx.x >> 6);
    const int t = b >> 4, h = b & 15;
    const int lane = threadIdx.x & 63;
    const size_t idx = (size_t)t * D_ + h * N_ + lane;
    const int wi = h * N_ + lane;
    const float kraw = k[idx];
    const float kv = kraw * k_k[wi];
    float ss = kv * kv;
    ss += __shfl_xor(ss, 1);
    ss += __shfl_xor(ss, 2);
    ss += __shfl_xor(ss, 4);
    ss += __shfl_xor(ss, 8);
    ss += __shfl_xor(ss, 16);
    ss += __shfl_xor(ss, 32);
    const float nrm = fmaxf(sqrtf(ss), 1e-12f);
    const float kkn = kv / nrm;
    kkb[idx] = f2bf(kkn);
    mbb[idx] = f2bf(-kkn * a_sig[idx]);
    const float kn = kraw * (1.0f + (a_sig[idx] - 1.0f) * k_a[wi]);
    k[idx] = kn;
    kb[idx] = f2bf(kn);
}

// ---------------------------------------------------------------------------
// Chunked scan pass 1, merged P+L, bf16 STREAMS for r/k/kk/mb (d, v stay
// fp32). One b128 now carries 8 values -> LDS reads/t drop 81 -> 49, and the
// measured wall is per-instruction on the shared LDS pipe (128 t-units/CU x
// reads x ~19cyc). Ring slot (1024B): [0:128) r bf16, [128:256) k bf16,
// [256:384) kk bf16, [384:512) mb bf16, [512:768) d f32, [768:1024) v f32.
// ---------------------------------------------------------------------------
#define FOR16(M) M(0) M(1) M(2) M(3) M(4) M(5) M(6) M(7) \
                 M(8) M(9) M(10) M(11) M(12) M(13) M(14) M(15)

__global__ __launch_bounds__(64, 1) void scan_pass1(
    const ushort* __restrict__ gRb, const float* __restrict__ gD,
    const ushort* __restrict__ gKb, const float* __restrict__ gV,
    const ushort* __restrict__ gKKb, const ushort* __restrict__ gMBb,
    float* __restrict__ Pbuf, float* __restrict__ Lbuf,
    float* __restrict__ zbuf, float* __restrict__ olbuf) {
    const int bid = blockIdx.x;          // 0..NCHUNK*H-1
    const int h = bid & 15;
    const int c = bid >> 4;
    const int lane = threadIdx.x;        // row index
    const int hb = h * N_;
    const int t0 = c * CLEN;
    const int tend = t0 + CLEN - 1;

    __shared__ __align__(16) unsigned char ring[2 * 1024];

    const int rsel = lane >> 4;
    const int sub = lane & 15;
    const ushort* pB = (rsel == 0 ? gRb : rsel == 1 ? gKb : rsel == 2 ? gKKb : gMBb)
                       + (size_t)t0 * D_ + hb + sub * 4;
    const float* pDV = (rsel == 0 ? gD : gV) + (size_t)t0 * D_ + hb + sub * 4;

    // P state: identity rows; L state: zero.
#define DECLP(q) f32x4 sp##q = {(lane == 4 * q + 0) ? 1.0f : 0.0f, \
                                (lane == 4 * q + 1) ? 1.0f : 0.0f, \
                                (lane == 4 * q + 2) ? 1.0f : 0.0f, \
                                (lane == 4 * q + 3) ? 1.0f : 0.0f};
    FOR16(DECLP)
#undef DECLP
#define DECLL(q) f32x4 sl##q = {0.f, 0.f, 0.f, 0.f};
    FOR16(DECLL)
#undef DECLL

    ushort4 b0, b1, b2, b3;
    float4 v0, v1, v2, v3;

#define LOADQ(qb, qd, tt) {                                                  \
        const size_t _adv = (size_t)((tt) - t0) * D_;                        \
        qb = *(const ushort4*)(pB + _adv);                                   \
        if (lane < 32) qd = *(const float4*)(pDV + _adv); }
#define WRITEQ(sl_, qb, qd) {                                                \
        *(ushort4*)(ring + (sl_) * 1024 + rsel * 128 + sub * 8) = qb;        \
        if (lane < 32)                                                       \
            *(float4*)(ring + (sl_) * 1024 + 512 + rsel * 256 + sub * 16) = qd; }
#define UNPK(u, lo, hi) {                                                    \
        lo.x = __uint_as_float((u).x << 16);                                 \
        lo.y = __uint_as_float((u).x & 0xFFFF0000u);                         \
        lo.z = __uint_as_float((u).y << 16);                                 \
        lo.w = __uint_as_float((u).y & 0xFFFF0000u);                         \
        hi.x = __uint_as_float((u).z << 16);                                 \
        hi.y = __uint_as_float((u).z & 0xFFFF0000u);                         \
        hi.z = __uint_as_float((u).w << 16);                                 \
        hi.w = __uint_as_float((u).w & 0xFFFF0000u); }
#define PAp(p, qa, qb_) {                                                    \
        const uint4 u = *(const uint4*)(sbKK + (p) * 16);                    \
        f32x4 lo, hi; UNPK(u, lo, hi);                                       \
        pacc += sp##qa * lo + sp##qb_ * hi;                                  \
        lacc += sl##qa * lo + sl##qb_ * hi; }
#define PBp(p, qa, qb_) {                                                    \
        const uint4 ur = *(const uint4*)(sbR + (p) * 16);                    \
        const uint4 uk = *(const uint4*)(sbK + (p) * 16);                    \
        const uint4 um = *(const uint4*)(sbMB + (p) * 16);                   \
        f32x4 rlo, rhi, klo, khi, mlo, mhi;                                  \
        UNPK(ur, rlo, rhi); UNPK(uk, klo, khi); UNPK(um, mlo, mhi);          \
        const f32x4 dlo = sbD[2 * (p)], dhi = sbD[2 * (p) + 1];              \
        sp##qa = sp##qa * dlo + mlo * sapP;                                  \
        sl##qa = sl##qa * dlo + (mlo * sapL + klo * vv);                     \
        oP += sp##qa * rlo; oL += sl##qa * rlo;                              \
        sp##qb_ = sp##qb_ * dhi + mhi * sapP;                                \
        sl##qb_ = sl##qb_ * dhi + (mhi * sapL + khi * vv);                   \
        oP += sp##qb_ * rhi; oL += sl##qb_ * rhi; }
#define COMPUTE(sl_, tt) {                                                   \
        const unsigned char* sb = (const unsigned char*)ring + (sl_) * 1024; \
        const unsigned char* sbR = sb;                                       \
        const unsigned char* sbK = sb + 128;                                 \
        const unsigned char* sbKK = sb + 256;                                \
        const unsigned char* sbMB = sb + 384;                                \
        const f32x4* sbD = (const f32x4*)(sb + 512);                         \
        const float* sbV = (const float*)(sb + 768);                         \
        f32x4 pacc = {0.f, 0.f, 0.f, 0.f};                                   \
        f32x4 lacc = {0.f, 0.f, 0.f, 0.f};                                   \
        PAp(0, 0, 1) PAp(1, 2, 3) PAp(2, 4, 5) PAp(3, 6, 7)                  \
        PAp(4, 8, 9) PAp(5, 10, 11) PAp(6, 12, 13) PAp(7, 14, 15)            \
        const float sapP = (pacc.x + pacc.y) + (pacc.z + pacc.w);            \
        const float sapL = (lacc.x + lacc.y) + (lacc.z + lacc.w);            \
        const float vv = sbV[lane];                                          \
        f32x4 oP = {0.f, 0.f, 0.f, 0.f};                                     \
        f32x4 oL = {0.f, 0.f, 0.f, 0.f};                                     \
        PBp(0, 0, 1) PBp(1, 2, 3) PBp(2, 4, 5) PBp(3, 6, 7)                  \
        PBp(4, 8, 9) PBp(5, 10, 11) PBp(6, 12, 13) PBp(7, 14, 15)            \
        zbuf[(size_t)(tt) * D_ + hb + lane] = (oP.x + oP.y) + (oP.z + oP.w); \
        olbuf[(size_t)(tt) * D_ + hb + lane] = (oL.x + oL.y) + (oL.z + oL.w); }

    // prologue: 4-deep register pipeline; slot0 primed with t0
    LOADQ(b0, v0, t0)
    LOADQ(b1, v1, t0 + 1)
    LOADQ(b2, v2, t0 + 2)
    LOADQ(b3, v3, t0 + 3)
    WRITEQ(0, b0, v0)

    for (int t = t0; t < t0 + CLEN; t += 4) {
        WRITEQ(1, b1, v1)                                      // data t+1
        LOADQ(b0, v0, (t + 4 > tend ? tend : t + 4))
        COMPUTE(0, t)
        WRITEQ(0, b2, v2)                                      // data t+2
        LOADQ(b1, v1, (t + 5 > tend ? tend : t + 5))
        COMPUTE(1, t + 1)
        WRITEQ(1, b3, v3)                                      // data t+3
        LOADQ(b2, v2, (t + 6 > tend ? tend : t + 6))
        COMPUTE(0, t + 2)
        WRITEQ(0, b0, v0)                                      // data t+4
        LOADQ(b3, v3, (t + 7 > tend ? tend : t + 7))
        COMPUTE(1, t + 3)
    }
#undef COMPUTE
#undef PBp
#undef PAp
#undef UNPK
#undef WRITEQ
#undef LOADQ

    const size_t base = ((size_t)c * 16 + h) * 4096 + (size_t)lane * 64;
#define STP(q) *(f32x4*)(Pbuf + base + 4 * q) = sp##q;
    FOR16(STP)
#undef STP
#define STL(q) *(f32x4*)(Lbuf + base + 4 * q) = sl##q;
    FOR16(STL)
#undef STL
}

// ---------------------------------------------------------------------------
// Parallel pair merge (unchanged from R9).
// ---------------------------------------------------------------------------
__global__ __launch_bounds__(64) void merge_pairs(float* __restrict__ Pbuf,
                                                  float* __restrict__ Lbuf) {
    const int h = blockIdx.x & 15, j = blockIdx.x >> 4;  // j 0..31
    const int t = threadIdx.x;
    __shared__ float PaT[64][65];
    __shared__ float LaT[64][65];
    __shared__ float Pb[64][68];
    const size_t ca = ((size_t)(2 * j) * 16 + h) * 4096;
    const size_t cb = ((size_t)(2 * j + 1) * 16 + h) * 4096;
#pragma unroll
    for (int q = 0; q < 16; q++) {
        const int idx = t + q * 64;  // float4 index 0..1023
        const int r = idx >> 4, c4 = (idx & 15) << 2;
        float4 pa = *(const float4*)(Pbuf + ca + (size_t)r * 64 + c4);
        float4 la = *(const float4*)(Lbuf + ca + (size_t)r * 64 + c4);
        float4 pb = *(const float4*)(Pbuf + cb + (size_t)r * 64 + c4);
        PaT[c4 + 0][r] = pa.x; PaT[c4 + 1][r] = pa.y;
        PaT[c4 + 2][r] = pa.z; PaT[c4 + 3][r] = pa.w;
        LaT[c4 + 0][r] = la.x; LaT[c4 + 1][r] = la.y;
        LaT[c4 + 2][r] = la.z; LaT[c4 + 3][r] = la.w;
        *(float4*)&Pb[r][c4] = pb;
    }
    __syncthreads();
    const int cg = (t & 3) << 4;  // col base 0/16/32/48
    const int r0 = (t >> 2) << 2; // row base 0..60 step 4
    float4 accP[4][4] = {};
    float4 accL[4][4];
#pragma unroll
    for (int rr = 0; rr < 4; rr++)
#pragma unroll
        for (int e = 0; e < 4; e++)
            accL[rr][e] = *(const float4*)(Lbuf + cb + (size_t)(r0 + rr) * 64 + cg + 4 * e);
    for (int m = 0; m < 64; m++) {
        float4 pb4[4];
#pragma unroll
        for (int e = 0; e < 4; e++) pb4[e] = *(const float4*)&Pb[m][cg + 4 * e];
#pragma unroll
        for (int rr = 0; rr < 4; rr++) {
            const float pa = PaT[m][r0 + rr];
            const float la = LaT[m][r0 + rr];
#pragma unroll
            for (int e = 0; e < 4; e++) {
                accP[rr][e].x = fmaf(pa, pb4[e].x, accP[rr][e].x);
                accP[rr][e].y = fmaf(pa, pb4[e].y, accP[rr][e].y);
                accP[rr][e].z = fmaf(pa, pb4[e].z, accP[rr][e].z);
                accP[rr][e].w = fmaf(pa, pb4[e].w, accP[rr][e].w);
                accL[rr][e].x = fmaf(la, pb4[e].x, accL[rr][e].x);
                accL[rr][e].y = fmaf(la, pb4[e].y, accL[rr][e].y);
                accL[rr][e].z = fmaf(la, pb4[e].z, accL[rr][e].z);
                accL[rr][e].w = fmaf(la, pb4[e].w, accL[rr][e].w);
            }
        }
    }
#pragma unroll
    for (int rr = 0; rr < 4; rr++)
#pragma unroll
        for (int e = 0; e < 4; e++) {
            *(float4*)(Pbuf + cb + (size_t)(r0 + rr) * 64 + cg + 4 * e) = accP[rr][e];
            *(float4*)(Lbuf + cb + (size_t)(r0 + rr) * 64 + cg + 4 * e) = accL[rr][e];
        }
}

// ---------------------------------------------------------------------------
// Serial combine over 32 super-chunks with register prefetch (unchanged).
// ---------------------------------------------------------------------------
__global__ __launch_bounds__(256) void scan_combine(
    const float* __restrict__ state_in, const float* __restrict__ Pbuf,
    const float* __restrict__ Lbuf, float* __restrict__ SstT, float* __restrict__ state_out) {
    const int h = blockIdx.x >> 2, rg = blockIdx.x & 3;
    const int tid = threadIdx.x;
    const int i = tid >> 4, j4 = (tid & 15) << 2;
    const int gi = rg * 16 + i;
    __shared__ float Sl[16][68];
    __shared__ float Pl[64][68];

    float4 sv = *(const float4*)(state_in + (size_t)h * 4096 + gi * 64 + j4);
    *(float4*)&Sl[i][j4] = sv;

    float4 rp0, rp1, rp2, rp3, rl;
    {
        const size_t cb = ((size_t)1 * 16 + h) * 4096;  // super-chunk 0 = slot 1
        rp0 = *(const float4*)(Pbuf + cb + (size_t)(i +  0) * 64 + j4);
        rp1 = *(const float4*)(Pbuf + cb + (size_t)(i + 16) * 64 + j4);
        rp2 = *(const float4*)(Pbuf + cb + (size_t)(i + 32) * 64 + j4);
        rp3 = *(const float4*)(Pbuf + cb + (size_t)(i + 48) * 64 + j4);
        rl  = *(const float4*)(Lbuf + cb + (size_t)gi * 64 + j4);
    }
    __syncthreads();

    for (int c = 0; c < NCHUNK / 2; c++) {
        *(float4*)&Pl[i +  0][j4] = rp0;
        *(float4*)&Pl[i + 16][j4] = rp1;
        *(float4*)&Pl[i + 32][j4] = rp2;
        *(float4*)&Pl[i + 48][j4] = rp3;
        float4 acc = rl;
        const size_t so = ((size_t)(2 * c) * 16 + h) * 4096;
        float4 scur = *(const float4*)&Sl[i][j4];
        SstT[so + (size_t)(j4 + 0) * 64 + gi] = scur.x;
        SstT[so + (size_t)(j4 + 1) * 64 + gi] = scur.y;
        SstT[so + (size_t)(j4 + 2) * 64 + gi] = scur.z;
        SstT[so + (size_t)(j4 + 3) * 64 + gi] = scur.w;
        __syncthreads();  // Pl visible to all waves
        if (c + 1 < NCHUNK / 2) {  // prefetch next super-chunk (slot 2c+3)
            const size_t cb = ((size_t)(2 * c + 3) * 16 + h) * 4096;
            rp0 = *(const float4*)(Pbuf + cb + (size_t)(i +  0) * 64 + j4);
            rp1 = *(const float4*)(Pbuf + cb + (size_t)(i + 16) * 64 + j4);
            rp2 = *(const float4*)(Pbuf + cb + (size_t)(i + 32) * 64 + j4);
            rp3 = *(const float4*)(Pbuf + cb + (size_t)(i + 48) * 64 + j4);
            rl  = *(const float4*)(Lbuf + cb + (size_t)gi * 64 + j4);
        }
#pragma unroll 8
        for (int m = 0; m < 64; m++) {
            const float smv = Sl[i][m];
            const float4 p4 = *(const float4*)&Pl[m][j4];
            acc.x = fmaf(smv, p4.x, acc.x);
            acc.y = fmaf(smv, p4.y, acc.y);
            acc.z = fmaf(smv, p4.z, acc.z);
            acc.w = fmaf(smv, p4.w, acc.w);
        }
        __syncthreads();
        *(float4*)&Sl[i][j4] = acc;
    }
    *(float4*)(state_out + (size_t)h * 4096 + gi * 64 + j4) = *(const float4*)&Sl[i][j4];
}

// ---------------------------------------------------------------------------
// Odd-fill: S_{2j+1} = S_{2j} @ P_{2j} + L_{2j} (even slots). (unchanged)
// ---------------------------------------------------------------------------
__global__ __launch_bounds__(256) void scan_oddfill(
    const float* __restrict__ Pbuf, const float* __restrict__ Lbuf,
    float* __restrict__ SstT) {
    const int b = blockIdx.x;
    const int rg = b & 3, h = (b >> 2) & 15, j = b >> 6;  // j 0..31
    const int tid = threadIdx.x;
    const int i = tid >> 4, j4 = (tid & 15) << 2;
    const int gi = rg * 16 + i;
    __shared__ float Sl[16][68];
    __shared__ float Pl[64][68];
    const size_t ce = ((size_t)(2 * j) * 16 + h) * 4096;
    const size_t co = ((size_t)(2 * j + 1) * 16 + h) * 4096;
    {
        float4 s;
        s.x = SstT[ce + (size_t)(j4 + 0) * 64 + gi];
        s.y = SstT[ce + (size_t)(j4 + 1) * 64 + gi];
        s.z = SstT[ce + (size_t)(j4 + 2) * 64 + gi];
        s.w = SstT[ce + (size_t)(j4 + 3) * 64 + gi];
        *(float4*)&Sl[i][j4] = s;
    }
#pragma unroll
    for (int q = 0; q < 4; q++) {
        const int prq = i + q * 16;
        *(float4*)&Pl[prq][j4] = *(const float4*)(Pbuf + ce + (size_t)prq * 64 + j4);
    }
    __syncthreads();
    float4 acc = *(const float4*)(Lbuf + ce + (size_t)gi * 64 + j4);
#pragma unroll 8
    for (int m = 0; m < 64; m++) {
        const float smv = Sl[i][m];
        const float4 p4 = *(const float4*)&Pl[m][j4];
        acc.x = fmaf(smv, p4.x, acc.x);
        acc.y = fmaf(smv, p4.y, acc.y);
        acc.z = fmaf(smv, p4.z, acc.z);
        acc.w = fmaf(smv, p4.w, acc.w);
    }
    SstT[co + (size_t)(j4 + 0) * 64 + gi] = acc.x;
    SstT[co + (size_t)(j4 + 1) * 64 + gi] = acc.y;
    SstT[co + (size_t)(j4 + 2) * 64 + gi] = acc.z;
    SstT[co + (size_t)(j4 + 3) * 64 + gi] = acc.w;
}

// ---------------------------------------------------------------------------
// FUSED fix + bonus + gate (unchanged from R9).
// ---------------------------------------------------------------------------
__global__ __launch_bounds__(256) void scan_fix(
    const float* __restrict__ zbuf, const float* __restrict__ olbuf,
    const float* __restrict__ SstT,
    const float* __restrict__ r, const float* __restrict__ k,
    const float* __restrict__ v, const float* __restrict__ g,
    const float* __restrict__ r_k, ushort* __restrict__ og) {
    const int tg = blockIdx.x >> 4, h = blockIdx.x & 15;
    const int hb = h * N_;
    const int tid = threadIdx.x;
    const int tok = tid >> 4, i4 = (tid & 15) << 2;
    const int tbase = tg * 16;
    const int c = tbase / CLEN;
    __shared__ float zl[16][68];
    __shared__ float Sl[64][68];

    *(float4*)&zl[tok][i4] = *(const float4*)(zbuf + (size_t)(tbase + tok) * D_ + hb + i4);
    const size_t cb = ((size_t)c * 16 + h) * 4096;
#pragma unroll
    for (int q = 0; q < 4; q++) {
        const int jr = (tid >> 4) + q * 16;
        *(float4*)&Sl[jr][i4] = *(const float4*)(SstT + cb + (size_t)jr * 64 + i4);
    }
    __syncthreads();
    const size_t tix = (size_t)(tbase + tok) * D_ + hb + i4;
    float4 acc = *(const float4*)(olbuf + tix);
#pragma unroll 8
    for (int j = 0; j < 64; j++) {
        const float zv = zl[tok][j];
        const float4 p4 = *(const float4*)&Sl[j][i4];
        acc.x = fmaf(zv, p4.x, acc.x);
        acc.y = fmaf(zv, p4.y, acc.y);
        acc.z = fmaf(zv, p4.z, acc.z);
        acc.w = fmaf(zv, p4.w, acc.w);
    }
    float4 rv = *(const float4*)(r + tix);
    float4 kv = *(const float4*)(k + tix);
    float4 rk = *(const float4*)(r_k + hb + i4);
    float cc = rv.x * kv.x * rk.x + rv.y * kv.y * rk.y +
               rv.z * kv.z * rk.z + rv.w * kv.w * rk.w;
    cc += __shfl_xor(cc, 1);
    cc += __shfl_xor(cc, 2);
    cc += __shfl_xor(cc, 4);
    cc += __shfl_xor(cc, 8);
    float4 vv = *(const float4*)(v + tix);
    float4 gv = *(const float4*)(g + tix);
    float4 o;
    o.x = (acc.x + cc * vv.x) * gv.x;
    o.y = (acc.y + cc * vv.y) * gv.y;
    o.z = (acc.z + cc * vv.z) * gv.z;
    o.w = (acc.w + cc * vv.w) * gv.w;
    st4(og + tix, o);
}

// ---------------------------------------------------------------------------
extern "C" void kernel_launch(void* const* d_in, const int* in_sizes, int n_in,
                              void* d_out, int out_size, void* d_ws, size_t ws_size,
                              hipStream_t stream) {
    const float* x      = (const float*)d_in[0];
    const float* x_prev = (const float*)d_in[1];
    const float* v_first= (const float*)d_in[2];
    const float* state  = (const float*)d_in[3];
    const float* ln1_w  = (const float*)d_in[4];
    const float* ln2_w  = (const float*)d_in[5];
    const float* x_r    = (const float*)d_in[6];
    const float* x_w    = (const float*)d_in[7];
    const float* x_k    = (const float*)d_in[8];
    const float* x_v    = (const float*)d_in[9];
    const float* x_a    = (const float*)d_in[10];
    const float* x_g    = (const float*)d_in[11];
    const float* w0     = (const float*)d_in[12];
    const float* w1     = (const float*)d_in[13];
    const float* w2     = (const float*)d_in[14];
    const float* a0     = (const float*)d_in[15];
    const float* a1     = (const float*)d_in[16];
    const float* a2     = (const float*)d_in[17];
    const float* v0     = (const float*)d_in[18];
    const float* v1     = (const float*)d_in[19];
    const float* v2     = (const float*)d_in[20];
    const float* g1     = (const float*)d_in[21];
    const float* g2     = (const float*)d_in[22];
    const float* k_k    = (const float*)d_in[23];
    const float* k_a    = (const float*)d_in[24];
    const float* r_k    = (const float*)d_in[25];
    const float* R_     = (const float*)d_in[26];
    const float* K_     = (const float*)d_in[27];
    const float* V_     = (const float*)d_in[28];
    const float* O_     = (const float*)d_in[29];
    const float* gate_w = (const float*)d_in[30];
    const float* up_w   = (const float*)d_in[31];
    const float* down_w = (const float*)d_in[32];

    float* ws = (float*)d_ws;
    const size_t U = (size_t)T_ * D_;  // 2M floats (8 MB)
    float* u_r  = ws;
    float* u_k  = ws + 1 * U;
    float* u_v  = ws + 2 * U;
    float* u_dc = ws + 3 * U;   // decay -> SstT[0:8MB]
    // ws+4U..6U: bf16 scan streams during scan; Opart/Hbuf later
    float* u_g  = ws + 6 * U;   // Lbuf[0:8MB] during scan; g AFTER oddfill
    float* u_ao = ws + 7 * U;   // a_sig -> Lbuf[8:16MB]
    ushort* KKb = (ushort*)(ws + 4 * U);      // 4 MB
    ushort* MBb = KKb + U;                    // 4 MB
    ushort* Kb  = (ushort*)(ws + 5 * U);      // 4 MB
    ushort* Rb  = Kb + U;                     // 4 MB
    ushort* XB = (ushort*)(ws + 8 * U);
    const size_t TD = U;
    ushort* XR = XB + 0 * TD;
    ushort* XW = XB + 1 * TD;
    ushort* XK = XB + 2 * TD;
    ushort* XV = XB + 3 * TD;
    ushort* XA = XB + 4 * TD;
    ushort* XG = XB + 5 * TD;
    float* Pbuf  = (float*)XB;         // XB[0:16MB]
    float* Lbuf  = u_g;                // ws+6U..8U (16MB)
    float* zbuf  = ws + 10 * U;        // XB[16:24MB]
    float* olbuf = (float*)d_out;      // d_out[0:8MB]
    float* SstT  = u_dc;               // ws+3U..5U (16MB; 2nd half over KKb/MBb, dead)
    ushort* OG   = XB;                 // bf16 4 MB (Pbuf dead after oddfill)
    ushort* XM   = (ushort*)(ws + 10 * U);
    float* Opart = ws + 4 * U;         // 2 x 8 MB (bf16 streams dead after pass1)
    ushort* Hbuf = (ushort*)(ws + 4 * U);   // 16 MB (Opart dead after reduce2)
    float* Dpart = ws;                 // 4 x 8 MB (u_r..u_dc dead after fix)
    ushort* WT = (ushort*)(ws + 11 * U);
    const size_t DD = (size_t)D_ * D_;
    const size_t DF = (size_t)D_ * F_;
    ushort* WTR = WT;
    ushort* WTK = WTR + DD;
    ushort* WTV = WTK + DD;
    ushort* WTO = WTV + DD;
    ushort* WTGU = WTO + DD;          // interleaved gate|up [8192,1024]
    ushort* WTD = WTGU + 2 * DF;
    ushort* WTw1 = WTD + DF;
    ushort* WTw2 = WTw1 + 64 * 1024;
    ushort* WTa1 = WTw2 + 64 * 1024;
    ushort* WTa2 = WTa1 + 64 * 1024;
    ushort* WTv1 = WTa2 + 64 * 1024;
    ushort* WTv2 = WTv1 + 32 * 1024;
    ushort* WTg1 = WTv2 + 32 * 1024;
    ushort* WTg2 = WTg1 + 128 * 1024;
    ushort* Lw = WTg2 + 128 * 1024;
    ushort* La = Lw + (size_t)T_ * 64;
    ushort* Lv = La + (size_t)T_ * 64;
    ushort* Lg = Lv + (size_t)T_ * 32;

    float* out_x = (float*)d_out;
    float* out_xn_last = out_x + (size_t)T_ * D_;
    float* out_state = out_xn_last + D_;

    // --- all 15 weight transposes in ONE launch (gate/up -> interleaved) ---
    TPack tp;
    int toff = 0, ti = 0;
    auto addT = [&](const float* in, ushort* out, int K, int N, int mode) {
        tp.d[ti].in = in; tp.d[ti].out = out; tp.d[ti].K = K; tp.d[ti].N = N;
        tp.d[ti].off = toff; tp.d[ti].mode = mode;
        toff += (N / 32) * (K / 32); ++ti;
    };
    addT(R_, WTR, D_, D_, 0);
    addT(K_, WTK, D_, D_, 0);
    addT(V_, WTV, D_, D_, 0);
    addT(O_, WTO, D_, D_, 0);
    addT(gate_w, WTGU, D_, F_, 1);
    addT(up_w, WTGU, D_, F_, 2);
    addT(down_w, WTD, F_, D_, 0);
    addT(w1, WTw1, D_, 64, 0);
    addT(w2, WTw2, 64, D_, 0);
    addT(a1, WTa1, D_, 64, 0);
    addT(a2, WTa2, 64, D_, 0);
    addT(v1, WTv1, D_, 32, 0);
    addT(v2, WTv2, 32, D_, 0);
    addT(g1, WTg1, D_, 128, 0);
    addT(g2, WTg2, 128, D_, 0);
    transpose_cast_multi<<<toff, 256, 0, stream>>>(tp);

    // 1. fused ln1 + token shift -> bf16 xr..xg + xn_last
    ln_shift_kernel<<<T_, 256, 0, stream>>>(x, x_prev, ln1_w,
                                            x_r, x_w, x_k, x_v, x_a, x_g,
                                            XR, XW, XK, XV, XA, XG, out_xn_last);
    // 2-5. r/k/v + 4 LoRA stage-1 GEMMs in ONE launch (r dual-writes fp32+bf16)
    auto mkmm = [](const ushort* A, const ushort* BT, float* Cf, ushort* Cb,
                   const float* res, const float* res2, const float* bias,
                   int Ntot, int K, int epi) {
        MMDesc m{A, BT, Cf, Cb, res, res2, bias, Ntot, K, epi};
        return m;
    };
    MMPack<7> pa;
    pa.d[0] = mkmm(XR, WTR, u_r, Rb, nullptr, nullptr, nullptr, D_, D_, 0);
    pa.d[1] = mkmm(XK, WTK, u_k, nullptr, nullptr, nullptr, nullptr, D_, D_, 0);
    pa.d[2] = mkmm(XV, WTV, u_v, nullptr, nullptr, nullptr, nullptr, D_, D_, 0);
    pa.d[3] = mkmm(XW, WTw1, nullptr, Lw, nullptr, nullptr, nullptr, 64,  D_, 3);  // tanh
    pa.d[4] = mkmm(XA, WTa1, nullptr, La, nullptr, nullptr, nullptr, 64,  D_, 0);
    pa.d[5] = mkmm(XV, WTv1, nullptr, Lv, nullptr, nullptr, nullptr, 32,  D_, 0);
    pa.d[6] = mkmm(XG, WTg1, nullptr, Lg, nullptr, nullptr, nullptr, 128, D_, 4);  // sigmoid
    mfma_gemm_multi<7><<<dim3(8, 16, 7), 256, 0, stream>>>(pa);
    // 6. LoRA stage-2 (decay / a_sig / v-lerp); g deferred (u_g = Lbuf)
    MMPack<3> pb;
    pb.d[0] = mkmm(Lw, WTw2, u_dc, nullptr, nullptr, nullptr, w0, D_, 64,  6);  // decay
    pb.d[1] = mkmm(La, WTa2, u_ao, nullptr, nullptr, nullptr, a0, D_, 64,  5);  // a_sig
    pb.d[2] = mkmm(Lv, WTv2, u_v,  nullptr, u_v, v_first,     v0, D_, 32,  7);  // v lerp
    mfma_gemm_multi<3><<<dim3(8, 16, 3), 256, 0, stream>>>(pb);
    // 7. kk / mb (bf16) / k-mod (fp32 + bf16)
    kk_kernel<<<T_ * H_ / 4, 256, 0, stream>>>(u_k, u_ao, k_k, k_a, KKb, MBb, Kb);
    // 8. chunked scan: pass1 (bf16 streams) -> pair-merge -> serial-32 -> odd-fill
    scan_pass1<<<NCHUNK * H_, 64, 0, stream>>>(Rb, u_dc, Kb, u_v, KKb, MBb,
                                               Pbuf, Lbuf, zbuf, olbuf);
    merge_pairs<<<16 * 32, 64, 0, stream>>>(Pbuf, Lbuf);
    scan_combine<<<H_ * 4, 256, 0, stream>>>(state, Pbuf, Lbuf, SstT, out_state);
    scan_oddfill<<<16 * 32 * 4, 256, 0, stream>>>(Pbuf, Lbuf, SstT);
    // 8b. deferred g GEMM (Lbuf dead -> u_g writable)
    mfma_gemm<float, false><<<dim3(8, 16), 256, 0, stream>>>(
        Lg, WTg2, u_g, nullptr, T_, D_, 128, 128, 0);
    // 9. fused fix + bonus + gate -> OG bf16
    scan_fix<<<(T_ / 16) * H_, 256, 0, stream>>>(zbuf, olbuf, SstT,
                                                 u_r, u_k, u_v, u_g, r_k, OG);
    // 10. O-proj split-K2 -> fp32 partials at ws+4U, 256 blocks
    mfma_gemm<float, true><<<dim3(8, 16, 2), 256, 0, stream>>>(
        OG, WTO, Opart, nullptr, T_, D_, D_, 512, 0);
    // 11. fused: out_x = x + p0 + p1; ln2(out_x) -> XM bf16
    rmsnorm_reduce2<<<T_, 256, 0, stream>>>(x, Opart, Opart + U, ln2_w, out_x, XM);
    // 12. MLP gate|up with FUSED swiglu epilogue -> Hbuf bf16 [T,4096]
    mfma_gemm<ushort, false><<<dim3(64, 16), 256, 0, stream>>>(
        XM, WTGU, Hbuf, nullptr, T_, 2 * F_, D_, D_, 2);
    // 13. down split-K4 -> fp32 partials over ws..4U, 512 blocks
    mfma_gemm<float, true><<<dim3(8, 16, 4), 256, 0, stream>>>(
        Hbuf, WTD, Dpart, nullptr, T_, D_, F_, 1024, 0);
    // 14. out_x += sum of 4 partials
    add4_kernel<<<(int)(U / 4 / 256), 256, 0, stream>>>(out_x, Dpart, (int)(U / 4));
}

// Round 11
// 580.455 us; speedup vs baseline: 1.1160x; 1.0198x over previous
//
#include <hip/hip_runtime.h>
#include <math.h>

// Problem constants (B=1)
#define T_ 2048
#define D_ 1024
#define H_ 16
#define N_ 64
#define F_ 4096
#define NCHUNK 64
#define CLEN 32

typedef __attribute__((ext_vector_type(8))) short bf16x8;
typedef __attribute__((ext_vector_type(4))) float f32x4;
typedef __attribute__((address_space(3))) unsigned int lds_u32_t;
typedef __attribute__((address_space(1))) const unsigned int glb_u32_t;

static __device__ __forceinline__ float sigf(float x) { return 1.0f / (1.0f + __expf(-x)); }

static __device__ __forceinline__ ushort f2bf(float f) {
    union { float f; unsigned u; } c; c.f = f;
    unsigned r = (c.u + 0x7FFFu + ((c.u >> 16) & 1u)) >> 16;
    return (ushort)r;
}
static __device__ __forceinline__ float bf2f(ushort h) {
    union { unsigned u; float f; } c; c.u = ((unsigned)h) << 16;
    return c.f;
}

static __device__ __forceinline__ void st4(float* p, float4 v) { *(float4*)p = v; }
static __device__ __forceinline__ void st4(ushort* p, float4 v) {
    ushort4 o; o.x = f2bf(v.x); o.y = f2bf(v.y); o.z = f2bf(v.z); o.w = f2bf(v.w);
    *(ushort4*)p = o;
}

// ---------------------------------------------------------------------------
// FUSED ln1 + token shift (unchanged).
// ---------------------------------------------------------------------------
__global__ __launch_bounds__(256) void ln_shift_kernel(
    const float* __restrict__ x, const float* __restrict__ x_prev,
    const float* __restrict__ w,
    const float* __restrict__ cr, const float* __restrict__ cw, const float* __restrict__ ck,
    const float* __restrict__ cv, const float* __restrict__ ca, const float* __restrict__ cg,
    ushort* __restrict__ xr, ushort* __restrict__ xw, ushort* __restrict__ xk,
    ushort* __restrict__ xv, ushort* __restrict__ xa, ushort* __restrict__ xg,
    float* __restrict__ last) {
    const int t = blockIdx.x;
    const int tid = threadIdx.x;
    const float4* x4 = (const float4*)x;
    float4 xc = x4[t * 256 + tid];
    float4 xp = (t == 0) ? ((const float4*)x_prev)[tid] : x4[(t - 1) * 256 + tid];
    float ssc = xc.x * xc.x + xc.y * xc.y + xc.z * xc.z + xc.w * xc.w;
    float ssp = xp.x * xp.x + xp.y * xp.y + xp.z * xp.z + xp.w * xp.w;
    ssc += __shfl_xor(ssc, 1); ssp += __shfl_xor(ssp, 1);
    ssc += __shfl_xor(ssc, 2); ssp += __shfl_xor(ssp, 2);
    ssc += __shfl_xor(ssc, 4); ssp += __shfl_xor(ssp, 4);
    ssc += __shfl_xor(ssc, 8); ssp += __shfl_xor(ssp, 8);
    ssc += __shfl_xor(ssc, 16); ssp += __shfl_xor(ssp, 16);
    ssc += __shfl_xor(ssc, 32); ssp += __shfl_xor(ssp, 32);
    __shared__ float redc[4], redp[4];
    if ((tid & 63) == 0) { redc[tid >> 6] = ssc; redp[tid >> 6] = ssp; }
    __syncthreads();
    const float totc = redc[0] + redc[1] + redc[2] + redc[3];
    const float totp = redp[0] + redp[1] + redp[2] + redp[3];
    const float sc = rsqrtf(totc * (1.0f / (float)D_) + 1e-6f);
    const float sp = rsqrtf(totp * (1.0f / (float)D_) + 1e-6f);
    float4 wv = ((const float4*)w)[tid];
    float4 cur, prev;
    cur.x = wv.x * xc.x * sc; cur.y = wv.y * xc.y * sc;
    cur.z = wv.z * xc.z * sc; cur.w = wv.w * xc.w * sc;
    if (t == 0) {
        prev = xp;  // raw x_prev per reference
    } else {
        prev.x = wv.x * xp.x * sp; prev.y = wv.y * xp.y * sp;
        prev.z = wv.z * xp.z * sp; prev.w = wv.w * xp.w * sp;
    }
    float4 xx;
    xx.x = prev.x - cur.x; xx.y = prev.y - cur.y;
    xx.z = prev.z - cur.z; xx.w = prev.w - cur.w;
    const size_t ob = (size_t)t * D_ + tid * 4;
#define APPLY(dst, c)                                   \
    {                                                   \
        float4 cc = ((const float4*)c)[tid];            \
        float4 o;                                       \
        o.x = cur.x + xx.x * cc.x;                      \
        o.y = cur.y + xx.y * cc.y;                      \
        o.z = cur.z + xx.z * cc.z;                      \
        o.w = cur.w + xx.w * cc.w;                      \
        st4(dst + ob, o);                               \
    }
    APPLY(xr, cr)
    APPLY(xw, cw)
    APPLY(xk, ck)
    APPLY(xv, cv)
    APPLY(xa, ca)
    APPLY(xg, cg)
#undef APPLY
    if (t == T_ - 1) ((float4*)last)[tid] = cur;
}

// ---------------------------------------------------------------------------
// Fused: v = x + p0 + p1; write resid AND rmsnorm(v)*w -> bf16 xm.
// ---------------------------------------------------------------------------
__global__ __launch_bounds__(256) void rmsnorm_reduce2(
    const float* __restrict__ x, const float* __restrict__ p0, const float* __restrict__ p1,
    const float* __restrict__ w, float* __restrict__ resid_out, ushort* __restrict__ xm) {
    const int t = blockIdx.x;
    const int tid = threadIdx.x;
    const size_t base = (size_t)t * D_ + tid * 4;
    float4 v = *(const float4*)(x + base);
    float4 a = *(const float4*)(p0 + base);
    float4 b = *(const float4*)(p1 + base);
    v.x += a.x + b.x; v.y += a.y + b.y; v.z += a.z + b.z; v.w += a.w + b.w;
    st4(resid_out + base, v);
    float ss = v.x * v.x + v.y * v.y + v.z * v.z + v.w * v.w;
    ss += __shfl_xor(ss, 1);
    ss += __shfl_xor(ss, 2);
    ss += __shfl_xor(ss, 4);
    ss += __shfl_xor(ss, 8);
    ss += __shfl_xor(ss, 16);
    ss += __shfl_xor(ss, 32);
    __shared__ float red[4];
    if ((tid & 63) == 0) red[tid >> 6] = ss;
    __syncthreads();
    float tot = red[0] + red[1] + red[2] + red[3];
    float scale = rsqrtf(tot * (1.0f / (float)D_) + 1e-6f);
    float4 wv = ((const float4*)w)[tid];
    float4 o;
    o.x = wv.x * v.x * scale;
    o.y = wv.y * v.y * scale;
    o.z = wv.z * v.z * scale;
    o.w = wv.w * v.w * scale;
    st4(xm + base, o);
}

// out[i] += p0[i]+p1[i]+p2[i]+p3[i]  (split-K4 reduce, float4-strided)
__global__ __launch_bounds__(256) void add4_kernel(float* __restrict__ out,
                                                   const float* __restrict__ p,
                                                   int n4slice) {
    const int i = blockIdx.x * 256 + threadIdx.x;  // float4 index
    const float4* p4 = (const float4*)p;
    float4 o = ((const float4*)out)[i];
    float4 a = p4[i], b = p4[i + n4slice], c = p4[i + 2 * n4slice], d = p4[i + 3 * n4slice];
    o.x += (a.x + b.x) + (c.x + d.x);
    o.y += (a.y + b.y) + (c.y + d.y);
    o.z += (a.z + b.z) + (c.z + d.z);
    o.w += (a.w + b.w) + (c.w + d.w);
    ((float4*)out)[i] = o;
}

// ---------------------------------------------------------------------------
// Merged weight transpose + cast (mode 1/2 = gate/up 16-col interleave).
// ---------------------------------------------------------------------------
struct TDesc { const float* in; ushort* out; int K, N, off, mode; };
struct TPack { TDesc d[15]; };

__global__ __launch_bounds__(256) void transpose_cast_multi(TPack p) {
    __shared__ float tile[32][33];
    const int bid = blockIdx.x;
    int di = 0;
#pragma unroll
    for (int i = 1; i < 15; i++)
        if (bid >= p.d[i].off) di = i;
    const TDesc d = p.d[di];
    const int local = bid - d.off;
    const int nt = d.N >> 5;
    const int bx = local % nt, by = local / nt;
    const int tx = threadIdx.x & 31, ty = threadIdx.x >> 5;  // 32 x 8
    const int n0 = bx * 32, k0 = by * 32;
#pragma unroll
    for (int i = 0; i < 4; i++)
        tile[ty + i * 8][tx] = d.in[(size_t)(k0 + ty + i * 8) * d.N + n0 + tx];
    __syncthreads();
#pragma unroll
    for (int i = 0; i < 4; i++) {
        const int n = n0 + ty + i * 8;
        int ro = n;
        if (d.mode == 1) ro = ((n >> 4) << 5) + (n & 15);
        else if (d.mode == 2) ro = ((n >> 4) << 5) + 16 + (n & 15);
        d.out[(size_t)ro * d.K + k0 + tx] = f2bf(tile[tx][ty + i * 8]);
    }
}

// ---------------------------------------------------------------------------
// bf16 MFMA GEMM, 2-phase double-buffered global_load_lds pipeline.
// epi: 0 none, 1 += res, 2 fused swiglu (16-col interleaved gate|up).
// ---------------------------------------------------------------------------
template <typename OutT, bool PARTIAL>
__global__ __launch_bounds__(256) void mfma_gemm(
    const ushort* __restrict__ A, const ushort* __restrict__ BT, OutT* __restrict__ C,
    const float* res, int M, int Ntot, int K, int klen, int epi) {
    __shared__ ushort As[2][128 * 32];
    __shared__ ushort Bs[2][128 * 32];
    const int tid = threadIdx.x;
    const int wave = tid >> 6, lane = tid & 63;
    const int wr = wave >> 1, wc = wave & 1;
    const int lrow = lane & 15, quad = lane >> 4;
    int bx = blockIdx.x, by = blockIdx.y;
    if (gridDim.x == 8 && gridDim.y == 16) {
        const int bid = by * 8 + bx;
        const int k = bid & 7, i = bid >> 3;
        bx = ((k & 1) << 2) + (i & 3);
        by = ((k >> 1) << 2) + (i >> 2);
    }
    const int m0 = by * 128, n0 = bx * 128;
    const int kbase = blockIdx.z * klen;
    const int srow = lane >> 2;
    const int scol = (lane & 3) << 3;

    f32x4 acc[4][4] = {};

    auto stage = [&](int buf, int kk) {
#pragma unroll
        for (int j = 0; j < 2; j++) {
            const int chunk = 2 * wave + j;  // 0..7
            const ushort* ga = A + (size_t)(m0 + chunk * 16 + srow) * K + kk + scol;
            __builtin_amdgcn_global_load_lds((glb_u32_t*)ga,
                                             (lds_u32_t*)&As[buf][chunk * 512], 16, 0, 0);
            const int brow = n0 + chunk * 16 + srow;
            if (brow < Ntot) {
                const ushort* gb = BT + (size_t)brow * K + kk + scol;
                __builtin_amdgcn_global_load_lds((glb_u32_t*)gb,
                                                 (lds_u32_t*)&Bs[buf][chunk * 512], 16, 0, 0);
            }
        }
    };

    stage(0, kbase);
    __syncthreads();
    int cur = 0;
    for (int k0 = kbase; k0 < kbase + klen; k0 += 32) {
        if (k0 + 32 < kbase + klen) stage(cur ^ 1, k0 + 32);
        bf16x8 af[4], bfr[4];
#pragma unroll
        for (int mi = 0; mi < 4; mi++)
            af[mi] = *(const bf16x8*)&As[cur][(wr * 64 + mi * 16 + lrow) * 32 + quad * 8];
#pragma unroll
        for (int ni = 0; ni < 4; ni++)
            bfr[ni] = *(const bf16x8*)&Bs[cur][(wc * 64 + ni * 16 + lrow) * 32 + quad * 8];
#pragma unroll
        for (int mi = 0; mi < 4; mi++)
#pragma unroll
            for (int ni = 0; ni < 4; ni++)
                acc[mi][ni] = __builtin_amdgcn_mfma_f32_16x16x32_bf16(af[mi], bfr[ni], acc[mi][ni], 0, 0, 0);
        __syncthreads();
        cur ^= 1;
    }

    const size_t zoff = PARTIAL ? (size_t)blockIdx.z * M * Ntot : 0;
    const int hstride = Ntot >> 1;  // epi==2 output stride
#pragma unroll
    for (int mi = 0; mi < 4; mi++) {
#pragma unroll
        for (int r = 0; r < 4; r++) {
            const int row = m0 + wr * 64 + mi * 16 + quad * 4 + r;
            if (epi == 2) {
                if constexpr (!PARTIAL && sizeof(OutT) == 2) {
#pragma unroll
                    for (int ni = 0; ni < 4; ni += 2) {
                        const int ci = n0 + wc * 64 + ni * 16 + lrow;  // gate col (interleaved)
                        const float gv = acc[mi][ni][r];
                        const float uv = acc[mi][ni + 1][r];
                        const int co = ((ci >> 5) << 4) + (ci & 15);
                        C[(size_t)row * hstride + co] = (OutT)f2bf(gv * sigf(gv) * uv);
                    }
                }
                continue;
            }
#pragma unroll
            for (int ni = 0; ni < 4; ni++) {
                const int col = n0 + wc * 64 + ni * 16 + lrow;
                if (col < Ntot) {
                    const size_t idx = (size_t)row * Ntot + col;
                    float val = acc[mi][ni][r];
                    if constexpr (PARTIAL) {
                        ((float*)C)[idx + zoff] = val;
                    } else {
                        if (epi == 1) val += res[idx];
                        if constexpr (sizeof(OutT) == 2) C[idx] = (OutT)f2bf(val);
                        else C[idx] = (OutT)val;
                    }
                }
            }
        }
    }
}

// ---------------------------------------------------------------------------
// Multi-GEMM: z-indexed descriptors, templated M-tile TM (64 or 128).
// TM=64 doubles the block count of the r/k/v slices (8x32 grid = 256 blocks
// each, ~3.5 active blocks/CU total) so the per-K-step vmcnt(0)+barrier
// latency is hidden by co-resident blocks (R10: 1.75/CU -> MfmaUtil 7.5%).
// Writes Cf (fp32) and/or Cb (bf16) -- BOTH when both set.
// epi: 0 none, 3 tanh, 4 sig, 5 sig(bias+v), 6 exp(-e^-.5*sig(bias+v)),
//      7 res+(res2-res)*sig(bias+v)
// ---------------------------------------------------------------------------
struct MMDesc {
    const ushort* A; const ushort* BT;
    float* Cf; ushort* Cb;
    const float* res; const float* res2; const float* bias;
    int Ntot, K, epi;
};
template <int NZ>
struct MMPack { MMDesc d[NZ]; };

template <int NZ, int TM>
__global__ __launch_bounds__(256) void mfma_gemm_multi(MMPack<NZ> p) {
    const MMDesc d = p.d[blockIdx.z];
    const int n0 = blockIdx.x * 128;
    if (n0 >= d.Ntot) return;  // uniform across block; no barrier crossed yet
    constexpr int MR = TM / 32;       // acc rows per wave
    __shared__ ushort As[2][TM * 32];
    __shared__ ushort Bs[2][128 * 32];
    const int tid = threadIdx.x;
    const int wave = tid >> 6, lane = tid & 63;
    const int wr = wave >> 1, wc = wave & 1;
    const int lrow = lane & 15, quad = lane >> 4;
    const int m0 = blockIdx.y * TM;
    const int srow = lane >> 2;
    const int scol = (lane & 3) << 3;
    const int K = d.K, Ntot = d.Ntot;

    f32x4 acc[MR][4] = {};

    auto stage = [&](int buf, int kk) {
#pragma unroll
        for (int j = 0; j < TM / 64; j++) {
            const int chunk = (TM / 64) * wave + j;   // A: TM/16 chunks total
            const ushort* ga = d.A + (size_t)(m0 + chunk * 16 + srow) * K + kk + scol;
            __builtin_amdgcn_global_load_lds((glb_u32_t*)ga,
                                             (lds_u32_t*)&As[buf][chunk * 512], 16, 0, 0);
        }
#pragma unroll
        for (int j = 0; j < 2; j++) {
            const int chunk = 2 * wave + j;           // B: 8 chunks (128 rows)
            const int brow = n0 + chunk * 16 + srow;
            if (brow < Ntot) {
                const ushort* gb = d.BT + (size_t)brow * K + kk + scol;
                __builtin_amdgcn_global_load_lds((glb_u32_t*)gb,
                                                 (lds_u32_t*)&Bs[buf][chunk * 512], 16, 0, 0);
            }
        }
    };

    stage(0, 0);
    __syncthreads();
    int cur = 0;
    for (int k0 = 0; k0 < K; k0 += 32) {
        if (k0 + 32 < K) stage(cur ^ 1, k0 + 32);
        bf16x8 af[MR], bfr[4];
#pragma unroll
        for (int mi = 0; mi < MR; mi++)
            af[mi] = *(const bf16x8*)&As[cur][(wr * (TM / 2) + mi * 16 + lrow) * 32 + quad * 8];
#pragma unroll
        for (int ni = 0; ni < 4; ni++)
            bfr[ni] = *(const bf16x8*)&Bs[cur][(wc * 64 + ni * 16 + lrow) * 32 + quad * 8];
#pragma unroll
        for (int mi = 0; mi < MR; mi++)
#pragma unroll
            for (int ni = 0; ni < 4; ni++)
                acc[mi][ni] = __builtin_amdgcn_mfma_f32_16x16x32_bf16(af[mi], bfr[ni], acc[mi][ni], 0, 0, 0);
        __syncthreads();
        cur ^= 1;
    }

#pragma unroll
    for (int mi = 0; mi < MR; mi++) {
#pragma unroll
        for (int r = 0; r < 4; r++) {
            const int row = m0 + wr * (TM / 2) + mi * 16 + quad * 4 + r;
#pragma unroll
            for (int ni = 0; ni < 4; ni++) {
                const int col = n0 + wc * 64 + ni * 16 + lrow;
                if (col < Ntot) {
                    const size_t idx = (size_t)row * Ntot + col;
                    float val = acc[mi][ni][r];
                    switch (d.epi) {
                        case 3: val = tanhf(val); break;
                        case 4: val = sigf(val); break;
                        case 5: val = sigf(d.bias[col] + val); break;
                        case 6: val = __expf(-0.60653065971263342f * sigf(d.bias[col] + val)); break;
                        case 7: {
                            float vr = d.res[idx];
                            val = vr + (d.res2[idx] - vr) * sigf(d.bias[col] + val);
                        } break;
                        default: break;
                    }
                    if (d.Cb) d.Cb[idx] = f2bf(val);
                    if (d.Cf) d.Cf[idx] = val;
                }
            }
        }
    }
}

// ---------------------------------------------------------------------------
// kk: normalize_per_head(k*k_k) -> bf16 kkb; mbb = bf16(-kk*a_sig);
// k-mod written BOTH fp32 (scan_fix bonus) and bf16 (scan stream).
// ---------------------------------------------------------------------------
__global__ __launch_bounds__(256) void kk_kernel(float* __restrict__ k,
                                                 const float* __restrict__ a_sig,
                                                 const float* __restrict__ k_k,
                                                 const float* __restrict__ k_a,
                                                 ushort* __restrict__ kkb,
                                                 ushort* __restrict__ mbb,
                                                 ushort* __restrict__ kb) {
    const int b = blockIdx.x * 4 + (threadIdx.x >> 6);
    const int t = b >> 4, h = b & 15;
    const int lane = threadIdx.x & 63;
    const size_t idx = (size_t)t * D_ + h * N_ + lane;
    const int wi = h * N_ + lane;
    const float kraw = k[idx];
    const float kv = kraw * k_k[wi];
    float ss = kv * kv;
    ss += __shfl_xor(ss, 1);
    ss += __shfl_xor(ss, 2);
    ss += __shfl_xor(ss, 4);
    ss += __shfl_xor(ss, 8);
    ss += __shfl_xor(ss, 16);
    ss += __shfl_xor(ss, 32);
    const float nrm = fmaxf(sqrtf(ss), 1e-12f);
    const float kkn = kv / nrm;
    kkb[idx] = f2bf(kkn);
    mbb[idx] = f2bf(-kkn * a_sig[idx]);
    const float kn = kraw * (1.0f + (a_sig[idx] - 1.0f) * k_a[wi]);
    k[idx] = kn;
    kb[idx] = f2bf(kn);
}

// ---------------------------------------------------------------------------
// Chunked scan pass 1, merged P+L, bf16 streams (unchanged from R10; ~74us,
// near the mixed LDS-issue/VALU floor).
// ---------------------------------------------------------------------------
#define FOR16(M) M(0) M(1) M(2) M(3) M(4) M(5) M(6) M(7) \
                 M(8) M(9) M(10) M(11) M(12) M(13) M(14) M(15)

__global__ __launch_bounds__(64, 1) void scan_pass1(
    const ushort* __restrict__ gRb, const float* __restrict__ gD,
    const ushort* __restrict__ gKb, const float* __restrict__ gV,
    const ushort* __restrict__ gKKb, const ushort* __restrict__ gMBb,
    float* __restrict__ Pbuf, float* __restrict__ Lbuf,
    float* __restrict__ zbuf, float* __restrict__ olbuf) {
    const int bid = blockIdx.x;          // 0..NCHUNK*H-1
    const int h = bid & 15;
    const int c = bid >> 4;
    const int lane = threadIdx.x;        // row index
    const int hb = h * N_;
    const int t0 = c * CLEN;
    const int tend = t0 + CLEN - 1;

    __shared__ __align__(16) unsigned char ring[2 * 1024];

    const int rsel = lane >> 4;
    const int sub = lane & 15;
    const ushort* pB = (rsel == 0 ? gRb : rsel == 1 ? gKb : rsel == 2 ? gKKb : gMBb)
                       + (size_t)t0 * D_ + hb + sub * 4;
    const float* pDV = (rsel == 0 ? gD : gV) + (size_t)t0 * D_ + hb + sub * 4;

    // P state: identity rows; L state: zero.
#define DECLP(q) f32x4 sp##q = {(lane == 4 * q + 0) ? 1.0f : 0.0f, \
                                (lane == 4 * q + 1) ? 1.0f : 0.0f, \
                                (lane == 4 * q + 2) ? 1.0f : 0.0f, \
                                (lane == 4 * q + 3) ? 1.0f : 0.0f};
    FOR16(DECLP)
#undef DECLP
#define DECLL(q) f32x4 sl##q = {0.f, 0.f, 0.f, 0.f};
    FOR16(DECLL)
#undef DECLL

    ushort4 b0, b1, b2, b3;
    float4 v0, v1, v2, v3;

#define LOADQ(qb, qd, tt) {                                                  \
        const size_t _adv = (size_t)((tt) - t0) * D_;                        \
        qb = *(const ushort4*)(pB + _adv);                                   \
        if (lane < 32) qd = *(const float4*)(pDV + _adv); }
#define WRITEQ(sl_, qb, qd) {                                                \
        *(ushort4*)(ring + (sl_) * 1024 + rsel * 128 + sub * 8) = qb;        \
        if (lane < 32)                                                       \
            *(float4*)(ring + (sl_) * 1024 + 512 + rsel * 256 + sub * 16) = qd; }
#define UNPK(u, lo, hi) {                                                    \
        lo.x = __uint_as_float((u).x << 16);                                 \
        lo.y = __uint_as_float((u).x & 0xFFFF0000u);                         \
        lo.z = __uint_as_float((u).y << 16);                                 \
        lo.w = __uint_as_float((u).y & 0xFFFF0000u);                         \
        hi.x = __uint_as_float((u).z << 16);                                 \
        hi.y = __uint_as_float((u).z & 0xFFFF0000u);                         \
        hi.z = __uint_as_float((u).w << 16);                                 \
        hi.w = __uint_as_float((u).w & 0xFFFF0000u); }
#define PAp(p, qa, qb_) {                                                    \
        const uint4 u = *(const uint4*)(sbKK + (p) * 16);                    \
        f32x4 lo, hi; UNPK(u, lo, hi);                                       \
        pacc += sp##qa * lo + sp##qb_ * hi;                                  \
        lacc += sl##qa * lo + sl##qb_ * hi; }
#define PBp(p, qa, qb_) {                                                    \
        const uint4 ur = *(const uint4*)(sbR + (p) * 16);                    \
        const uint4 uk = *(const uint4*)(sbK + (p) * 16);                    \
        const uint4 um = *(const uint4*)(sbMB + (p) * 16);                   \
        f32x4 rlo, rhi, klo, khi, mlo, mhi;                                  \
        UNPK(ur, rlo, rhi); UNPK(uk, klo, khi); UNPK(um, mlo, mhi);          \
        const f32x4 dlo = sbD[2 * (p)], dhi = sbD[2 * (p) + 1];              \
        sp##qa = sp##qa * dlo + mlo * sapP;                                  \
        sl##qa = sl##qa * dlo + (mlo * sapL + klo * vv);                     \
        oP += sp##qa * rlo; oL += sl##qa * rlo;                              \
        sp##qb_ = sp##qb_ * dhi + mhi * sapP;                                \
        sl##qb_ = sl##qb_ * dhi + (mhi * sapL + khi * vv);                   \
        oP += sp##qb_ * rhi; oL += sl##qb_ * rhi; }
#define COMPUTE(sl_, tt) {                                                   \
        const unsigned char* sb = (const unsigned char*)ring + (sl_) * 1024; \
        const unsigned char* sbR = sb;                                       \
        const unsigned char* sbK = sb + 128;                                 \
        const unsigned char* sbKK = sb + 256;                                \
        const unsigned char* sbMB = sb + 384;                                \
        const f32x4* sbD = (const f32x4*)(sb + 512);                         \
        const float* sbV = (const float*)(sb + 768);                         \
        f32x4 pacc = {0.f, 0.f, 0.f, 0.f};                                   \
        f32x4 lacc = {0.f, 0.f, 0.f, 0.f};                                   \
        PAp(0, 0, 1) PAp(1, 2, 3) PAp(2, 4, 5) PAp(3, 6, 7)                  \
        PAp(4, 8, 9) PAp(5, 10, 11) PAp(6, 12, 13) PAp(7, 14, 15)            \
        const float sapP = (pacc.x + pacc.y) + (pacc.z + pacc.w);            \
        const float sapL = (lacc.x + lacc.y) + (lacc.z + lacc.w);            \
        const float vv = sbV[lane];                                          \
        f32x4 oP = {0.f, 0.f, 0.f, 0.f};                                     \
        f32x4 oL = {0.f, 0.f, 0.f, 0.f};                                     \
        PBp(0, 0, 1) PBp(1, 2, 3) PBp(2, 4, 5) PBp(3, 6, 7)                  \
        PBp(4, 8, 9) PBp(5, 10, 11) PBp(6, 12, 13) PBp(7, 14, 15)            \
        zbuf[(size_t)(tt) * D_ + hb + lane] = (oP.x + oP.y) + (oP.z + oP.w); \
        olbuf[(size_t)(tt) * D_ + hb + lane] = (oL.x + oL.y) + (oL.z + oL.w); }

    // prologue: 4-deep register pipeline; slot0 primed with t0
    LOADQ(b0, v0, t0)
    LOADQ(b1, v1, t0 + 1)
    LOADQ(b2, v2, t0 + 2)
    LOADQ(b3, v3, t0 + 3)
    WRITEQ(0, b0, v0)

    for (int t = t0; t < t0 + CLEN; t += 4) {
        WRITEQ(1, b1, v1)                                      // data t+1
        LOADQ(b0, v0, (t + 4 > tend ? tend : t + 4))
        COMPUTE(0, t)
        WRITEQ(0, b2, v2)                                      // data t+2
        LOADQ(b1, v1, (t + 5 > tend ? tend : t + 5))
        COMPUTE(1, t + 1)
        WRITEQ(1, b3, v3)                                      // data t+3
        LOADQ(b2, v2, (t + 6 > tend ? tend : t + 6))
        COMPUTE(0, t + 2)
        WRITEQ(0, b0, v0)                                      // data t+4
        LOADQ(b3, v3, (t + 7 > tend ? tend : t + 7))
        COMPUTE(1, t + 3)
    }
#undef COMPUTE
#undef PBp
#undef PAp
#undef UNPK
#undef WRITEQ
#undef LOADQ

    const size_t base = ((size_t)c * 16 + h) * 4096 + (size_t)lane * 64;
#define STP(q) *(f32x4*)(Pbuf + base + 4 * q) = sp##q;
    FOR16(STP)
#undef STP
#define STL(q) *(f32x4*)(Lbuf + base + 4 * q) = sl##q;
    FOR16(STL)
#undef STL
}

// ---------------------------------------------------------------------------
// Parallel pair merge (unchanged).
// ---------------------------------------------------------------------------
__global__ __launch_bounds__(64) void merge_pairs(float* __restrict__ Pbuf,
                                                  float* __restrict__ Lbuf) {
    const int h = blockIdx.x & 15, j = blockIdx.x >> 4;  // j 0..31
    const int t = threadIdx.x;
    __shared__ float PaT[64][65];
    __shared__ float LaT[64][65];
    __shared__ float Pb[64][68];
    const size_t ca = ((size_t)(2 * j) * 16 + h) * 4096;
    const size_t cb = ((size_t)(2 * j + 1) * 16 + h) * 4096;
#pragma unroll
    for (int q = 0; q < 16; q++) {
        const int idx = t + q * 64;  // float4 index 0..1023
        const int r = idx >> 4, c4 = (idx & 15) << 2;
        float4 pa = *(const float4*)(Pbuf + ca + (size_t)r * 64 + c4);
        float4 la = *(const float4*)(Lbuf + ca + (size_t)r * 64 + c4);
        float4 pb = *(const float4*)(Pbuf + cb + (size_t)r * 64 + c4);
        PaT[c4 + 0][r] = pa.x; PaT[c4 + 1][r] = pa.y;
        PaT[c4 + 2][r] = pa.z; PaT[c4 + 3][r] = pa.w;
        LaT[c4 + 0][r] = la.x; LaT[c4 + 1][r] = la.y;
        LaT[c4 + 2][r] = la.z; LaT[c4 + 3][r] = la.w;
        *(float4*)&Pb[r][c4] = pb;
    }
    __syncthreads();
    const int cg = (t & 3) << 4;  // col base 0/16/32/48
    const int r0 = (t >> 2) << 2; // row base 0..60 step 4
    float4 accP[4][4] = {};
    float4 accL[4][4];
#pragma unroll
    for (int rr = 0; rr < 4; rr++)
#pragma unroll
        for (int e = 0; e < 4; e++)
            accL[rr][e] = *(const float4*)(Lbuf + cb + (size_t)(r0 + rr) * 64 + cg + 4 * e);
    for (int m = 0; m < 64; m++) {
        float4 pb4[4];
#pragma unroll
        for (int e = 0; e < 4; e++) pb4[e] = *(const float4*)&Pb[m][cg + 4 * e];
#pragma unroll
        for (int rr = 0; rr < 4; rr++) {
            const float pa = PaT[m][r0 + rr];
            const float la = LaT[m][r0 + rr];
#pragma unroll
            for (int e = 0; e < 4; e++) {
                accP[rr][e].x = fmaf(pa, pb4[e].x, accP[rr][e].x);
                accP[rr][e].y = fmaf(pa, pb4[e].y, accP[rr][e].y);
                accP[rr][e].z = fmaf(pa, pb4[e].z, accP[rr][e].z);
                accP[rr][e].w = fmaf(pa, pb4[e].w, accP[rr][e].w);
                accL[rr][e].x = fmaf(la, pb4[e].x, accL[rr][e].x);
                accL[rr][e].y = fmaf(la, pb4[e].y, accL[rr][e].y);
                accL[rr][e].z = fmaf(la, pb4[e].z, accL[rr][e].z);
                accL[rr][e].w = fmaf(la, pb4[e].w, accL[rr][e].w);
            }
        }
    }
#pragma unroll
    for (int rr = 0; rr < 4; rr++)
#pragma unroll
        for (int e = 0; e < 4; e++) {
            *(float4*)(Pbuf + cb + (size_t)(r0 + rr) * 64 + cg + 4 * e) = accP[rr][e];
            *(float4*)(Lbuf + cb + (size_t)(r0 + rr) * 64 + cg + 4 * e) = accL[rr][e];
        }
}

// ---------------------------------------------------------------------------
// Serial combine over 32 super-chunks with register prefetch (unchanged).
// ---------------------------------------------------------------------------
__global__ __launch_bounds__(256) void scan_combine(
    const float* __restrict__ state_in, const float* __restrict__ Pbuf,
    const float* __restrict__ Lbuf, float* __restrict__ SstT, float* __restrict__ state_out) {
    const int h = blockIdx.x >> 2, rg = blockIdx.x & 3;
    const int tid = threadIdx.x;
    const int i = tid >> 4, j4 = (tid & 15) << 2;
    const int gi = rg * 16 + i;
    __shared__ float Sl[16][68];
    __shared__ float Pl[64][68];

    float4 sv = *(const float4*)(state_in + (size_t)h * 4096 + gi * 64 + j4);
    *(float4*)&Sl[i][j4] = sv;

    float4 rp0, rp1, rp2, rp3, rl;
    {
        const size_t cb = ((size_t)1 * 16 + h) * 4096;  // super-chunk 0 = slot 1
        rp0 = *(const float4*)(Pbuf + cb + (size_t)(i +  0) * 64 + j4);
        rp1 = *(const float4*)(Pbuf + cb + (size_t)(i + 16) * 64 + j4);
        rp2 = *(const float4*)(Pbuf + cb + (size_t)(i + 32) * 64 + j4);
        rp3 = *(const float4*)(Pbuf + cb + (size_t)(i + 48) * 64 + j4);
        rl  = *(const float4*)(Lbuf + cb + (size_t)gi * 64 + j4);
    }
    __syncthreads();

    for (int c = 0; c < NCHUNK / 2; c++) {
        *(float4*)&Pl[i +  0][j4] = rp0;
        *(float4*)&Pl[i + 16][j4] = rp1;
        *(float4*)&Pl[i + 32][j4] = rp2;
        *(float4*)&Pl[i + 48][j4] = rp3;
        float4 acc = rl;
        const size_t so = ((size_t)(2 * c) * 16 + h) * 4096;
        float4 scur = *(const float4*)&Sl[i][j4];
        SstT[so + (size_t)(j4 + 0) * 64 + gi] = scur.x;
        SstT[so + (size_t)(j4 + 1) * 64 + gi] = scur.y;
        SstT[so + (size_t)(j4 + 2) * 64 + gi] = scur.z;
        SstT[so + (size_t)(j4 + 3) * 64 + gi] = scur.w;
        __syncthreads();  // Pl visible to all waves
        if (c + 1 < NCHUNK / 2) {  // prefetch next super-chunk (slot 2c+3)
            const size_t cb = ((size_t)(2 * c + 3) * 16 + h) * 4096;
            rp0 = *(const float4*)(Pbuf + cb + (size_t)(i +  0) * 64 + j4);
            rp1 = *(const float4*)(Pbuf + cb + (size_t)(i + 16) * 64 + j4);
            rp2 = *(const float4*)(Pbuf + cb + (size_t)(i + 32) * 64 + j4);
            rp3 = *(const float4*)(Pbuf + cb + (size_t)(i + 48) * 64 + j4);
            rl  = *(const float4*)(Lbuf + cb + (size_t)gi * 64 + j4);
        }
#pragma unroll 8
        for (int m = 0; m < 64; m++) {
            const float smv = Sl[i][m];
            const float4 p4 = *(const float4*)&Pl[m][j4];
            acc.x = fmaf(smv, p4.x, acc.x);
            acc.y = fmaf(smv, p4.y, acc.y);
            acc.z = fmaf(smv, p4.z, acc.z);
            acc.w = fmaf(smv, p4.w, acc.w);
        }
        __syncthreads();
        *(float4*)&Sl[i][j4] = acc;
    }
    *(float4*)(state_out + (size_t)h * 4096 + gi * 64 + j4) = *(const float4*)&Sl[i][j4];
}

// ---------------------------------------------------------------------------
// Odd-fill: S_{2j+1} = S_{2j} @ P_{2j} + L_{2j} (even slots). (unchanged)
// ---------------------------------------------------------------------------
__global__ __launch_bounds__(256) void scan_oddfill(
    const float* __restrict__ Pbuf, const float* __restrict__ Lbuf,
    float* __restrict__ SstT) {
    const int b = blockIdx.x;
    const int rg = b & 3, h = (b >> 2) & 15, j = b >> 6;  // j 0..31
    const int tid = threadIdx.x;
    const int i = tid >> 4, j4 = (tid & 15) << 2;
    const int gi = rg * 16 + i;
    __shared__ float Sl[16][68];
    __shared__ float Pl[64][68];
    const size_t ce = ((size_t)(2 * j) * 16 + h) * 4096;
    const size_t co = ((size_t)(2 * j + 1) * 16 + h) * 4096;
    {
        float4 s;
        s.x = SstT[ce + (size_t)(j4 + 0) * 64 + gi];
        s.y = SstT[ce + (size_t)(j4 + 1) * 64 + gi];
        s.z = SstT[ce + (size_t)(j4 + 2) * 64 + gi];
        s.w = SstT[ce + (size_t)(j4 + 3) * 64 + gi];
        *(float4*)&Sl[i][j4] = s;
    }
#pragma unroll
    for (int q = 0; q < 4; q++) {
        const int prq = i + q * 16;
        *(float4*)&Pl[prq][j4] = *(const float4*)(Pbuf + ce + (size_t)prq * 64 + j4);
    }
    __syncthreads();
    float4 acc = *(const float4*)(Lbuf + ce + (size_t)gi * 64 + j4);
#pragma unroll 8
    for (int m = 0; m < 64; m++) {
        const float smv = Sl[i][m];
        const float4 p4 = *(const float4*)&Pl[m][j4];
        acc.x = fmaf(smv, p4.x, acc.x);
        acc.y = fmaf(smv, p4.y, acc.y);
        acc.z = fmaf(smv, p4.z, acc.z);
        acc.w = fmaf(smv, p4.w, acc.w);
    }
    SstT[co + (size_t)(j4 + 0) * 64 + gi] = acc.x;
    SstT[co + (size_t)(j4 + 1) * 64 + gi] = acc.y;
    SstT[co + (size_t)(j4 + 2) * 64 + gi] = acc.z;
    SstT[co + (size_t)(j4 + 3) * 64 + gi] = acc.w;
}

// ---------------------------------------------------------------------------
// FUSED fix + bonus + gate (unchanged).
// ---------------------------------------------------------------------------
__global__ __launch_bounds__(256) void scan_fix(
    const float* __restrict__ zbuf, const float* __restrict__ olbuf,
    const float* __restrict__ SstT,
    const float* __restrict__ r, const float* __restrict__ k,
    const float* __restrict__ v, const float* __restrict__ g,
    const float* __restrict__ r_k, ushort* __restrict__ og) {
    const int tg = blockIdx.x >> 4, h = blockIdx.x & 15;
    const int hb = h * N_;
    const int tid = threadIdx.x;
    const int tok = tid >> 4, i4 = (tid & 15) << 2;
    const int tbase = tg * 16;
    const int c = tbase / CLEN;
    __shared__ float zl[16][68];
    __shared__ float Sl[64][68];

    *(float4*)&zl[tok][i4] = *(const float4*)(zbuf + (size_t)(tbase + tok) * D_ + hb + i4);
    const size_t cb = ((size_t)c * 16 + h) * 4096;
#pragma unroll
    for (int q = 0; q < 4; q++) {
        const int jr = (tid >> 4) + q * 16;
        *(float4*)&Sl[jr][i4] = *(const float4*)(SstT + cb + (size_t)jr * 64 + i4);
    }
    __syncthreads();
    const size_t tix = (size_t)(tbase + tok) * D_ + hb + i4;
    float4 acc = *(const float4*)(olbuf + tix);
#pragma unroll 8
    for (int j = 0; j < 64; j++) {
        const float zv = zl[tok][j];
        const float4 p4 = *(const float4*)&Sl[j][i4];
        acc.x = fmaf(zv, p4.x, acc.x);
        acc.y = fmaf(zv, p4.y, acc.y);
        acc.z = fmaf(zv, p4.z, acc.z);
        acc.w = fmaf(zv, p4.w, acc.w);
    }
    float4 rv = *(const float4*)(r + tix);
    float4 kv = *(const float4*)(k + tix);
    float4 rk = *(const float4*)(r_k + hb + i4);
    float cc = rv.x * kv.x * rk.x + rv.y * kv.y * rk.y +
               rv.z * kv.z * rk.z + rv.w * kv.w * rk.w;
    cc += __shfl_xor(cc, 1);
    cc += __shfl_xor(cc, 2);
    cc += __shfl_xor(cc, 4);
    cc += __shfl_xor(cc, 8);
    float4 vv = *(const float4*)(v + tix);
    float4 gv = *(const float4*)(g + tix);
    float4 o;
    o.x = (acc.x + cc * vv.x) * gv.x;
    o.y = (acc.y + cc * vv.y) * gv.y;
    o.z = (acc.z + cc * vv.z) * gv.z;
    o.w = (acc.w + cc * vv.w) * gv.w;
    st4(og + tix, o);
}

// ---------------------------------------------------------------------------
extern "C" void kernel_launch(void* const* d_in, const int* in_sizes, int n_in,
                              void* d_out, int out_size, void* d_ws, size_t ws_size,
                              hipStream_t stream) {
    const float* x      = (const float*)d_in[0];
    const float* x_prev = (const float*)d_in[1];
    const float* v_first= (const float*)d_in[2];
    const float* state  = (const float*)d_in[3];
    const float* ln1_w  = (const float*)d_in[4];
    const float* ln2_w  = (const float*)d_in[5];
    const float* x_r    = (const float*)d_in[6];
    const float* x_w    = (const float*)d_in[7];
    const float* x_k    = (const float*)d_in[8];
    const float* x_v    = (const float*)d_in[9];
    const float* x_a    = (const float*)d_in[10];
    const float* x_g    = (const float*)d_in[11];
    const float* w0     = (const float*)d_in[12];
    const float* w1     = (const float*)d_in[13];
    const float* w2     = (const float*)d_in[14];
    const float* a0     = (const float*)d_in[15];
    const float* a1     = (const float*)d_in[16];
    const float* a2     = (const float*)d_in[17];
    const float* v0     = (const float*)d_in[18];
    const float* v1     = (const float*)d_in[19];
    const float* v2     = (const float*)d_in[20];
    const float* g1     = (const float*)d_in[21];
    const float* g2     = (const float*)d_in[22];
    const float* k_k    = (const float*)d_in[23];
    const float* k_a    = (const float*)d_in[24];
    const float* r_k    = (const float*)d_in[25];
    const float* R_     = (const float*)d_in[26];
    const float* K_     = (const float*)d_in[27];
    const float* V_     = (const float*)d_in[28];
    const float* O_     = (const float*)d_in[29];
    const float* gate_w = (const float*)d_in[30];
    const float* up_w   = (const float*)d_in[31];
    const float* down_w = (const float*)d_in[32];

    float* ws = (float*)d_ws;
    const size_t U = (size_t)T_ * D_;  // 2M floats (8 MB)
    float* u_r  = ws;
    float* u_k  = ws + 1 * U;
    float* u_v  = ws + 2 * U;
    float* u_dc = ws + 3 * U;   // decay -> SstT[0:8MB]
    // ws+4U..6U: bf16 scan streams during scan; Opart/Hbuf later
    float* u_g  = ws + 6 * U;   // Lbuf[0:8MB] during scan; g AFTER oddfill
    float* u_ao = ws + 7 * U;   // a_sig -> Lbuf[8:16MB]
    ushort* KKb = (ushort*)(ws + 4 * U);      // 4 MB
    ushort* MBb = KKb + U;                    // 4 MB
    ushort* Kb  = (ushort*)(ws + 5 * U);      // 4 MB
    ushort* Rb  = Kb + U;                     // 4 MB
    ushort* XB = (ushort*)(ws + 8 * U);
    const size_t TD = U;
    ushort* XR = XB + 0 * TD;
    ushort* XW = XB + 1 * TD;
    ushort* XK = XB + 2 * TD;
    ushort* XV = XB + 3 * TD;
    ushort* XA = XB + 4 * TD;
    ushort* XG = XB + 5 * TD;
    float* Pbuf  = (float*)XB;         // XB[0:16MB]
    float* Lbuf  = u_g;                // ws+6U..8U (16MB)
    float* zbuf  = ws + 10 * U;        // XB[16:24MB]
    float* olbuf = (float*)d_out;      // d_out[0:8MB]
    float* SstT  = u_dc;               // ws+3U..5U (16MB; 2nd half over KKb/MBb, dead)
    ushort* OG   = XB;                 // bf16 4 MB (Pbuf dead after oddfill)
    ushort* XM   = (ushort*)(ws + 10 * U);
    float* Opart = ws + 4 * U;         // 2 x 8 MB (bf16 streams dead after pass1)
    ushort* Hbuf = (ushort*)(ws + 4 * U);   // 16 MB (Opart dead after reduce2)
    float* Dpart = ws;                 // 4 x 8 MB (u_r..u_dc dead after fix)
    ushort* WT = (ushort*)(ws + 11 * U);
    const size_t DD = (size_t)D_ * D_;
    const size_t DF = (size_t)D_ * F_;
    ushort* WTR = WT;
    ushort* WTK = WTR + DD;
    ushort* WTV = WTK + DD;
    ushort* WTO = WTV + DD;
    ushort* WTGU = WTO + DD;          // interleaved gate|up [8192,1024]
    ushort* WTD = WTGU + 2 * DF;
    ushort* WTw1 = WTD + DF;
    ushort* WTw2 = WTw1 + 64 * 1024;
    ushort* WTa1 = WTw2 + 64 * 1024;
    ushort* WTa2 = WTa1 + 64 * 1024;
    ushort* WTv1 = WTa2 + 64 * 1024;
    ushort* WTv2 = WTv1 + 32 * 1024;
    ushort* WTg1 = WTv2 + 32 * 1024;
    ushort* WTg2 = WTg1 + 128 * 1024;
    ushort* Lw = WTg2 + 128 * 1024;
    ushort* La = Lw + (size_t)T_ * 64;
    ushort* Lv = La + (size_t)T_ * 64;
    ushort* Lg = Lv + (size_t)T_ * 32;

    float* out_x = (float*)d_out;
    float* out_xn_last = out_x + (size_t)T_ * D_;
    float* out_state = out_xn_last + D_;

    // --- all 15 weight transposes in ONE launch (gate/up -> interleaved) ---
    TPack tp;
    int toff = 0, ti = 0;
    auto addT = [&](const float* in, ushort* out, int K, int N, int mode) {
        tp.d[ti].in = in; tp.d[ti].out = out; tp.d[ti].K = K; tp.d[ti].N = N;
        tp.d[ti].off = toff; tp.d[ti].mode = mode;
        toff += (N / 32) * (K / 32); ++ti;
    };
    addT(R_, WTR, D_, D_, 0);
    addT(K_, WTK, D_, D_, 0);
    addT(V_, WTV, D_, D_, 0);
    addT(O_, WTO, D_, D_, 0);
    addT(gate_w, WTGU, D_, F_, 1);
    addT(up_w, WTGU, D_, F_, 2);
    addT(down_w, WTD, F_, D_, 0);
    addT(w1, WTw1, D_, 64, 0);
    addT(w2, WTw2, 64, D_, 0);
    addT(a1, WTa1, D_, 64, 0);
    addT(a2, WTa2, 64, D_, 0);
    addT(v1, WTv1, D_, 32, 0);
    addT(v2, WTv2, 32, D_, 0);
    addT(g1, WTg1, D_, 128, 0);
    addT(g2, WTg2, 128, D_, 0);
    transpose_cast_multi<<<toff, 256, 0, stream>>>(tp);

    // 1. fused ln1 + token shift -> bf16 xr..xg + xn_last
    ln_shift_kernel<<<T_, 256, 0, stream>>>(x, x_prev, ln1_w,
                                            x_r, x_w, x_k, x_v, x_a, x_g,
                                            XR, XW, XK, XV, XA, XG, out_xn_last);
    // 2-5. r/k/v + 4 LoRA stage-1 GEMMs in ONE launch, TM=64 tiles
    //      (8x32 grid per slice: 896 active blocks ~ 3.5/CU)
    auto mkmm = [](const ushort* A, const ushort* BT, float* Cf, ushort* Cb,
                   const float* res, const float* res2, const float* bias,
                   int Ntot, int K, int epi) {
        MMDesc m{A, BT, Cf, Cb, res, res2, bias, Ntot, K, epi};
        return m;
    };
    MMPack<7> pa;
    pa.d[0] = mkmm(XR, WTR, u_r, Rb, nullptr, nullptr, nullptr, D_, D_, 0);
    pa.d[1] = mkmm(XK, WTK, u_k, nullptr, nullptr, nullptr, nullptr, D_, D_, 0);
    pa.d[2] = mkmm(XV, WTV, u_v, nullptr, nullptr, nullptr, nullptr, D_, D_, 0);
    pa.d[3] = mkmm(XW, WTw1, nullptr, Lw, nullptr, nullptr, nullptr, 64,  D_, 3);  // tanh
    pa.d[4] = mkmm(XA, WTa1, nullptr, La, nullptr, nullptr, nullptr, 64,  D_, 0);
    pa.d[5] = mkmm(XV, WTv1, nullptr, Lv, nullptr, nullptr, nullptr, 32,  D_, 0);
    pa.d[6] = mkmm(XG, WTg1, nullptr, Lg, nullptr, nullptr, nullptr, 128, D_, 4);  // sigmoid
    mfma_gemm_multi<7, 64><<<dim3(8, 32, 7), 256, 0, stream>>>(pa);
    // 6. LoRA stage-2 (decay / a_sig / v-lerp), TM=64; g deferred (u_g = Lbuf)
    MMPack<3> pb;
    pb.d[0] = mkmm(Lw, WTw2, u_dc, nullptr, nullptr, nullptr, w0, D_, 64,  6);  // decay
    pb.d[1] = mkmm(La, WTa2, u_ao, nullptr, nullptr, nullptr, a0, D_, 64,  5);  // a_sig
    pb.d[2] = mkmm(Lv, WTv2, u_v,  nullptr, u_v, v_first,     v0, D_, 32,  7);  // v lerp
    mfma_gemm_multi<3, 64><<<dim3(8, 32, 3), 256, 0, stream>>>(pb);
    // 7. kk / mb (bf16) / k-mod (fp32 + bf16)
    kk_kernel<<<T_ * H_ / 4, 256, 0, stream>>>(u_k, u_ao, k_k, k_a, KKb, MBb, Kb);
    // 8. chunked scan: pass1 (bf16 streams) -> pair-merge -> serial-32 -> odd-fill
    scan_pass1<<<NCHUNK * H_, 64, 0, stream>>>(Rb, u_dc, Kb, u_v, KKb, MBb,
                                               Pbuf, Lbuf, zbuf, olbuf);
    merge_pairs<<<16 * 32, 64, 0, stream>>>(Pbuf, Lbuf);
    scan_combine<<<H_ * 4, 256, 0, stream>>>(state, Pbuf, Lbuf, SstT, out_state);
    scan_oddfill<<<16 * 32 * 4, 256, 0, stream>>>(Pbuf, Lbuf, SstT);
    // 8b. deferred g GEMM (Lbuf dead -> u_g writable)
    mfma_gemm<float, false><<<dim3(8, 16), 256, 0, stream>>>(
        Lg, WTg2, u_g, nullptr, T_, D_, 128, 128, 0);
    // 9. fused fix + bonus + gate -> OG bf16
    scan_fix<<<(T_ / 16) * H_, 256, 0, stream>>>(zbuf, olbuf, SstT,
                                                 u_r, u_k, u_v, u_g, r_k, OG);
    // 10. O-proj split-K2 -> fp32 partials at ws+4U, 256 blocks
    mfma_gemm<float, true><<<dim3(8, 16, 2), 256, 0, stream>>>(
        OG, WTO, Opart, nullptr, T_, D_, D_, 512, 0);
    // 11. fused: out_x = x + p0 + p1; ln2(out_x) -> XM bf16
    rmsnorm_reduce2<<<T_, 256, 0, stream>>>(x, Opart, Opart + U, ln2_w, out_x, XM);
    // 12. MLP gate|up with FUSED swiglu epilogue -> Hbuf bf16 [T,4096]
    mfma_gemm<ushort, false><<<dim3(64, 16), 256, 0, stream>>>(
        XM, WTGU, Hbuf, nullptr, T_, 2 * F_, D_, D_, 2);
    // 13. down split-K4 -> fp32 partials over ws..4U, 512 blocks
    mfma_gemm<float, true><<<dim3(8, 16, 4), 256, 0, stream>>>(
        Hbuf, WTD, Dpart, nullptr, T_, D_, F_, 1024, 0);
    // 14. out_x += sum of 4 partials
    add4_kernel<<<(int)(U / 4 / 256), 256, 0, stream>>>(out_x, Dpart, (int)(U / 4));
}